// Round 10
// baseline (3192.334 us; speedup 1.0000x reference)
//
#include <hip/hip_runtime.h>
#include <math.h>

#define TT    4096
#define DD    512
#define HH    8
#define DHH   64
#define NH    4
#define LLAY  4
#define DFFN  2048
#define BHH   32          // B*H
#define NC    256         // chunks per bh (NH*NB)
#define MROWS 16384       // B*T

typedef __attribute__((ext_vector_type(8))) short s16x8;
typedef __attribute__((ext_vector_type(4))) float f32x4;
typedef unsigned short ushort_t;

union U4 { unsigned u[4]; s16x8 v; };

__device__ __forceinline__ unsigned short f2bf(float f) {
    unsigned u = __float_as_uint(f);
    unsigned r = (u + 0x7FFFu + ((u >> 16) & 1u)) >> 16;
    return (unsigned short)r;
}
__device__ __forceinline__ float bf2f(unsigned short h) {
    return __uint_as_float(((unsigned)h) << 16);
}

// XCD-aware bijective swizzle (T1, m157): nwg must be divisible by 8.
__device__ __forceinline__ void xcd_swz(int& bx, int& by) {
    const int gx = gridDim.x;
    const int nwg = gx * gridDim.y;
    const int flat = by * gx + bx;
    const int q = nwg >> 3;
    const int swz = (flat & 7) * q + (flat >> 3);
    bx = swz % gx;
    by = swz / gx;
}

// ---------------------------------------------------------------------------
// bf16x3 MFMA GEMM, 2-phase double-buffered: C = op(A @ W^T + b)[+r]
// outputs: fp32 (outf) and/or hi/lo pair (outh,outl) and/or packed u32 (outp)
// ---------------------------------------------------------------------------
__global__ __launch_bounds__(256) void gemm_bf3_k(
    const ushort_t* __restrict__ Ah, const ushort_t* __restrict__ Al, int lda,
    const ushort_t* __restrict__ Wh, const ushort_t* __restrict__ Wl, int ldw,
    const float* __restrict__ bias, const float* __restrict__ resid,
    float* __restrict__ outf, ushort_t* __restrict__ outh, ushort_t* __restrict__ outl,
    unsigned* __restrict__ outp,
    int M, int N, int K, int relu)
{
    __shared__ __align__(16) ushort_t lds[2][4 * 128 * 32];   // 2 x 32KB
    const int tid  = threadIdx.x;
    const int lane = tid & 63;
    const int wv   = tid >> 6;
    const int wm   = wv >> 1, wn = wv & 1;
    int bx = blockIdx.x, by = blockIdx.y;
    xcd_swz(bx, by);
    const int row0 = by * 128, col0 = bx * 128;
    const int g    = lane >> 4;
    const int srow0 = wv * 32;

    f32x4 acc[4][4];
#pragma unroll
    for (int mi = 0; mi < 4; mi++)
#pragma unroll
        for (int ni = 0; ni < 4; ni++) acc[mi][ni] = (f32x4)(0.f);

    auto STAGE = [&](int buf, int k0) {
#pragma unroll
        for (int ii = 0; ii < 2; ii++) {
            const int r   = srow0 + ii * 16 + (lane >> 2);
            const int ug  = (((lane & 3) ^ ((r >> 1) & 3)) << 3);
            const size_t ga = (size_t)(row0 + r) * lda + k0 + ug;
            const size_t gw = (size_t)(col0 + r) * ldw + k0 + ug;
            const int lo  = (srow0 + ii * 16) * 32;
            __builtin_amdgcn_global_load_lds(
                (const __attribute__((address_space(1))) void*)(Ah + ga),
                (__attribute__((address_space(3))) void*)&lds[buf][0 * 4096 + lo], 16, 0, 0);
            __builtin_amdgcn_global_load_lds(
                (const __attribute__((address_space(1))) void*)(Al + ga),
                (__attribute__((address_space(3))) void*)&lds[buf][1 * 4096 + lo], 16, 0, 0);
            __builtin_amdgcn_global_load_lds(
                (const __attribute__((address_space(1))) void*)(Wh + gw),
                (__attribute__((address_space(3))) void*)&lds[buf][2 * 4096 + lo], 16, 0, 0);
            __builtin_amdgcn_global_load_lds(
                (const __attribute__((address_space(1))) void*)(Wl + gw),
                (__attribute__((address_space(3))) void*)&lds[buf][3 * 4096 + lo], 16, 0, 0);
        }
    };

    const int nt = K >> 5;
    STAGE(0, 0);

    for (int t = 0; t < nt; ++t) {
        const int cur = t & 1;
        if (t + 1 < nt) {
            STAGE(cur ^ 1, (t + 1) << 5);
            asm volatile("s_waitcnt vmcnt(8)" ::: "memory");
        } else {
            asm volatile("s_waitcnt vmcnt(0)" ::: "memory");
        }
        __builtin_amdgcn_s_barrier();
        __builtin_amdgcn_sched_barrier(0);

        s16x8 ah[4], al[4], wh[4], wl[4];
#pragma unroll
        for (int mi = 0; mi < 4; mi++) {
            const int m  = wm * 64 + mi * 16 + (lane & 15);
            const int pu = ((g ^ ((m >> 1) & 3)) << 3);
            ah[mi] = *(const s16x8*)&lds[cur][0 * 4096 + m * 32 + pu];
            al[mi] = *(const s16x8*)&lds[cur][1 * 4096 + m * 32 + pu];
            const int n  = wn * 64 + mi * 16 + (lane & 15);
            const int pn = ((g ^ ((n >> 1) & 3)) << 3);
            wh[mi] = *(const s16x8*)&lds[cur][2 * 4096 + n * 32 + pn];
            wl[mi] = *(const s16x8*)&lds[cur][3 * 4096 + n * 32 + pn];
        }
#pragma unroll
        for (int mi = 0; mi < 4; mi++)
#pragma unroll
            for (int ni = 0; ni < 4; ni++) {
                acc[mi][ni] = __builtin_amdgcn_mfma_f32_16x16x32_bf16(ah[mi], wh[ni], acc[mi][ni], 0, 0, 0);
                acc[mi][ni] = __builtin_amdgcn_mfma_f32_16x16x32_bf16(al[mi], wh[ni], acc[mi][ni], 0, 0, 0);
                acc[mi][ni] = __builtin_amdgcn_mfma_f32_16x16x32_bf16(ah[mi], wl[ni], acc[mi][ni], 0, 0, 0);
            }

        __builtin_amdgcn_sched_barrier(0);
        __builtin_amdgcn_s_barrier();     // WAR: lds[cur] overwritten at t+1's STAGE
    }

#pragma unroll
    for (int mi = 0; mi < 4; mi++) {
#pragma unroll
        for (int ni = 0; ni < 4; ni++) {
#pragma unroll
            for (int r = 0; r < 4; r++) {
                const int row = row0 + wm * 64 + mi * 16 + g * 4 + r;
                const int col = col0 + wn * 64 + ni * 16 + (lane & 15);
                float v = acc[mi][ni][r];
                if (bias)  v += bias[col];
                if (relu)  v = fmaxf(v, 0.f);
                if (resid) v += resid[(size_t)row * N + col];
                if (outf)  outf[(size_t)row * N + col] = v;
                if (outh) {
                    unsigned short h = f2bf(v);
                    outh[(size_t)row * N + col] = h;
                    outl[(size_t)row * N + col] = f2bf(v - bf2f(h));
                }
                if (outp) {
                    unsigned short h = f2bf(v);
                    outp[(size_t)row * N + col] =
                        (unsigned)h | ((unsigned)f2bf(v - bf2f(h)) << 16);
                }
            }
        }
    }
}

// ---------------------------------------------------------------------------
// bf16x6 MFMA GEMM (qk only): ~2^-26 rel err. Emits fp32 + packed hi/lo.
// ---------------------------------------------------------------------------
__global__ __launch_bounds__(256) void gemm_bf6_k(
    const ushort_t* __restrict__ A1, const ushort_t* __restrict__ A2,
    const ushort_t* __restrict__ A3, int lda,
    const ushort_t* __restrict__ W1, const ushort_t* __restrict__ W2,
    const ushort_t* __restrict__ W3,
    float* __restrict__ outf, unsigned* __restrict__ outp, int M, int N, int K)
{
    __shared__ __align__(16) ushort_t lds[6 * 128 * 32];   // A1,A2,A3,W1,W2,W3
    const int tid  = threadIdx.x;
    const int lane = tid & 63;
    const int wv   = tid >> 6;
    const int wm   = wv >> 1, wn = wv & 1;
    int bx = blockIdx.x, by = blockIdx.y;
    xcd_swz(bx, by);
    const int row0 = by * 128, col0 = bx * 128;
    const int g    = lane >> 4;

    f32x4 acc[4][4];
#pragma unroll
    for (int mi = 0; mi < 4; mi++)
#pragma unroll
        for (int ni = 0; ni < 4; ni++) acc[mi][ni] = (f32x4)(0.f);

    const int srow0 = wv * 32;

    for (int k0 = 0; k0 < K; k0 += 32) {
        __syncthreads();
#pragma unroll
        for (int ii = 0; ii < 2; ii++) {
            const int r   = srow0 + ii * 16 + (lane >> 2);
            const int ug  = (((lane & 3) ^ ((r >> 1) & 3)) << 3);
            const size_t ga = (size_t)(row0 + r) * lda + k0 + ug;
            const size_t gw = (size_t)(col0 + r) * K   + k0 + ug;
            const int lo  = (srow0 + ii * 16) * 32;
            __builtin_amdgcn_global_load_lds(
                (const __attribute__((address_space(1))) void*)(A1 + ga),
                (__attribute__((address_space(3))) void*)&lds[0 * 4096 + lo], 16, 0, 0);
            __builtin_amdgcn_global_load_lds(
                (const __attribute__((address_space(1))) void*)(A2 + ga),
                (__attribute__((address_space(3))) void*)&lds[1 * 4096 + lo], 16, 0, 0);
            __builtin_amdgcn_global_load_lds(
                (const __attribute__((address_space(1))) void*)(A3 + ga),
                (__attribute__((address_space(3))) void*)&lds[2 * 4096 + lo], 16, 0, 0);
            __builtin_amdgcn_global_load_lds(
                (const __attribute__((address_space(1))) void*)(W1 + gw),
                (__attribute__((address_space(3))) void*)&lds[3 * 4096 + lo], 16, 0, 0);
            __builtin_amdgcn_global_load_lds(
                (const __attribute__((address_space(1))) void*)(W2 + gw),
                (__attribute__((address_space(3))) void*)&lds[4 * 4096 + lo], 16, 0, 0);
            __builtin_amdgcn_global_load_lds(
                (const __attribute__((address_space(1))) void*)(W3 + gw),
                (__attribute__((address_space(3))) void*)&lds[5 * 4096 + lo], 16, 0, 0);
        }
        __syncthreads();

        s16x8 a1[4], a2[4], a3[4], w1[4], w2[4], w3[4];
#pragma unroll
        for (int mi = 0; mi < 4; mi++) {
            const int m  = wm * 64 + mi * 16 + (lane & 15);
            const int pu = ((g ^ ((m >> 1) & 3)) << 3);
            a1[mi] = *(const s16x8*)&lds[0 * 4096 + m * 32 + pu];
            a2[mi] = *(const s16x8*)&lds[1 * 4096 + m * 32 + pu];
            a3[mi] = *(const s16x8*)&lds[2 * 4096 + m * 32 + pu];
            const int n  = wn * 64 + mi * 16 + (lane & 15);
            const int pn = ((g ^ ((n >> 1) & 3)) << 3);
            w1[mi] = *(const s16x8*)&lds[3 * 4096 + n * 32 + pn];
            w2[mi] = *(const s16x8*)&lds[4 * 4096 + n * 32 + pn];
            w3[mi] = *(const s16x8*)&lds[5 * 4096 + n * 32 + pn];
        }
#pragma unroll
        for (int mi = 0; mi < 4; mi++)
#pragma unroll
            for (int ni = 0; ni < 4; ni++) {
                acc[mi][ni] = __builtin_amdgcn_mfma_f32_16x16x32_bf16(a1[mi], w1[ni], acc[mi][ni], 0, 0, 0);
                acc[mi][ni] = __builtin_amdgcn_mfma_f32_16x16x32_bf16(a2[mi], w1[ni], acc[mi][ni], 0, 0, 0);
                acc[mi][ni] = __builtin_amdgcn_mfma_f32_16x16x32_bf16(a1[mi], w2[ni], acc[mi][ni], 0, 0, 0);
                acc[mi][ni] = __builtin_amdgcn_mfma_f32_16x16x32_bf16(a2[mi], w2[ni], acc[mi][ni], 0, 0, 0);
                acc[mi][ni] = __builtin_amdgcn_mfma_f32_16x16x32_bf16(a1[mi], w3[ni], acc[mi][ni], 0, 0, 0);
                acc[mi][ni] = __builtin_amdgcn_mfma_f32_16x16x32_bf16(a3[mi], w1[ni], acc[mi][ni], 0, 0, 0);
            }
    }

#pragma unroll
    for (int mi = 0; mi < 4; mi++) {
#pragma unroll
        for (int ni = 0; ni < 4; ni++) {
#pragma unroll
            for (int r = 0; r < 4; r++) {
                const int row = row0 + wm * 64 + mi * 16 + g * 4 + r;
                const int col = col0 + wn * 64 + ni * 16 + (lane & 15);
                float v = acc[mi][ni][r];
                outf[(size_t)row * N + col] = v;
                unsigned short h = f2bf(v);
                outp[(size_t)row * N + col] =
                    (unsigned)h | ((unsigned)f2bf(v - bf2f(h)) << 16);
            }
        }
    }
}

// ---------------------------------------------------------------------------
// fp32 -> bf16 split converter
// ---------------------------------------------------------------------------
__global__ __launch_bounds__(256) void cvt_k(
    const float* __restrict__ in, ushort_t* __restrict__ o1,
    ushort_t* __restrict__ o2, ushort_t* __restrict__ o3, int n4)
{
    int i = blockIdx.x * 256 + threadIdx.x;
    if (i >= n4) return;
    float4 v = ((const float4*)in)[i];
    float vv[4] = {v.x, v.y, v.z, v.w};
    union { unsigned short us[4]; ushort4 v4; } H, L, M;
#pragma unroll
    for (int q = 0; q < 4; q++) {
        unsigned short a = f2bf(vv[q]);
        float r1 = vv[q] - bf2f(a);
        unsigned short b = f2bf(r1);
        H.us[q] = a; L.us[q] = b;
        M.us[q] = f2bf(r1 - bf2f(b));
    }
    ((ushort4*)o1)[i] = H.v4;
    ((ushort4*)o2)[i] = L.v4;
    if (o3) ((ushort4*)o3)[i] = M.v4;
}

// ---------------------------------------------------------------------------
// Bucket kernel v2 (all 4 rounds per block) — reads fp32 qk
// ---------------------------------------------------------------------------
__global__ __launch_bounds__(256) void bucket_k(
    const float* __restrict__ qk, const float* __restrict__ rot,
    int* __restrict__ bkt)
{
    __shared__ float rs[NH][64][32];    // 32 KB
    const int bh = blockIdx.y;
    const int t = blockIdx.x * 256 + threadIdx.x;
    for (int i = threadIdx.x; i < NH * 64 * 32; i += 256) {
        int r = i >> 11, f = (i >> 5) & 63, j = i & 31;
        rs[r][f][j] = rot[(f * NH + r) * 32 + j];
    }
    __syncthreads();
    const int b = bh >> 3, h = bh & 7;
    const float* q = qk + ((size_t)(b * TT + t)) * DD + h * DHH;
    float qv[64];
#pragma unroll
    for (int f4 = 0; f4 < 16; f4++) {
        float4 tmp = ((const float4*)q)[f4];
        qv[f4 * 4 + 0] = tmp.x; qv[f4 * 4 + 1] = tmp.y;
        qv[f4 * 4 + 2] = tmp.z; qv[f4 * 4 + 3] = tmp.w;
    }
    for (int r = 0; r < NH; r++) {
        float rv[32];
#pragma unroll
        for (int j = 0; j < 32; j++) rv[j] = 0.f;
        for (int f = 0; f < 64; f++) {
            float qf = qv[f];
#pragma unroll
            for (int j = 0; j < 32; j++) rv[j] = fmaf(qf, rs[r][f][j], rv[j]);
        }
        float best = rv[0];
        int bi = 0;
#pragma unroll
        for (int j = 1; j < 32; j++) { if (rv[j] > best) { best = rv[j]; bi = j; } }
#pragma unroll
        for (int j = 0; j < 32; j++) { float v = -rv[j]; if (v > best) { best = v; bi = 32 + j; } }
        bkt[((size_t)bh * NH + r) * TT + t] = bi;
    }
}

// ---------------------------------------------------------------------------
// Parallel stable counting sort per (bh, round). (verified R4)
// ---------------------------------------------------------------------------
__global__ __launch_bounds__(256) void sort_k(
    const int* __restrict__ bkt, int* __restrict__ st)
{
    __shared__ int lb[TT];
    __shared__ unsigned short cnt[128][64];
    __shared__ int base[64];
    const int r = blockIdx.x, bh = blockIdx.y;
    const int tid = threadIdx.x;
    const int* src = bkt + ((size_t)bh * NH + r) * TT;

    const int4* s4 = (const int4*)src;
    int4* l4 = (int4*)lb;
#pragma unroll
    for (int q = 0; q < 4; q++) l4[tid + q * 256] = s4[tid + q * 256];
    unsigned* cz = (unsigned*)cnt;
#pragma unroll
    for (int q = 0; q < 16; q++) cz[tid + q * 256] = 0;
    __syncthreads();

    if (tid < 128) {
        for (int it = 0; it < 32; it++) {
            int bb = lb[tid * 32 + it];
            cnt[tid][bb]++;
        }
    }
    __syncthreads();

    if (tid < 64) {
        const int bb = tid;
        int run = 0;
        for (int s = 0; s < 128; s++) {
            int t = cnt[s][bb];
            cnt[s][bb] = (unsigned short)run;
            run += t;
        }
        int inc = run;
#pragma unroll
        for (int off = 1; off < 64; off <<= 1) {
            int n = __shfl_up(inc, off, 64);
            if (tid >= off) inc += n;
        }
        base[bb] = inc - run;
    }
    __syncthreads();

    if (tid < 128) {
        int* dst = st + (size_t)bh * (NH * TT) + (size_t)r * TT;
        for (int it = 0; it < 32; it++) {
            int t = tid * 32 + it;
            int bb = lb[t];
            int pos = base[bb] + (int)cnt[tid][bb];
            cnt[tid][bb]++;
            dst[pos] = t;
        }
    }
}

// ---------------------------------------------------------------------------
// Attention v5: inputs pre-packed as u32 (hi | lo<<16) per element.
// Staging: V copied verbatim to LDS; K unpacked to hi/lo words (4 ops/pair).
// Strip of 8 bh.
// ---------------------------------------------------------------------------
__global__ __launch_bounds__(256, 2) void attn_k(
    const unsigned* __restrict__ qkp, const unsigned* __restrict__ vp,
    const int* __restrict__ st, float* __restrict__ obuf,
    float* __restrict__ lseb, int bh0)
{
    __shared__ __align__(16) ushort_t ksh[128 * 72];
    __shared__ __align__(16) ushort_t ksl[128 * 72];
    __shared__ __align__(16) unsigned vsp[128 * 66];
    __shared__ float invn[128];
    __shared__ int   tks[128];

    const int c   = blockIdx.x;
    const int bhl = blockIdx.y;
    const int bh  = bh0 + bhl;
    const int b   = bh >> 3, h = bh & 7;
    const int tid = threadIdx.x;
    const int* stb = st + (size_t)bh * (NH * TT);

    if (tid < 128) {
        int cc = (tid < 64) ? c : ((c + NC - 1) & (NC - 1));
        tks[tid] = stb[cc * 64 + (tid & 63)];
    }
    __syncthreads();

    {   // stage K (unpack hi/lo) + V (verbatim) + inv k-norms
        const int row = tid >> 1, c0 = (tid & 1) * 32;
        const int t = tks[row];
        const uint4* kg = (const uint4*)(qkp + ((size_t)(b * TT + t)) * DD + h * DHH + c0);
        const uint4* vg = (const uint4*)(vp  + ((size_t)(b * TT + t)) * DD + h * DHH + c0);
        unsigned kp[32];
        uint4 vq[8];
        float ss = 0.f;
#pragma unroll
        for (int q = 0; q < 8; q++) {
            uint4 kq = kg[q];
            kp[4 * q + 0] = kq.x; kp[4 * q + 1] = kq.y;
            kp[4 * q + 2] = kq.z; kp[4 * q + 3] = kq.w;
            vq[q] = vg[q];
        }
#pragma unroll
        for (int e = 0; e < 32; e++) {
            float f = __uint_as_float(kp[e] << 16) + __uint_as_float(kp[e] & 0xffff0000u);
            ss = fmaf(f, f, ss);
        }
        ss += __shfl_xor(ss, 1);
        if ((tid & 1) == 0) invn[row] = 1.0f / fmaxf(sqrtf(ss), 1e-12f);

        unsigned hw[16], lw[16];
#pragma unroll
        for (int e = 0; e < 16; e++) {
            hw[e] = (kp[2 * e] & 0xffffu) | (kp[2 * e + 1] << 16);
            lw[e] = (kp[2 * e] >> 16) | (kp[2 * e + 1] & 0xffff0000u);
        }
        uint4* kdh = (uint4*)&ksh[row * 72 + c0];
        uint4* kdl = (uint4*)&ksl[row * 72 + c0];
#pragma unroll
        for (int q = 0; q < 4; q++) {
            kdh[q] = make_uint4(hw[4 * q], hw[4 * q + 1], hw[4 * q + 2], hw[4 * q + 3]);
            kdl[q] = make_uint4(lw[4 * q], lw[4 * q + 1], lw[4 * q + 2], lw[4 * q + 3]);
        }
        uint2* vd = (uint2*)&vsp[row * 66 + c0];
#pragma unroll
        for (int q = 0; q < 8; q++) {
            vd[2 * q]     = make_uint2(vq[q].x, vq[q].y);
            vd[2 * q + 1] = make_uint2(vq[q].z, vq[q].w);
        }
    }
    __syncthreads();

    const int lane = tid & 63;
    const int wv   = tid >> 6;
    const int cc16 = lane & 15;
    const int g    = lane >> 4;
    const int rr   = c >> 6;

    f32x4 stt[8];
#pragma unroll
    for (int jt = 0; jt < 8; jt++) stt[jt] = (f32x4)(0.f);

    const int qrow = wv * 16 + cc16;
#pragma unroll
    for (int ks = 0; ks < 2; ks++) {
        s16x8 qh = *(const s16x8*)&ksh[qrow * 72 + ks * 32 + g * 8];
        s16x8 ql = *(const s16x8*)&ksl[qrow * 72 + ks * 32 + g * 8];
#pragma unroll
        for (int jt = 0; jt < 8; jt++) {
            const int krow = jt * 16 + cc16;
            s16x8 ah = *(const s16x8*)&ksh[krow * 72 + ks * 32 + g * 8];
            s16x8 al = *(const s16x8*)&ksl[krow * 72 + ks * 32 + g * 8];
            stt[jt] = __builtin_amdgcn_mfma_f32_16x16x32_bf16(ah, qh, stt[jt], 0, 0, 0);
            stt[jt] = __builtin_amdgcn_mfma_f32_16x16x32_bf16(al, qh, stt[jt], 0, 0, 0);
            stt[jt] = __builtin_amdgcn_mfma_f32_16x16x32_bf16(ah, ql, stt[jt], 0, 0, 0);
        }
    }

    const int tqi = tks[wv * 16 + cc16];
    float m = -INFINITY;
#pragma unroll
    for (int jt = 0; jt < 8; jt++) {
#pragma unroll
        for (int r4 = 0; r4 < 4; r4++) {
            const int j = jt * 16 + g * 4 + r4;
            float d = stt[jt][r4] * invn[j] * 0.125f;
            if (tqi == tks[j]) d = -5e4f;
            stt[jt][r4] = d;
            m = fmaxf(m, d);
        }
    }
    m = fmaxf(m, __shfl_xor(m, 16));
    m = fmaxf(m, __shfl_xor(m, 32));
    float s = 0.f;
#pragma unroll
    for (int jt = 0; jt < 8; jt++) {
#pragma unroll
        for (int r4 = 0; r4 < 4; r4++) {
            float e = expf(stt[jt][r4] - m);
            stt[jt][r4] = e;
            s += e;
        }
    }
    s += __shfl_xor(s, 16);
    s += __shfl_xor(s, 32);
    const float is = 1.0f / s;
    if (g == 0) lseb[((size_t)bh * NH + rr) * TT + tqi] = m + logf(s);

    unsigned ph[8][2], pl[8][2];
#pragma unroll
    for (int jt = 0; jt < 8; jt++) {
#pragma unroll
        for (int w2 = 0; w2 < 2; w2++) {
            float p0 = stt[jt][2 * w2] * is;
            float p1 = stt[jt][2 * w2 + 1] * is;
            unsigned short h0 = f2bf(p0), h1 = f2bf(p1);
            ph[jt][w2] = (unsigned)h0 | ((unsigned)h1 << 16);
            pl[jt][w2] = (unsigned)f2bf(p0 - bf2f(h0)) | ((unsigned)f2bf(p1 - bf2f(h1)) << 16);
        }
    }

    f32x4 occ[4];
#pragma unroll
    for (int nt = 0; nt < 4; nt++) occ[nt] = (f32x4)(0.f);

    const int srcLow  = ((g & 1) << 5) + cc16;
    const int srcHigh = srcLow + 16;
    const bool hiT = (lane & 32) != 0;

#pragma unroll
    for (int ks = 0; ks < 4; ks++) {
        U4 Phi, Plo;
        {
            unsigned a0 = (unsigned)__shfl((int)ph[2 * ks][0], srcLow);
            unsigned a1 = (unsigned)__shfl((int)ph[2 * ks][1], srcLow);
            unsigned a2 = (unsigned)__shfl((int)ph[2 * ks][0], srcHigh);
            unsigned a3 = (unsigned)__shfl((int)ph[2 * ks][1], srcHigh);
            unsigned b0 = (unsigned)__shfl((int)ph[2 * ks + 1][0], srcLow);
            unsigned b1 = (unsigned)__shfl((int)ph[2 * ks + 1][1], srcLow);
            unsigned b2 = (unsigned)__shfl((int)ph[2 * ks + 1][0], srcHigh);
            unsigned b3 = (unsigned)__shfl((int)ph[2 * ks + 1][1], srcHigh);
            Phi.u[0] = hiT ? b0 : a0; Phi.u[1] = hiT ? b1 : a1;
            Phi.u[2] = hiT ? b2 : a2; Phi.u[3] = hiT ? b3 : a3;
            unsigned c0 = (unsigned)__shfl((int)pl[2 * ks][0], srcLow);
            unsigned c1 = (unsigned)__shfl((int)pl[2 * ks][1], srcLow);
            unsigned c2 = (unsigned)__shfl((int)pl[2 * ks][0], srcHigh);
            unsigned c3 = (unsigned)__shfl((int)pl[2 * ks][1], srcHigh);
            unsigned d0 = (unsigned)__shfl((int)pl[2 * ks + 1][0], srcLow);
            unsigned d1 = (unsigned)__shfl((int)pl[2 * ks + 1][1], srcLow);
            unsigned d2 = (unsigned)__shfl((int)pl[2 * ks + 1][0], srcHigh);
            unsigned d3 = (unsigned)__shfl((int)pl[2 * ks + 1][1], srcHigh);
            Plo.u[0] = hiT ? d0 : c0; Plo.u[1] = hiT ? d1 : c1;
            Plo.u[2] = hiT ? d2 : c2; Plo.u[3] = hiT ? d3 : c3;
        }
#pragma unroll
        for (int nt = 0; nt < 4; nt++) {
            unsigned u[8];
#pragma unroll
            for (int e = 0; e < 8; e++)
                u[e] = vsp[(32 * ks + 8 * g + e) * 66 + nt * 16 + cc16];
            U4 Vh, Vl;
#pragma unroll
            for (int m2 = 0; m2 < 4; m2++) {
                Vh.u[m2] = (u[2 * m2] & 0xffffu) | (u[2 * m2 + 1] << 16);
                Vl.u[m2] = (u[2 * m2] >> 16) | (u[2 * m2 + 1] & 0xffff0000u);
            }
            occ[nt] = __builtin_amdgcn_mfma_f32_16x16x32_bf16(Phi.v, Vh.v, occ[nt], 0, 0, 0);
            occ[nt] = __builtin_amdgcn_mfma_f32_16x16x32_bf16(Plo.v, Vh.v, occ[nt], 0, 0, 0);
            occ[nt] = __builtin_amdgcn_mfma_f32_16x16x32_bf16(Phi.v, Vl.v, occ[nt], 0, 0, 0);
        }
    }

#pragma unroll
    for (int r4 = 0; r4 < 4; r4++) {
        const int i = wv * 16 + g * 4 + r4;
        const int ti = tks[i];
        float* dst = obuf + (((size_t)bhl * NH + rr) * TT + ti) * DHH + cc16;
        dst[0]  = occ[0][r4];
        dst[16] = occ[1][r4];
        dst[32] = occ[2][r4];
        dst[48] = occ[3][r4];
    }
}

// ---------------------------------------------------------------------------
// Combine rounds for an 8-bh strip
// ---------------------------------------------------------------------------
__global__ __launch_bounds__(256) void combine_k(
    const float* __restrict__ obuf, const float* __restrict__ lseb,
    ushort_t* __restrict__ att, int bh0)
{
    int idx = blockIdx.x * 256 + threadIdx.x;
    int d = idx & 63;
    int t = (idx >> 6) & (TT - 1);
    int bhl = idx >> 18;
    int bh = bh0 + bhl;
    float l0 = lseb[((size_t)bh * NH + 0) * TT + t];
    float l1 = lseb[((size_t)bh * NH + 1) * TT + t];
    float l2 = lseb[((size_t)bh * NH + 2) * TT + t];
    float l3 = lseb[((size_t)bh * NH + 3) * TT + t];
    float m = fmaxf(fmaxf(l0, l1), fmaxf(l2, l3));
    float e0 = expf(l0 - m), e1 = expf(l1 - m), e2 = expf(l2 - m), e3 = expf(l3 - m);
    float inv = 1.0f / (e0 + e1 + e2 + e3);
    float o0 = obuf[(((size_t)bhl * NH + 0) * TT + t) * DHH + d];
    float o1 = obuf[(((size_t)bhl * NH + 1) * TT + t) * DHH + d];
    float o2 = obuf[(((size_t)bhl * NH + 2) * TT + t) * DHH + d];
    float o3 = obuf[(((size_t)bhl * NH + 3) * TT + t) * DHH + d];
    float o = (e0 * o0 + e1 * o1 + e2 * o2 + e3 * o3) * inv;
    int b = bh >> 3, h = bh & 7;
    size_t base = (size_t)(b * TT + t) * 1024 + h * DHH + d;
    unsigned short hi = f2bf(o);
    att[base]       = hi;
    att[base + 512] = f2bf(o - bf2f(hi));
}

// ---------------------------------------------------------------------------
// LayerNorm over D=512; optional 3-way bf16 split output.
// ---------------------------------------------------------------------------
__global__ __launch_bounds__(64) void ln_k(
    const float* __restrict__ in, const float* __restrict__ g,
    const float* __restrict__ be, float* __restrict__ out,
    ushort_t* __restrict__ oh, ushort_t* __restrict__ ol,
    ushort_t* __restrict__ ol2)
{
    const int row = blockIdx.x;
    const int tid = threadIdx.x;
    const float* x = in + (size_t)row * DD;
    float4 a = *(const float4*)(x + tid * 8);
    float4 b = *(const float4*)(x + tid * 8 + 4);
    float s = a.x + a.y + a.z + a.w + b.x + b.y + b.z + b.w;
#pragma unroll
    for (int o = 32; o >= 1; o >>= 1) s += __shfl_xor(s, o, 64);
    float mean = s * (1.0f / 512.0f);
    float dx[8];
    dx[0] = a.x - mean; dx[1] = a.y - mean; dx[2] = a.z - mean; dx[3] = a.w - mean;
    dx[4] = b.x - mean; dx[5] = b.y - mean; dx[6] = b.z - mean; dx[7] = b.w - mean;
    float ss = 0.f;
#pragma unroll
    for (int q = 0; q < 8; q++) ss += dx[q] * dx[q];
#pragma unroll
    for (int o = 32; o >= 1; o >>= 1) ss += __shfl_xor(ss, o, 64);
    float var = ss * (1.0f / 512.0f);
    float inv = 1.0f / sqrtf(var + 1e-6f);
    const float* gp = g + tid * 8;
    const float* bp = be + tid * 8;
    float y[8];
#pragma unroll
    for (int q = 0; q < 8; q++) y[q] = dx[q] * inv * gp[q] + bp[q];
    float* yp = out + (size_t)row * DD + tid * 8;
    *(float4*)(yp)     = make_float4(y[0], y[1], y[2], y[3]);
    *(float4*)(yp + 4) = make_float4(y[4], y[5], y[6], y[7]);
    if (oh) {
        union { unsigned short us[8]; ushort4 v4[2]; } H, L, M;
#pragma unroll
        for (int q = 0; q < 8; q++) {
            unsigned short h = f2bf(y[q]);
            float r1 = y[q] - bf2f(h);
            unsigned short l = f2bf(r1);
            H.us[q] = h; L.us[q] = l;
            M.us[q] = f2bf(r1 - bf2f(l));
        }
        size_t e = (size_t)row * DD + tid * 8;
        *(ushort4*)(oh + e)      = H.v4[0];
        *(ushort4*)(oh + e + 4)  = H.v4[1];
        *(ushort4*)(ol + e)      = L.v4[0];
        *(ushort4*)(ol + e + 4)  = L.v4[1];
        *(ushort4*)(ol2 + e)     = M.v4[0];
        *(ushort4*)(ol2 + e + 4) = M.v4[1];
    }
}

// ---------------------------------------------------------------------------
extern "C" void kernel_launch(void* const* d_in, const int* in_sizes, int n_in,
                              void* d_out, int out_size, void* d_ws, size_t ws_size,
                              hipStream_t stream)
{
    const float* src  = (const float*)d_in[0];
    const float* rots = (const float*)d_in[1];
    const float* Wqk  = (const float*)d_in[2];
    const float* Wv   = (const float*)d_in[3];
    const float* Wout = (const float*)d_in[4];
    const float* bout = (const float*)d_in[5];
    const float* W1   = (const float*)d_in[6];
    const float* b1   = (const float*)d_in[7];
    const float* W2   = (const float*)d_in[8];
    const float* b2   = (const float*)d_in[9];
    const float* g2   = (const float*)d_in[10];
    const float* be2  = (const float*)d_in[11];
    const float* gf   = (const float*)d_in[12];
    const float* bf   = (const float*)d_in[13];
    float* out = (float*)d_out;

    // ---- workspace layout (~234 MB) ----
    // p+0:     qkb fp32 / attb (SZ_X)
    // p+SZ_X:  vp packed / yff fp32 (SZ_X)
    // p+2SZ_X: qkp packed (SZ_X)   } h1 hi/lo spans these 2 SZ_X during FFN
    // p+3SZ_X: obuf 8-bh (SZ_X)    }
    // p+4SZ_X: weight splits
    char* w = (char*)d_ws;
    const size_t SZ_X = (size_t)MROWS * DD * 4;               // 33.55 MB
    const size_t XHALF = (size_t)MROWS * DD;
    float*    x     = (float*)(w);
    ushort_t* xs    = (ushort_t*)(w + SZ_X);
    ushort_t* xh    = xs;
    ushort_t* xl    = xs + XHALF;
    ushort_t* xl2   = xs + 2 * XHALF;
    char*     p     = w + SZ_X + 3 * XHALF * 2;
    float*    qkb   = (float*)(p);
    ushort_t* attb  = (ushort_t*)(p);
    unsigned* vp    = (unsigned*)(p + SZ_X);
    float*    vb    = (float*)(p + SZ_X);                     // yff (after attn)
    unsigned* qkp   = (unsigned*)(p + 2 * SZ_X);
    float*    obuf  = (float*)(p + 3 * SZ_X);
    ushort_t* h1b   = (ushort_t*)(p + 2 * SZ_X);              // spans 2 SZ_X in FFN
    ushort_t* wb    = (ushort_t*)(p + 4 * SZ_X);
    char*     tail  = p + 4 * SZ_X + 6029312 * 2;
    int*      bkt   = (int*)(tail);
    int*      st    = (int*)(tail + (size_t)BHH * NH * TT * 4);
    float*    lseb  = (float*)(tail + 2 * (size_t)BHH * NH * TT * 4);

    ushort_t* wvh = wb;            ushort_t* wvl = wb + 262144;
    ushort_t* woh = wb + 524288;   ushort_t* wol = wb + 786432;
    ushort_t* w1h = wb + 1048576;  ushort_t* w1l = wb + 2097152;
    ushort_t* w2h = wb + 3145728;  ushort_t* w2l = wb + 4194304;
    ushort_t* wq1 = wb + 5242880;  ushort_t* wq2 = wb + 5505024;
    ushort_t* wq3 = wb + 5767168;
    const size_t H1HALF = (size_t)MROWS * 1024;               // N-strip: 16384 x 1024
    ushort_t* h1h = h1b;           ushort_t* h1l = h1b + H1HALF;

    hipMemcpyAsync(x, src, SZ_X, hipMemcpyDeviceToDevice, stream);
    cvt_k<<<(MROWS * DD / 4 + 255) / 256, 256, 0, stream>>>(src, xh, xl, xl2, MROWS * DD / 4);

    for (int i = 0; i < LLAY; i++) {
        const float* Wqk_i = Wqk + (size_t)i * DD * DD;
        const float* Wv_i  = Wv  + (size_t)i * DD * DD;
        const float* Wout_i= Wout+ (size_t)i * DD * DD;
        const float* bout_i= bout+ (size_t)i * DD;
        const float* W1_i  = W1  + (size_t)i * DFFN * DD;
        const float* b1_i  = b1  + (size_t)i * DFFN;
        const float* W2_i  = W2  + (size_t)i * DD * DFFN;
        const float* b2_i  = b2  + (size_t)i * DD;
        const float* g2_i  = g2  + (size_t)i * DD;
        const float* be2_i = be2 + (size_t)i * DD;
        const float* rot_i = rots + (size_t)i * DHH * NH * 32;

        cvt_k<<<(262144 / 4 + 255) / 256, 256, 0, stream>>>(Wqk_i, wq1, wq2, wq3, 262144 / 4);
        cvt_k<<<(262144 / 4 + 255) / 256, 256, 0, stream>>>(Wv_i, wvh, wvl, nullptr, 262144 / 4);
        cvt_k<<<(262144 / 4 + 255) / 256, 256, 0, stream>>>(Wout_i, woh, wol, nullptr, 262144 / 4);
        cvt_k<<<(1048576 / 4 + 255) / 256, 256, 0, stream>>>(W1_i, w1h, w1l, nullptr, 1048576 / 4);
        cvt_k<<<(1048576 / 4 + 255) / 256, 256, 0, stream>>>(W2_i, w2h, w2l, nullptr, 1048576 / 4);

        // qk = x @ Wqk^T  (bf16x6, fp32 for bucket + packed for attn)
        gemm_bf6_k<<<dim3(4, 128), 256, 0, stream>>>(xh, xl, xl2, DD, wq1, wq2, wq3,
                                                     qkb, qkp, MROWS, DD, DD);
        // v = x @ Wv^T  (bf16x3, 2-phase, packed output)
        gemm_bf3_k<<<dim3(4, 128), 256, 0, stream>>>(xh, xl, DD, wvh, wvl, DD,
                                                     nullptr, nullptr,
                                                     nullptr, nullptr, nullptr, vp,
                                                     MROWS, DD, DD, 0);
        bucket_k<<<dim3(16, BHH), 256, 0, stream>>>(qkb, rot_i, bkt);
        sort_k<<<dim3(NH, BHH), 256, 0, stream>>>(bkt, st);

        // attention in 4 strips of 8 bh; combine -> att hi/lo
        for (int s = 0; s < 4; s++) {
            attn_k<<<dim3(NC, 8), 256, 0, stream>>>(qkp, vp, st, obuf, lseb, s * 8);
            combine_k<<<8192, 256, 0, stream>>>(obuf, lseb, attb, s * 8);
        }

        // x = x + att @ Wout^T + bout ; emit x hi/lo (for FFN input)
        gemm_bf3_k<<<dim3(4, 128), 256, 0, stream>>>(attb, attb + 512, 1024, woh, wol, DD,
                                                     bout_i, x, x, xh, xl, nullptr,
                                                     MROWS, DD, DD, 0);
        // FFN: full-M, split DFFN into 2 column halves (h1 reuses qkp+obuf)
        for (int hf = 0; hf < 2; hf++) {
            const size_t wo = (size_t)hf * 1024;
            gemm_bf3_k<<<dim3(8, 128), 256, 0, stream>>>(xh, xl, DD,
                                                         w1h + wo * DD, w1l + wo * DD, DD,
                                                         b1_i + wo, nullptr,
                                                         nullptr, h1h, h1l, nullptr,
                                                         MROWS, 1024, DD, 1);
            gemm_bf3_k<<<dim3(4, 128), 256, 0, stream>>>(h1h, h1l, 1024,
                                                         w2h + wo, w2l + wo, DFFN,
                                                         hf == 0 ? b2_i : nullptr,
                                                         hf == 0 ? x : vb,
                                                         vb, nullptr, nullptr, nullptr,
                                                         MROWS, DD, 1024, 0);
        }
        // x = LN(yff); emit 3-way split for next layer's qk/v
        ln_k<<<MROWS, 64, 0, stream>>>(vb, g2_i, be2_i, x, xh, xl, xl2);
    }
    ln_k<<<MROWS, 64, 0, stream>>>(x, gf, bf, out, nullptr, nullptr, nullptr);
}

// Round 11
// 3080.670 us; speedup vs baseline: 1.0362x; 1.0362x over previous
//
#include <hip/hip_runtime.h>
#include <math.h>

#define TT    4096
#define DD    512
#define HH    8
#define DHH   64
#define NH    4
#define LLAY  4
#define DFFN  2048
#define BHH   32          // B*H
#define NC    256         // chunks per bh (NH*NB)
#define MROWS 16384       // B*T

typedef __attribute__((ext_vector_type(8))) short s16x8;
typedef __attribute__((ext_vector_type(4))) float f32x4;
typedef unsigned short ushort_t;

union U4 { unsigned u[4]; s16x8 v; };

__device__ __forceinline__ unsigned short f2bf(float f) {
    unsigned u = __float_as_uint(f);
    unsigned r = (u + 0x7FFFu + ((u >> 16) & 1u)) >> 16;
    return (unsigned short)r;
}
__device__ __forceinline__ float bf2f(unsigned short h) {
    return __uint_as_float(((unsigned)h) << 16);
}

// XCD-aware bijective swizzle (T1, m157): nwg must be divisible by 8.
__device__ __forceinline__ void xcd_swz(int& bx, int& by) {
    const int gx = gridDim.x;
    const int nwg = gx * gridDim.y;
    const int flat = by * gx + bx;
    const int q = nwg >> 3;
    const int swz = (flat & 7) * q + (flat >> 3);
    bx = swz % gx;
    by = swz / gx;
}

// ---------------------------------------------------------------------------
// bf16x3 MFMA GEMM, 2-phase double-buffered: C = op(A @ W^T + b)[+r]
// outputs: fp32 (outf) and/or hi/lo pair (outh,outl) and/or packed u32 (outp)
// ---------------------------------------------------------------------------
__global__ __launch_bounds__(256) void gemm_bf3_k(
    const ushort_t* __restrict__ Ah, const ushort_t* __restrict__ Al, int lda,
    const ushort_t* __restrict__ Wh, const ushort_t* __restrict__ Wl, int ldw,
    const float* __restrict__ bias, const float* __restrict__ resid,
    float* __restrict__ outf, ushort_t* __restrict__ outh, ushort_t* __restrict__ outl,
    unsigned* __restrict__ outp,
    int M, int N, int K, int relu)
{
    __shared__ __align__(16) ushort_t lds[2][4 * 128 * 32];   // 2 x 32KB
    const int tid  = threadIdx.x;
    const int lane = tid & 63;
    const int wv   = tid >> 6;
    const int wm   = wv >> 1, wn = wv & 1;
    int bx = blockIdx.x, by = blockIdx.y;
    xcd_swz(bx, by);
    const int row0 = by * 128, col0 = bx * 128;
    const int g    = lane >> 4;
    const int srow0 = wv * 32;

    f32x4 acc[4][4];
#pragma unroll
    for (int mi = 0; mi < 4; mi++)
#pragma unroll
        for (int ni = 0; ni < 4; ni++) acc[mi][ni] = (f32x4)(0.f);

    auto STAGE = [&](int buf, int k0) {
#pragma unroll
        for (int ii = 0; ii < 2; ii++) {
            const int r   = srow0 + ii * 16 + (lane >> 2);
            const int ug  = (((lane & 3) ^ ((r >> 1) & 3)) << 3);
            const size_t ga = (size_t)(row0 + r) * lda + k0 + ug;
            const size_t gw = (size_t)(col0 + r) * ldw + k0 + ug;
            const int lo  = (srow0 + ii * 16) * 32;
            __builtin_amdgcn_global_load_lds(
                (const __attribute__((address_space(1))) void*)(Ah + ga),
                (__attribute__((address_space(3))) void*)&lds[buf][0 * 4096 + lo], 16, 0, 0);
            __builtin_amdgcn_global_load_lds(
                (const __attribute__((address_space(1))) void*)(Al + ga),
                (__attribute__((address_space(3))) void*)&lds[buf][1 * 4096 + lo], 16, 0, 0);
            __builtin_amdgcn_global_load_lds(
                (const __attribute__((address_space(1))) void*)(Wh + gw),
                (__attribute__((address_space(3))) void*)&lds[buf][2 * 4096 + lo], 16, 0, 0);
            __builtin_amdgcn_global_load_lds(
                (const __attribute__((address_space(1))) void*)(Wl + gw),
                (__attribute__((address_space(3))) void*)&lds[buf][3 * 4096 + lo], 16, 0, 0);
        }
    };

    const int nt = K >> 5;
    STAGE(0, 0);

    for (int t = 0; t < nt; ++t) {
        const int cur = t & 1;
        if (t + 1 < nt) {
            STAGE(cur ^ 1, (t + 1) << 5);
            asm volatile("s_waitcnt vmcnt(8)" ::: "memory");
        } else {
            asm volatile("s_waitcnt vmcnt(0)" ::: "memory");
        }
        __builtin_amdgcn_s_barrier();
        __builtin_amdgcn_sched_barrier(0);

        s16x8 ah[4], al[4], wh[4], wl[4];
#pragma unroll
        for (int mi = 0; mi < 4; mi++) {
            const int m  = wm * 64 + mi * 16 + (lane & 15);
            const int pu = ((g ^ ((m >> 1) & 3)) << 3);
            ah[mi] = *(const s16x8*)&lds[cur][0 * 4096 + m * 32 + pu];
            al[mi] = *(const s16x8*)&lds[cur][1 * 4096 + m * 32 + pu];
            const int n  = wn * 64 + mi * 16 + (lane & 15);
            const int pn = ((g ^ ((n >> 1) & 3)) << 3);
            wh[mi] = *(const s16x8*)&lds[cur][2 * 4096 + n * 32 + pn];
            wl[mi] = *(const s16x8*)&lds[cur][3 * 4096 + n * 32 + pn];
        }
#pragma unroll
        for (int mi = 0; mi < 4; mi++)
#pragma unroll
            for (int ni = 0; ni < 4; ni++) {
                acc[mi][ni] = __builtin_amdgcn_mfma_f32_16x16x32_bf16(ah[mi], wh[ni], acc[mi][ni], 0, 0, 0);
                acc[mi][ni] = __builtin_amdgcn_mfma_f32_16x16x32_bf16(al[mi], wh[ni], acc[mi][ni], 0, 0, 0);
                acc[mi][ni] = __builtin_amdgcn_mfma_f32_16x16x32_bf16(ah[mi], wl[ni], acc[mi][ni], 0, 0, 0);
            }

        __builtin_amdgcn_sched_barrier(0);
        __builtin_amdgcn_s_barrier();     // WAR: lds[cur] overwritten at t+1's STAGE
    }

#pragma unroll
    for (int mi = 0; mi < 4; mi++) {
#pragma unroll
        for (int ni = 0; ni < 4; ni++) {
#pragma unroll
            for (int r = 0; r < 4; r++) {
                const int row = row0 + wm * 64 + mi * 16 + g * 4 + r;
                const int col = col0 + wn * 64 + ni * 16 + (lane & 15);
                float v = acc[mi][ni][r];
                if (bias)  v += bias[col];
                if (relu)  v = fmaxf(v, 0.f);
                if (resid) v += resid[(size_t)row * N + col];
                if (outf)  outf[(size_t)row * N + col] = v;
                if (outh) {
                    unsigned short h = f2bf(v);
                    outh[(size_t)row * N + col] = h;
                    outl[(size_t)row * N + col] = f2bf(v - bf2f(h));
                }
                if (outp) {
                    unsigned short h = f2bf(v);
                    outp[(size_t)row * N + col] =
                        (unsigned)h | ((unsigned)f2bf(v - bf2f(h)) << 16);
                }
            }
        }
    }
}

// ---------------------------------------------------------------------------
// bf16x6 MFMA GEMM (qk only): ~2^-26 rel err. Emits fp32 + packed hi/lo.
// ---------------------------------------------------------------------------
__global__ __launch_bounds__(256) void gemm_bf6_k(
    const ushort_t* __restrict__ A1, const ushort_t* __restrict__ A2,
    const ushort_t* __restrict__ A3, int lda,
    const ushort_t* __restrict__ W1, const ushort_t* __restrict__ W2,
    const ushort_t* __restrict__ W3,
    float* __restrict__ outf, unsigned* __restrict__ outp, int M, int N, int K)
{
    __shared__ __align__(16) ushort_t lds[6 * 128 * 32];   // A1,A2,A3,W1,W2,W3
    const int tid  = threadIdx.x;
    const int lane = tid & 63;
    const int wv   = tid >> 6;
    const int wm   = wv >> 1, wn = wv & 1;
    int bx = blockIdx.x, by = blockIdx.y;
    xcd_swz(bx, by);
    const int row0 = by * 128, col0 = bx * 128;
    const int g    = lane >> 4;

    f32x4 acc[4][4];
#pragma unroll
    for (int mi = 0; mi < 4; mi++)
#pragma unroll
        for (int ni = 0; ni < 4; ni++) acc[mi][ni] = (f32x4)(0.f);

    const int srow0 = wv * 32;

    for (int k0 = 0; k0 < K; k0 += 32) {
        __syncthreads();
#pragma unroll
        for (int ii = 0; ii < 2; ii++) {
            const int r   = srow0 + ii * 16 + (lane >> 2);
            const int ug  = (((lane & 3) ^ ((r >> 1) & 3)) << 3);
            const size_t ga = (size_t)(row0 + r) * lda + k0 + ug;
            const size_t gw = (size_t)(col0 + r) * K   + k0 + ug;
            const int lo  = (srow0 + ii * 16) * 32;
            __builtin_amdgcn_global_load_lds(
                (const __attribute__((address_space(1))) void*)(A1 + ga),
                (__attribute__((address_space(3))) void*)&lds[0 * 4096 + lo], 16, 0, 0);
            __builtin_amdgcn_global_load_lds(
                (const __attribute__((address_space(1))) void*)(A2 + ga),
                (__attribute__((address_space(3))) void*)&lds[1 * 4096 + lo], 16, 0, 0);
            __builtin_amdgcn_global_load_lds(
                (const __attribute__((address_space(1))) void*)(A3 + ga),
                (__attribute__((address_space(3))) void*)&lds[2 * 4096 + lo], 16, 0, 0);
            __builtin_amdgcn_global_load_lds(
                (const __attribute__((address_space(1))) void*)(W1 + gw),
                (__attribute__((address_space(3))) void*)&lds[3 * 4096 + lo], 16, 0, 0);
            __builtin_amdgcn_global_load_lds(
                (const __attribute__((address_space(1))) void*)(W2 + gw),
                (__attribute__((address_space(3))) void*)&lds[4 * 4096 + lo], 16, 0, 0);
            __builtin_amdgcn_global_load_lds(
                (const __attribute__((address_space(1))) void*)(W3 + gw),
                (__attribute__((address_space(3))) void*)&lds[5 * 4096 + lo], 16, 0, 0);
        }
        __syncthreads();

        s16x8 a1[4], a2[4], a3[4], w1[4], w2[4], w3[4];
#pragma unroll
        for (int mi = 0; mi < 4; mi++) {
            const int m  = wm * 64 + mi * 16 + (lane & 15);
            const int pu = ((g ^ ((m >> 1) & 3)) << 3);
            a1[mi] = *(const s16x8*)&lds[0 * 4096 + m * 32 + pu];
            a2[mi] = *(const s16x8*)&lds[1 * 4096 + m * 32 + pu];
            a3[mi] = *(const s16x8*)&lds[2 * 4096 + m * 32 + pu];
            const int n  = wn * 64 + mi * 16 + (lane & 15);
            const int pn = ((g ^ ((n >> 1) & 3)) << 3);
            w1[mi] = *(const s16x8*)&lds[3 * 4096 + n * 32 + pn];
            w2[mi] = *(const s16x8*)&lds[4 * 4096 + n * 32 + pn];
            w3[mi] = *(const s16x8*)&lds[5 * 4096 + n * 32 + pn];
        }
#pragma unroll
        for (int mi = 0; mi < 4; mi++)
#pragma unroll
            for (int ni = 0; ni < 4; ni++) {
                acc[mi][ni] = __builtin_amdgcn_mfma_f32_16x16x32_bf16(a1[mi], w1[ni], acc[mi][ni], 0, 0, 0);
                acc[mi][ni] = __builtin_amdgcn_mfma_f32_16x16x32_bf16(a2[mi], w1[ni], acc[mi][ni], 0, 0, 0);
                acc[mi][ni] = __builtin_amdgcn_mfma_f32_16x16x32_bf16(a1[mi], w2[ni], acc[mi][ni], 0, 0, 0);
                acc[mi][ni] = __builtin_amdgcn_mfma_f32_16x16x32_bf16(a2[mi], w2[ni], acc[mi][ni], 0, 0, 0);
                acc[mi][ni] = __builtin_amdgcn_mfma_f32_16x16x32_bf16(a1[mi], w3[ni], acc[mi][ni], 0, 0, 0);
                acc[mi][ni] = __builtin_amdgcn_mfma_f32_16x16x32_bf16(a3[mi], w1[ni], acc[mi][ni], 0, 0, 0);
            }
    }

#pragma unroll
    for (int mi = 0; mi < 4; mi++) {
#pragma unroll
        for (int ni = 0; ni < 4; ni++) {
#pragma unroll
            for (int r = 0; r < 4; r++) {
                const int row = row0 + wm * 64 + mi * 16 + g * 4 + r;
                const int col = col0 + wn * 64 + ni * 16 + (lane & 15);
                float v = acc[mi][ni][r];
                outf[(size_t)row * N + col] = v;
                unsigned short h = f2bf(v);
                outp[(size_t)row * N + col] =
                    (unsigned)h | ((unsigned)f2bf(v - bf2f(h)) << 16);
            }
        }
    }
}

// ---------------------------------------------------------------------------
// fp32 -> bf16 split converter
// ---------------------------------------------------------------------------
__global__ __launch_bounds__(256) void cvt_k(
    const float* __restrict__ in, ushort_t* __restrict__ o1,
    ushort_t* __restrict__ o2, ushort_t* __restrict__ o3, int n4)
{
    int i = blockIdx.x * 256 + threadIdx.x;
    if (i >= n4) return;
    float4 v = ((const float4*)in)[i];
    float vv[4] = {v.x, v.y, v.z, v.w};
    union { unsigned short us[4]; ushort4 v4; } H, L, M;
#pragma unroll
    for (int q = 0; q < 4; q++) {
        unsigned short a = f2bf(vv[q]);
        float r1 = vv[q] - bf2f(a);
        unsigned short b = f2bf(r1);
        H.us[q] = a; L.us[q] = b;
        M.us[q] = f2bf(r1 - bf2f(b));
    }
    ((ushort4*)o1)[i] = H.v4;
    ((ushort4*)o2)[i] = L.v4;
    if (o3) ((ushort4*)o3)[i] = M.v4;
}

// ---------------------------------------------------------------------------
// Bucket kernel v2 (all 4 rounds per block) — reads fp32 qk
// ---------------------------------------------------------------------------
__global__ __launch_bounds__(256) void bucket_k(
    const float* __restrict__ qk, const float* __restrict__ rot,
    int* __restrict__ bkt)
{
    __shared__ float rs[NH][64][32];    // 32 KB
    const int bh = blockIdx.y;
    const int t = blockIdx.x * 256 + threadIdx.x;
    for (int i = threadIdx.x; i < NH * 64 * 32; i += 256) {
        int r = i >> 11, f = (i >> 5) & 63, j = i & 31;
        rs[r][f][j] = rot[(f * NH + r) * 32 + j];
    }
    __syncthreads();
    const int b = bh >> 3, h = bh & 7;
    const float* q = qk + ((size_t)(b * TT + t)) * DD + h * DHH;
    float qv[64];
#pragma unroll
    for (int f4 = 0; f4 < 16; f4++) {
        float4 tmp = ((const float4*)q)[f4];
        qv[f4 * 4 + 0] = tmp.x; qv[f4 * 4 + 1] = tmp.y;
        qv[f4 * 4 + 2] = tmp.z; qv[f4 * 4 + 3] = tmp.w;
    }
    for (int r = 0; r < NH; r++) {
        float rv[32];
#pragma unroll
        for (int j = 0; j < 32; j++) rv[j] = 0.f;
        for (int f = 0; f < 64; f++) {
            float qf = qv[f];
#pragma unroll
            for (int j = 0; j < 32; j++) rv[j] = fmaf(qf, rs[r][f][j], rv[j]);
        }
        float best = rv[0];
        int bi = 0;
#pragma unroll
        for (int j = 1; j < 32; j++) { if (rv[j] > best) { best = rv[j]; bi = j; } }
#pragma unroll
        for (int j = 0; j < 32; j++) { float v = -rv[j]; if (v > best) { best = v; bi = 32 + j; } }
        bkt[((size_t)bh * NH + r) * TT + t] = bi;
    }
}

// ---------------------------------------------------------------------------
// Parallel stable counting sort per (bh, round). (verified R4)
// ---------------------------------------------------------------------------
__global__ __launch_bounds__(256) void sort_k(
    const int* __restrict__ bkt, int* __restrict__ st)
{
    __shared__ int lb[TT];
    __shared__ unsigned short cnt[128][64];
    __shared__ int base[64];
    const int r = blockIdx.x, bh = blockIdx.y;
    const int tid = threadIdx.x;
    const int* src = bkt + ((size_t)bh * NH + r) * TT;

    const int4* s4 = (const int4*)src;
    int4* l4 = (int4*)lb;
#pragma unroll
    for (int q = 0; q < 4; q++) l4[tid + q * 256] = s4[tid + q * 256];
    unsigned* cz = (unsigned*)cnt;
#pragma unroll
    for (int q = 0; q < 16; q++) cz[tid + q * 256] = 0;
    __syncthreads();

    if (tid < 128) {
        for (int it = 0; it < 32; it++) {
            int bb = lb[tid * 32 + it];
            cnt[tid][bb]++;
        }
    }
    __syncthreads();

    if (tid < 64) {
        const int bb = tid;
        int run = 0;
        for (int s = 0; s < 128; s++) {
            int t = cnt[s][bb];
            cnt[s][bb] = (unsigned short)run;
            run += t;
        }
        int inc = run;
#pragma unroll
        for (int off = 1; off < 64; off <<= 1) {
            int n = __shfl_up(inc, off, 64);
            if (tid >= off) inc += n;
        }
        base[bb] = inc - run;
    }
    __syncthreads();

    if (tid < 128) {
        int* dst = st + (size_t)bh * (NH * TT) + (size_t)r * TT;
        for (int it = 0; it < 32; it++) {
            int t = tid * 32 + it;
            int bb = lb[t];
            int pos = base[bb] + (int)cnt[tid][bb];
            cnt[tid][bb]++;
            dst[pos] = t;
        }
    }
}

// ---------------------------------------------------------------------------
// Attention v5: inputs pre-packed as u32 (hi | lo<<16) per element.
// Staging: V copied verbatim to LDS; K unpacked to hi/lo words.
// Strip of 8 bh.
// ---------------------------------------------------------------------------
__global__ __launch_bounds__(256, 2) void attn_k(
    const unsigned* __restrict__ qkp, const unsigned* __restrict__ vp,
    const int* __restrict__ st, float* __restrict__ obuf,
    float* __restrict__ lseb, int bh0)
{
    __shared__ __align__(16) ushort_t ksh[128 * 72];
    __shared__ __align__(16) ushort_t ksl[128 * 72];
    __shared__ __align__(16) unsigned vsp[128 * 66];
    __shared__ float invn[128];
    __shared__ int   tks[128];

    const int c   = blockIdx.x;
    const int bhl = blockIdx.y;
    const int bh  = bh0 + bhl;
    const int b   = bh >> 3, h = bh & 7;
    const int tid = threadIdx.x;
    const int* stb = st + (size_t)bh * (NH * TT);

    if (tid < 128) {
        int cc = (tid < 64) ? c : ((c + NC - 1) & (NC - 1));
        tks[tid] = stb[cc * 64 + (tid & 63)];
    }
    __syncthreads();

    {   // stage K (unpack hi/lo) + V (verbatim) + inv k-norms
        const int row = tid >> 1, c0 = (tid & 1) * 32;
        const int t = tks[row];
        const uint4* kg = (const uint4*)(qkp + ((size_t)(b * TT + t)) * DD + h * DHH + c0);
        const uint4* vg = (const uint4*)(vp  + ((size_t)(b * TT + t)) * DD + h * DHH + c0);
        unsigned kp[32];
        uint4 vq[8];
        float ss = 0.f;
#pragma unroll
        for (int q = 0; q < 8; q++) {
            uint4 kq = kg[q];
            kp[4 * q + 0] = kq.x; kp[4 * q + 1] = kq.y;
            kp[4 * q + 2] = kq.z; kp[4 * q + 3] = kq.w;
            vq[q] = vg[q];
        }
#pragma unroll
        for (int e = 0; e < 32; e++) {
            float f = __uint_as_float(kp[e] << 16) + __uint_as_float(kp[e] & 0xffff0000u);
            ss = fmaf(f, f, ss);
        }
        ss += __shfl_xor(ss, 1);
        if ((tid & 1) == 0) invn[row] = 1.0f / fmaxf(sqrtf(ss), 1e-12f);

        unsigned hw[16], lw[16];
#pragma unroll
        for (int e = 0; e < 16; e++) {
            hw[e] = (kp[2 * e] & 0xffffu) | (kp[2 * e + 1] << 16);
            lw[e] = (kp[2 * e] >> 16) | (kp[2 * e + 1] & 0xffff0000u);
        }
        uint4* kdh = (uint4*)&ksh[row * 72 + c0];
        uint4* kdl = (uint4*)&ksl[row * 72 + c0];
#pragma unroll
        for (int q = 0; q < 4; q++) {
            kdh[q] = make_uint4(hw[4 * q], hw[4 * q + 1], hw[4 * q + 2], hw[4 * q + 3]);
            kdl[q] = make_uint4(lw[4 * q], lw[4 * q + 1], lw[4 * q + 2], lw[4 * q + 3]);
        }
        uint2* vd = (uint2*)&vsp[row * 66 + c0];
#pragma unroll
        for (int q = 0; q < 8; q++) {
            vd[2 * q]     = make_uint2(vq[q].x, vq[q].y);
            vd[2 * q + 1] = make_uint2(vq[q].z, vq[q].w);
        }
    }
    __syncthreads();

    const int lane = tid & 63;
    const int wv   = tid >> 6;
    const int cc16 = lane & 15;
    const int g    = lane >> 4;
    const int rr   = c >> 6;

    f32x4 stt[8];
#pragma unroll
    for (int jt = 0; jt < 8; jt++) stt[jt] = (f32x4)(0.f);

    const int qrow = wv * 16 + cc16;
#pragma unroll
    for (int ks = 0; ks < 2; ks++) {
        s16x8 qh = *(const s16x8*)&ksh[qrow * 72 + ks * 32 + g * 8];
        s16x8 ql = *(const s16x8*)&ksl[qrow * 72 + ks * 32 + g * 8];
#pragma unroll
        for (int jt = 0; jt < 8; jt++) {
            const int krow = jt * 16 + cc16;
            s16x8 ah = *(const s16x8*)&ksh[krow * 72 + ks * 32 + g * 8];
            s16x8 al = *(const s16x8*)&ksl[krow * 72 + ks * 32 + g * 8];
            stt[jt] = __builtin_amdgcn_mfma_f32_16x16x32_bf16(ah, qh, stt[jt], 0, 0, 0);
            stt[jt] = __builtin_amdgcn_mfma_f32_16x16x32_bf16(al, qh, stt[jt], 0, 0, 0);
            stt[jt] = __builtin_amdgcn_mfma_f32_16x16x32_bf16(ah, ql, stt[jt], 0, 0, 0);
        }
    }

    const int tqi = tks[wv * 16 + cc16];
    float m = -INFINITY;
#pragma unroll
    for (int jt = 0; jt < 8; jt++) {
#pragma unroll
        for (int r4 = 0; r4 < 4; r4++) {
            const int j = jt * 16 + g * 4 + r4;
            float d = stt[jt][r4] * invn[j] * 0.125f;
            if (tqi == tks[j]) d = -5e4f;
            stt[jt][r4] = d;
            m = fmaxf(m, d);
        }
    }
    m = fmaxf(m, __shfl_xor(m, 16));
    m = fmaxf(m, __shfl_xor(m, 32));
    float s = 0.f;
#pragma unroll
    for (int jt = 0; jt < 8; jt++) {
#pragma unroll
        for (int r4 = 0; r4 < 4; r4++) {
            float e = expf(stt[jt][r4] - m);
            stt[jt][r4] = e;
            s += e;
        }
    }
    s += __shfl_xor(s, 16);
    s += __shfl_xor(s, 32);
    const float is = 1.0f / s;
    if (g == 0) lseb[((size_t)bh * NH + rr) * TT + tqi] = m + logf(s);

    unsigned ph[8][2], pl[8][2];
#pragma unroll
    for (int jt = 0; jt < 8; jt++) {
#pragma unroll
        for (int w2 = 0; w2 < 2; w2++) {
            float p0 = stt[jt][2 * w2] * is;
            float p1 = stt[jt][2 * w2 + 1] * is;
            unsigned short h0 = f2bf(p0), h1 = f2bf(p1);
            ph[jt][w2] = (unsigned)h0 | ((unsigned)h1 << 16);
            pl[jt][w2] = (unsigned)f2bf(p0 - bf2f(h0)) | ((unsigned)f2bf(p1 - bf2f(h1)) << 16);
        }
    }

    f32x4 occ[4];
#pragma unroll
    for (int nt = 0; nt < 4; nt++) occ[nt] = (f32x4)(0.f);

    const int srcLow  = ((g & 1) << 5) + cc16;
    const int srcHigh = srcLow + 16;
    const bool hiT = (lane & 32) != 0;

#pragma unroll
    for (int ks = 0; ks < 4; ks++) {
        U4 Phi, Plo;
        {
            unsigned a0 = (unsigned)__shfl((int)ph[2 * ks][0], srcLow);
            unsigned a1 = (unsigned)__shfl((int)ph[2 * ks][1], srcLow);
            unsigned a2 = (unsigned)__shfl((int)ph[2 * ks][0], srcHigh);
            unsigned a3 = (unsigned)__shfl((int)ph[2 * ks][1], srcHigh);
            unsigned b0 = (unsigned)__shfl((int)ph[2 * ks + 1][0], srcLow);
            unsigned b1 = (unsigned)__shfl((int)ph[2 * ks + 1][1], srcLow);
            unsigned b2 = (unsigned)__shfl((int)ph[2 * ks + 1][0], srcHigh);
            unsigned b3 = (unsigned)__shfl((int)ph[2 * ks + 1][1], srcHigh);
            Phi.u[0] = hiT ? b0 : a0; Phi.u[1] = hiT ? b1 : a1;
            Phi.u[2] = hiT ? b2 : a2; Phi.u[3] = hiT ? b3 : a3;
            unsigned c0 = (unsigned)__shfl((int)pl[2 * ks][0], srcLow);
            unsigned c1 = (unsigned)__shfl((int)pl[2 * ks][1], srcLow);
            unsigned c2 = (unsigned)__shfl((int)pl[2 * ks][0], srcHigh);
            unsigned c3 = (unsigned)__shfl((int)pl[2 * ks][1], srcHigh);
            unsigned d0 = (unsigned)__shfl((int)pl[2 * ks + 1][0], srcLow);
            unsigned d1 = (unsigned)__shfl((int)pl[2 * ks + 1][1], srcLow);
            unsigned d2 = (unsigned)__shfl((int)pl[2 * ks + 1][0], srcHigh);
            unsigned d3 = (unsigned)__shfl((int)pl[2 * ks + 1][1], srcHigh);
            Plo.u[0] = hiT ? d0 : c0; Plo.u[1] = hiT ? d1 : c1;
            Plo.u[2] = hiT ? d2 : c2; Plo.u[3] = hiT ? d3 : c3;
        }
#pragma unroll
        for (int nt = 0; nt < 4; nt++) {
            unsigned u[8];
#pragma unroll
            for (int e = 0; e < 8; e++)
                u[e] = vsp[(32 * ks + 8 * g + e) * 66 + nt * 16 + cc16];
            U4 Vh, Vl;
#pragma unroll
            for (int m2 = 0; m2 < 4; m2++) {
                Vh.u[m2] = (u[2 * m2] & 0xffffu) | (u[2 * m2 + 1] << 16);
                Vl.u[m2] = (u[2 * m2] >> 16) | (u[2 * m2 + 1] & 0xffff0000u);
            }
            occ[nt] = __builtin_amdgcn_mfma_f32_16x16x32_bf16(Phi.v, Vh.v, occ[nt], 0, 0, 0);
            occ[nt] = __builtin_amdgcn_mfma_f32_16x16x32_bf16(Plo.v, Vh.v, occ[nt], 0, 0, 0);
            occ[nt] = __builtin_amdgcn_mfma_f32_16x16x32_bf16(Phi.v, Vl.v, occ[nt], 0, 0, 0);
        }
    }

#pragma unroll
    for (int r4 = 0; r4 < 4; r4++) {
        const int i = wv * 16 + g * 4 + r4;
        const int ti = tks[i];
        float* dst = obuf + (((size_t)bhl * NH + rr) * TT + ti) * DHH + cc16;
        dst[0]  = occ[0][r4];
        dst[16] = occ[1][r4];
        dst[32] = occ[2][r4];
        dst[48] = occ[3][r4];
    }
}

// ---------------------------------------------------------------------------
// Combine rounds for an 8-bh strip
// ---------------------------------------------------------------------------
__global__ __launch_bounds__(256) void combine_k(
    const float* __restrict__ obuf, const float* __restrict__ lseb,
    ushort_t* __restrict__ att, int bh0)
{
    int idx = blockIdx.x * 256 + threadIdx.x;
    int d = idx & 63;
    int t = (idx >> 6) & (TT - 1);
    int bhl = idx >> 18;
    int bh = bh0 + bhl;
    float l0 = lseb[((size_t)bh * NH + 0) * TT + t];
    float l1 = lseb[((size_t)bh * NH + 1) * TT + t];
    float l2 = lseb[((size_t)bh * NH + 2) * TT + t];
    float l3 = lseb[((size_t)bh * NH + 3) * TT + t];
    float m = fmaxf(fmaxf(l0, l1), fmaxf(l2, l3));
    float e0 = expf(l0 - m), e1 = expf(l1 - m), e2 = expf(l2 - m), e3 = expf(l3 - m);
    float inv = 1.0f / (e0 + e1 + e2 + e3);
    float o0 = obuf[(((size_t)bhl * NH + 0) * TT + t) * DHH + d];
    float o1 = obuf[(((size_t)bhl * NH + 1) * TT + t) * DHH + d];
    float o2 = obuf[(((size_t)bhl * NH + 2) * TT + t) * DHH + d];
    float o3 = obuf[(((size_t)bhl * NH + 3) * TT + t) * DHH + d];
    float o = (e0 * o0 + e1 * o1 + e2 * o2 + e3 * o3) * inv;
    int b = bh >> 3, h = bh & 7;
    size_t base = (size_t)(b * TT + t) * 1024 + h * DHH + d;
    unsigned short hi = f2bf(o);
    att[base]       = hi;
    att[base + 512] = f2bf(o - bf2f(hi));
}

// ---------------------------------------------------------------------------
// LayerNorm over D=512; optional 3-way bf16 split output. Safe in-place.
// ---------------------------------------------------------------------------
__global__ __launch_bounds__(64) void ln_k(
    const float* __restrict__ in, const float* __restrict__ g,
    const float* __restrict__ be, float* __restrict__ out,
    ushort_t* __restrict__ oh, ushort_t* __restrict__ ol,
    ushort_t* __restrict__ ol2)
{
    const int row = blockIdx.x;
    const int tid = threadIdx.x;
    const float* x = in + (size_t)row * DD;
    float4 a = *(const float4*)(x + tid * 8);
    float4 b = *(const float4*)(x + tid * 8 + 4);
    float s = a.x + a.y + a.z + a.w + b.x + b.y + b.z + b.w;
#pragma unroll
    for (int o = 32; o >= 1; o >>= 1) s += __shfl_xor(s, o, 64);
    float mean = s * (1.0f / 512.0f);
    float dx[8];
    dx[0] = a.x - mean; dx[1] = a.y - mean; dx[2] = a.z - mean; dx[3] = a.w - mean;
    dx[4] = b.x - mean; dx[5] = b.y - mean; dx[6] = b.z - mean; dx[7] = b.w - mean;
    float ss = 0.f;
#pragma unroll
    for (int q = 0; q < 8; q++) ss += dx[q] * dx[q];
#pragma unroll
    for (int o = 32; o >= 1; o >>= 1) ss += __shfl_xor(ss, o, 64);
    float var = ss * (1.0f / 512.0f);
    float inv = 1.0f / sqrtf(var + 1e-6f);
    const float* gp = g + tid * 8;
    const float* bp = be + tid * 8;
    float y[8];
#pragma unroll
    for (int q = 0; q < 8; q++) y[q] = dx[q] * inv * gp[q] + bp[q];
    float* yp = out + (size_t)row * DD + tid * 8;
    *(float4*)(yp)     = make_float4(y[0], y[1], y[2], y[3]);
    *(float4*)(yp + 4) = make_float4(y[4], y[5], y[6], y[7]);
    if (oh) {
        union { unsigned short us[8]; ushort4 v4[2]; } H, L, M;
#pragma unroll
        for (int q = 0; q < 8; q++) {
            unsigned short h = f2bf(y[q]);
            float r1 = y[q] - bf2f(h);
            unsigned short l = f2bf(r1);
            H.us[q] = h; L.us[q] = l;
            M.us[q] = f2bf(r1 - bf2f(l));
        }
        size_t e = (size_t)row * DD + tid * 8;
        *(ushort4*)(oh + e)      = H.v4[0];
        *(ushort4*)(oh + e + 4)  = H.v4[1];
        *(ushort4*)(ol + e)      = L.v4[0];
        *(ushort4*)(ol + e + 4)  = L.v4[1];
        *(ushort4*)(ol2 + e)     = M.v4[0];
        *(ushort4*)(ol2 + e + 4) = M.v4[1];
    }
}

// ---------------------------------------------------------------------------
extern "C" void kernel_launch(void* const* d_in, const int* in_sizes, int n_in,
                              void* d_out, int out_size, void* d_ws, size_t ws_size,
                              hipStream_t stream)
{
    const float* src  = (const float*)d_in[0];
    const float* rots = (const float*)d_in[1];
    const float* Wqk  = (const float*)d_in[2];
    const float* Wv   = (const float*)d_in[3];
    const float* Wout = (const float*)d_in[4];
    const float* bout = (const float*)d_in[5];
    const float* W1   = (const float*)d_in[6];
    const float* b1   = (const float*)d_in[7];
    const float* W2   = (const float*)d_in[8];
    const float* b2   = (const float*)d_in[9];
    const float* g2   = (const float*)d_in[10];
    const float* be2  = (const float*)d_in[11];
    const float* gf   = (const float*)d_in[12];
    const float* bf   = (const float*)d_in[13];
    float* out = (float*)d_out;

    // ---- workspace layout (~234 MB) ----
    // During attn: p+0 dead(qkb), p+1 vp, p+2 qkp, p+3 obuf.
    // During FFN:  p+0..p+2 = h1h (67MB), p+2..p+4 = h1l (67MB); yff in-place on x.
    char* w = (char*)d_ws;
    const size_t SZ_X = (size_t)MROWS * DD * 4;               // 33.55 MB
    const size_t XHALF = (size_t)MROWS * DD;
    float*    x     = (float*)(w);
    ushort_t* xs    = (ushort_t*)(w + SZ_X);
    ushort_t* xh    = xs;
    ushort_t* xl    = xs + XHALF;
    ushort_t* xl2   = xs + 2 * XHALF;
    char*     p     = w + SZ_X + 3 * XHALF * 2;
    float*    qkb   = (float*)(p);
    ushort_t* attb  = (ushort_t*)(p);
    unsigned* vp    = (unsigned*)(p + SZ_X);
    unsigned* qkp   = (unsigned*)(p + 2 * SZ_X);
    float*    obuf  = (float*)(p + 3 * SZ_X);
    ushort_t* h1h   = (ushort_t*)(p);                         // FFN: spans p..p+2SZ_X
    ushort_t* h1l   = (ushort_t*)(p + 2 * SZ_X);              // FFN: spans p+2..p+4SZ_X
    ushort_t* wb    = (ushort_t*)(p + 4 * SZ_X);
    char*     tail  = p + 4 * SZ_X + 6029312 * 2;
    int*      bkt   = (int*)(tail);
    int*      st    = (int*)(tail + (size_t)BHH * NH * TT * 4);
    float*    lseb  = (float*)(tail + 2 * (size_t)BHH * NH * TT * 4);

    ushort_t* wvh = wb;            ushort_t* wvl = wb + 262144;
    ushort_t* woh = wb + 524288;   ushort_t* wol = wb + 786432;
    ushort_t* w1h = wb + 1048576;  ushort_t* w1l = wb + 2097152;
    ushort_t* w2h = wb + 3145728;  ushort_t* w2l = wb + 4194304;
    ushort_t* wq1 = wb + 5242880;  ushort_t* wq2 = wb + 5505024;
    ushort_t* wq3 = wb + 5767168;

    hipMemcpyAsync(x, src, SZ_X, hipMemcpyDeviceToDevice, stream);
    cvt_k<<<(MROWS * DD / 4 + 255) / 256, 256, 0, stream>>>(src, xh, xl, xl2, MROWS * DD / 4);

    for (int i = 0; i < LLAY; i++) {
        const float* Wqk_i = Wqk + (size_t)i * DD * DD;
        const float* Wv_i  = Wv  + (size_t)i * DD * DD;
        const float* Wout_i= Wout+ (size_t)i * DD * DD;
        const float* bout_i= bout+ (size_t)i * DD;
        const float* W1_i  = W1  + (size_t)i * DFFN * DD;
        const float* b1_i  = b1  + (size_t)i * DFFN;
        const float* W2_i  = W2  + (size_t)i * DD * DFFN;
        const float* b2_i  = b2  + (size_t)i * DD;
        const float* g2_i  = g2  + (size_t)i * DD;
        const float* be2_i = be2 + (size_t)i * DD;
        const float* rot_i = rots + (size_t)i * DHH * NH * 32;

        cvt_k<<<(262144 / 4 + 255) / 256, 256, 0, stream>>>(Wqk_i, wq1, wq2, wq3, 262144 / 4);
        cvt_k<<<(262144 / 4 + 255) / 256, 256, 0, stream>>>(Wv_i, wvh, wvl, nullptr, 262144 / 4);
        cvt_k<<<(262144 / 4 + 255) / 256, 256, 0, stream>>>(Wout_i, woh, wol, nullptr, 262144 / 4);
        cvt_k<<<(1048576 / 4 + 255) / 256, 256, 0, stream>>>(W1_i, w1h, w1l, nullptr, 1048576 / 4);
        cvt_k<<<(1048576 / 4 + 255) / 256, 256, 0, stream>>>(W2_i, w2h, w2l, nullptr, 1048576 / 4);

        // qk = x @ Wqk^T  (bf16x6, fp32 for bucket + packed for attn)
        gemm_bf6_k<<<dim3(4, 128), 256, 0, stream>>>(xh, xl, xl2, DD, wq1, wq2, wq3,
                                                     qkb, qkp, MROWS, DD, DD);
        // v = x @ Wv^T  (bf16x3, 2-phase, packed output)
        gemm_bf3_k<<<dim3(4, 128), 256, 0, stream>>>(xh, xl, DD, wvh, wvl, DD,
                                                     nullptr, nullptr,
                                                     nullptr, nullptr, nullptr, vp,
                                                     MROWS, DD, DD, 0);
        bucket_k<<<dim3(16, BHH), 256, 0, stream>>>(qkb, rot_i, bkt);
        sort_k<<<dim3(NH, BHH), 256, 0, stream>>>(bkt, st);

        // attention in 4 strips of 8 bh; combine -> att hi/lo
        for (int s = 0; s < 4; s++) {
            attn_k<<<dim3(NC, 8), 256, 0, stream>>>(qkp, vp, st, obuf, lseb, s * 8);
            combine_k<<<8192, 256, 0, stream>>>(obuf, lseb, attb, s * 8);
        }

        // x = x + att @ Wout^T + bout ; emit x hi/lo (for FFN input)
        gemm_bf3_k<<<dim3(4, 128), 256, 0, stream>>>(attb, attb + 512, 1024, woh, wol, DD,
                                                     bout_i, x, x, xh, xl, nullptr,
                                                     MROWS, DD, DD, 0);
        // FFN1 full-N: h1 = relu(x @ W1^T + b1)  (one launch, 2048 blocks)
        gemm_bf3_k<<<dim3(16, 128), 256, 0, stream>>>(xh, xl, DD, w1h, w1l, DD,
                                                      b1_i, nullptr,
                                                      nullptr, h1h, h1l, nullptr,
                                                      MROWS, DFFN, DD, 1);
        // FFN2 full-K: x = x + h1 @ W2^T + b2  (in-place residual on x)
        gemm_bf3_k<<<dim3(4, 128), 256, 0, stream>>>(h1h, h1l, DFFN, w2h, w2l, DFFN,
                                                     b2_i, x,
                                                     x, nullptr, nullptr, nullptr,
                                                     MROWS, DD, DFFN, 0);
        // x = LN(x) in-place; emit 3-way split for next layer's qk/v
        ln_k<<<MROWS, 64, 0, stream>>>(x, g2_i, be2_i, x, xh, xl, xl2);
    }
    ln_k<<<MROWS, 64, 0, stream>>>(x, gf, bf, out, nullptr, nullptr, nullptr);
}

// Round 12
// 3037.566 us; speedup vs baseline: 1.0510x; 1.0142x over previous
//
#include <hip/hip_runtime.h>
#include <math.h>

#define TT    4096
#define DD    512
#define HH    8
#define DHH   64
#define NH    4
#define LLAY  4
#define DFFN  2048
#define BHH   32          // B*H
#define NC    256         // chunks per bh (NH*NB)
#define MROWS 16384       // B*T

typedef __attribute__((ext_vector_type(8))) short s16x8;
typedef __attribute__((ext_vector_type(4))) float f32x4;
typedef unsigned short ushort_t;

union U4 { unsigned u[4]; s16x8 v; };

__device__ __forceinline__ unsigned short f2bf(float f) {
    unsigned u = __float_as_uint(f);
    unsigned r = (u + 0x7FFFu + ((u >> 16) & 1u)) >> 16;
    return (unsigned short)r;
}
__device__ __forceinline__ float bf2f(unsigned short h) {
    return __uint_as_float(((unsigned)h) << 16);
}

// XCD-aware bijective swizzle (T1, m157): nwg must be divisible by 8.
__device__ __forceinline__ void xcd_swz(int& bx, int& by) {
    const int gx = gridDim.x;
    const int nwg = gx * gridDim.y;
    const int flat = by * gx + bx;
    const int q = nwg >> 3;
    const int swz = (flat & 7) * q + (flat >> 3);
    bx = swz % gx;
    by = swz / gx;
}

// ---------------------------------------------------------------------------
// bf16x3 MFMA GEMM, 2-phase double-buffered: C = op(A @ W^T + b)[+r]
// outputs: fp32 (outf) and/or hi/lo pair (outh,outl) and/or packed u32 (outp)
// ---------------------------------------------------------------------------
__global__ __launch_bounds__(256) void gemm_bf3_k(
    const ushort_t* __restrict__ Ah, const ushort_t* __restrict__ Al, int lda,
    const ushort_t* __restrict__ Wh, const ushort_t* __restrict__ Wl, int ldw,
    const float* __restrict__ bias, const float* __restrict__ resid,
    float* __restrict__ outf, ushort_t* __restrict__ outh, ushort_t* __restrict__ outl,
    unsigned* __restrict__ outp,
    int M, int N, int K, int relu)
{
    __shared__ __align__(16) ushort_t lds[2][4 * 128 * 32];   // 2 x 32KB
    const int tid  = threadIdx.x;
    const int lane = tid & 63;
    const int wv   = tid >> 6;
    const int wm   = wv >> 1, wn = wv & 1;
    int bx = blockIdx.x, by = blockIdx.y;
    xcd_swz(bx, by);
    const int row0 = by * 128, col0 = bx * 128;
    const int g    = lane >> 4;
    const int srow0 = wv * 32;

    f32x4 acc[4][4];
#pragma unroll
    for (int mi = 0; mi < 4; mi++)
#pragma unroll
        for (int ni = 0; ni < 4; ni++) acc[mi][ni] = (f32x4)(0.f);

    auto STAGE = [&](int buf, int k0) {
#pragma unroll
        for (int ii = 0; ii < 2; ii++) {
            const int r   = srow0 + ii * 16 + (lane >> 2);
            const int ug  = (((lane & 3) ^ ((r >> 1) & 3)) << 3);
            const size_t ga = (size_t)(row0 + r) * lda + k0 + ug;
            const size_t gw = (size_t)(col0 + r) * ldw + k0 + ug;
            const int lo  = (srow0 + ii * 16) * 32;
            __builtin_amdgcn_global_load_lds(
                (const __attribute__((address_space(1))) void*)(Ah + ga),
                (__attribute__((address_space(3))) void*)&lds[buf][0 * 4096 + lo], 16, 0, 0);
            __builtin_amdgcn_global_load_lds(
                (const __attribute__((address_space(1))) void*)(Al + ga),
                (__attribute__((address_space(3))) void*)&lds[buf][1 * 4096 + lo], 16, 0, 0);
            __builtin_amdgcn_global_load_lds(
                (const __attribute__((address_space(1))) void*)(Wh + gw),
                (__attribute__((address_space(3))) void*)&lds[buf][2 * 4096 + lo], 16, 0, 0);
            __builtin_amdgcn_global_load_lds(
                (const __attribute__((address_space(1))) void*)(Wl + gw),
                (__attribute__((address_space(3))) void*)&lds[buf][3 * 4096 + lo], 16, 0, 0);
        }
    };

    const int nt = K >> 5;
    STAGE(0, 0);

    for (int t = 0; t < nt; ++t) {
        const int cur = t & 1;
        if (t + 1 < nt) {
            STAGE(cur ^ 1, (t + 1) << 5);
            asm volatile("s_waitcnt vmcnt(8)" ::: "memory");
        } else {
            asm volatile("s_waitcnt vmcnt(0)" ::: "memory");
        }
        __builtin_amdgcn_s_barrier();
        __builtin_amdgcn_sched_barrier(0);

        s16x8 ah[4], al[4], wh[4], wl[4];
#pragma unroll
        for (int mi = 0; mi < 4; mi++) {
            const int m  = wm * 64 + mi * 16 + (lane & 15);
            const int pu = ((g ^ ((m >> 1) & 3)) << 3);
            ah[mi] = *(const s16x8*)&lds[cur][0 * 4096 + m * 32 + pu];
            al[mi] = *(const s16x8*)&lds[cur][1 * 4096 + m * 32 + pu];
            const int n  = wn * 64 + mi * 16 + (lane & 15);
            const int pn = ((g ^ ((n >> 1) & 3)) << 3);
            wh[mi] = *(const s16x8*)&lds[cur][2 * 4096 + n * 32 + pn];
            wl[mi] = *(const s16x8*)&lds[cur][3 * 4096 + n * 32 + pn];
        }
        __builtin_amdgcn_s_setprio(1);
#pragma unroll
        for (int mi = 0; mi < 4; mi++)
#pragma unroll
            for (int ni = 0; ni < 4; ni++) {
                acc[mi][ni] = __builtin_amdgcn_mfma_f32_16x16x32_bf16(ah[mi], wh[ni], acc[mi][ni], 0, 0, 0);
                acc[mi][ni] = __builtin_amdgcn_mfma_f32_16x16x32_bf16(al[mi], wh[ni], acc[mi][ni], 0, 0, 0);
                acc[mi][ni] = __builtin_amdgcn_mfma_f32_16x16x32_bf16(ah[mi], wl[ni], acc[mi][ni], 0, 0, 0);
            }
        __builtin_amdgcn_s_setprio(0);

        __builtin_amdgcn_sched_barrier(0);
        __builtin_amdgcn_s_barrier();     // WAR: lds[cur] overwritten at t+1's STAGE
    }

#pragma unroll
    for (int mi = 0; mi < 4; mi++) {
#pragma unroll
        for (int ni = 0; ni < 4; ni++) {
#pragma unroll
            for (int r = 0; r < 4; r++) {
                const int row = row0 + wm * 64 + mi * 16 + g * 4 + r;
                const int col = col0 + wn * 64 + ni * 16 + (lane & 15);
                float v = acc[mi][ni][r];
                if (bias)  v += bias[col];
                if (relu)  v = fmaxf(v, 0.f);
                if (resid) v += resid[(size_t)row * N + col];
                if (outf)  outf[(size_t)row * N + col] = v;
                if (outh) {
                    unsigned short h = f2bf(v);
                    outh[(size_t)row * N + col] = h;
                    outl[(size_t)row * N + col] = f2bf(v - bf2f(h));
                }
                if (outp) {
                    unsigned short h = f2bf(v);
                    outp[(size_t)row * N + col] =
                        (unsigned)h | ((unsigned)f2bf(v - bf2f(h)) << 16);
                }
            }
        }
    }
}

// ---------------------------------------------------------------------------
// bf16x6 MFMA GEMM (qk only): ~2^-26 rel err. Emits fp32 + packed hi/lo.
// ---------------------------------------------------------------------------
__global__ __launch_bounds__(256) void gemm_bf6_k(
    const ushort_t* __restrict__ A1, const ushort_t* __restrict__ A2,
    const ushort_t* __restrict__ A3, int lda,
    const ushort_t* __restrict__ W1, const ushort_t* __restrict__ W2,
    const ushort_t* __restrict__ W3,
    float* __restrict__ outf, unsigned* __restrict__ outp, int M, int N, int K)
{
    __shared__ __align__(16) ushort_t lds[6 * 128 * 32];   // A1,A2,A3,W1,W2,W3
    const int tid  = threadIdx.x;
    const int lane = tid & 63;
    const int wv   = tid >> 6;
    const int wm   = wv >> 1, wn = wv & 1;
    int bx = blockIdx.x, by = blockIdx.y;
    xcd_swz(bx, by);
    const int row0 = by * 128, col0 = bx * 128;
    const int g    = lane >> 4;

    f32x4 acc[4][4];
#pragma unroll
    for (int mi = 0; mi < 4; mi++)
#pragma unroll
        for (int ni = 0; ni < 4; ni++) acc[mi][ni] = (f32x4)(0.f);

    const int srow0 = wv * 32;

    for (int k0 = 0; k0 < K; k0 += 32) {
        __syncthreads();
#pragma unroll
        for (int ii = 0; ii < 2; ii++) {
            const int r   = srow0 + ii * 16 + (lane >> 2);
            const int ug  = (((lane & 3) ^ ((r >> 1) & 3)) << 3);
            const size_t ga = (size_t)(row0 + r) * lda + k0 + ug;
            const size_t gw = (size_t)(col0 + r) * K   + k0 + ug;
            const int lo  = (srow0 + ii * 16) * 32;
            __builtin_amdgcn_global_load_lds(
                (const __attribute__((address_space(1))) void*)(A1 + ga),
                (__attribute__((address_space(3))) void*)&lds[0 * 4096 + lo], 16, 0, 0);
            __builtin_amdgcn_global_load_lds(
                (const __attribute__((address_space(1))) void*)(A2 + ga),
                (__attribute__((address_space(3))) void*)&lds[1 * 4096 + lo], 16, 0, 0);
            __builtin_amdgcn_global_load_lds(
                (const __attribute__((address_space(1))) void*)(A3 + ga),
                (__attribute__((address_space(3))) void*)&lds[2 * 4096 + lo], 16, 0, 0);
            __builtin_amdgcn_global_load_lds(
                (const __attribute__((address_space(1))) void*)(W1 + gw),
                (__attribute__((address_space(3))) void*)&lds[3 * 4096 + lo], 16, 0, 0);
            __builtin_amdgcn_global_load_lds(
                (const __attribute__((address_space(1))) void*)(W2 + gw),
                (__attribute__((address_space(3))) void*)&lds[4 * 4096 + lo], 16, 0, 0);
            __builtin_amdgcn_global_load_lds(
                (const __attribute__((address_space(1))) void*)(W3 + gw),
                (__attribute__((address_space(3))) void*)&lds[5 * 4096 + lo], 16, 0, 0);
        }
        __syncthreads();

        s16x8 a1[4], a2[4], a3[4], w1[4], w2[4], w3[4];
#pragma unroll
        for (int mi = 0; mi < 4; mi++) {
            const int m  = wm * 64 + mi * 16 + (lane & 15);
            const int pu = ((g ^ ((m >> 1) & 3)) << 3);
            a1[mi] = *(const s16x8*)&lds[0 * 4096 + m * 32 + pu];
            a2[mi] = *(const s16x8*)&lds[1 * 4096 + m * 32 + pu];
            a3[mi] = *(const s16x8*)&lds[2 * 4096 + m * 32 + pu];
            const int n  = wn * 64 + mi * 16 + (lane & 15);
            const int pn = ((g ^ ((n >> 1) & 3)) << 3);
            w1[mi] = *(const s16x8*)&lds[3 * 4096 + n * 32 + pn];
            w2[mi] = *(const s16x8*)&lds[4 * 4096 + n * 32 + pn];
            w3[mi] = *(const s16x8*)&lds[5 * 4096 + n * 32 + pn];
        }
        __builtin_amdgcn_s_setprio(1);
#pragma unroll
        for (int mi = 0; mi < 4; mi++)
#pragma unroll
            for (int ni = 0; ni < 4; ni++) {
                acc[mi][ni] = __builtin_amdgcn_mfma_f32_16x16x32_bf16(a1[mi], w1[ni], acc[mi][ni], 0, 0, 0);
                acc[mi][ni] = __builtin_amdgcn_mfma_f32_16x16x32_bf16(a2[mi], w1[ni], acc[mi][ni], 0, 0, 0);
                acc[mi][ni] = __builtin_amdgcn_mfma_f32_16x16x32_bf16(a1[mi], w2[ni], acc[mi][ni], 0, 0, 0);
                acc[mi][ni] = __builtin_amdgcn_mfma_f32_16x16x32_bf16(a2[mi], w2[ni], acc[mi][ni], 0, 0, 0);
                acc[mi][ni] = __builtin_amdgcn_mfma_f32_16x16x32_bf16(a1[mi], w3[ni], acc[mi][ni], 0, 0, 0);
                acc[mi][ni] = __builtin_amdgcn_mfma_f32_16x16x32_bf16(a3[mi], w1[ni], acc[mi][ni], 0, 0, 0);
            }
        __builtin_amdgcn_s_setprio(0);
    }

#pragma unroll
    for (int mi = 0; mi < 4; mi++) {
#pragma unroll
        for (int ni = 0; ni < 4; ni++) {
#pragma unroll
            for (int r = 0; r < 4; r++) {
                const int row = row0 + wm * 64 + mi * 16 + g * 4 + r;
                const int col = col0 + wn * 64 + ni * 16 + (lane & 15);
                float v = acc[mi][ni][r];
                outf[(size_t)row * N + col] = v;
                unsigned short h = f2bf(v);
                outp[(size_t)row * N + col] =
                    (unsigned)h | ((unsigned)f2bf(v - bf2f(h)) << 16);
            }
        }
    }
}

// ---------------------------------------------------------------------------
// fp32 -> bf16 split converter (+ optional fp32 copy)
// ---------------------------------------------------------------------------
__global__ __launch_bounds__(256) void cvt_k(
    const float* __restrict__ in, ushort_t* __restrict__ o1,
    ushort_t* __restrict__ o2, ushort_t* __restrict__ o3,
    float* __restrict__ ocopy, int n4)
{
    int i = blockIdx.x * 256 + threadIdx.x;
    if (i >= n4) return;
    float4 v = ((const float4*)in)[i];
    if (ocopy) ((float4*)ocopy)[i] = v;
    float vv[4] = {v.x, v.y, v.z, v.w};
    union { unsigned short us[4]; ushort4 v4; } H, L, M;
#pragma unroll
    for (int q = 0; q < 4; q++) {
        unsigned short a = f2bf(vv[q]);
        float r1 = vv[q] - bf2f(a);
        unsigned short b = f2bf(r1);
        H.us[q] = a; L.us[q] = b;
        M.us[q] = f2bf(r1 - bf2f(b));
    }
    ((ushort4*)o1)[i] = H.v4;
    ((ushort4*)o2)[i] = L.v4;
    if (o3) ((ushort4*)o3)[i] = M.v4;
}

// ---------------------------------------------------------------------------
// Batched per-layer weight split conversion: one launch covers
// Wqk (3-split, 256 blk) | Wv (256) | Wout (256) | W1 (1024) | W2 (1024).
// ---------------------------------------------------------------------------
__global__ __launch_bounds__(256) void cvtw_k(
    const float* __restrict__ Wqk_i, const float* __restrict__ Wv_i,
    const float* __restrict__ Wout_i, const float* __restrict__ W1_i,
    const float* __restrict__ W2_i,
    ushort_t* __restrict__ wq1, ushort_t* __restrict__ wq2, ushort_t* __restrict__ wq3,
    ushort_t* __restrict__ wvh, ushort_t* __restrict__ wvl,
    ushort_t* __restrict__ woh, ushort_t* __restrict__ wol,
    ushort_t* __restrict__ w1h, ushort_t* __restrict__ w1l,
    ushort_t* __restrict__ w2h, ushort_t* __restrict__ w2l)
{
    const int blk = blockIdx.x;
    const float* in;
    ushort_t *o1, *o2, *o3 = nullptr;
    int i;
    if (blk < 256)       { in = Wqk_i;  o1 = wq1; o2 = wq2; o3 = wq3; i = blk * 256; }
    else if (blk < 512)  { in = Wv_i;   o1 = wvh; o2 = wvl; i = (blk - 256) * 256; }
    else if (blk < 768)  { in = Wout_i; o1 = woh; o2 = wol; i = (blk - 512) * 256; }
    else if (blk < 1792) { in = W1_i;   o1 = w1h; o2 = w1l; i = (blk - 768) * 256; }
    else                 { in = W2_i;   o1 = w2h; o2 = w2l; i = (blk - 1792) * 256; }
    i += threadIdx.x;
    float4 v = ((const float4*)in)[i];
    float vv[4] = {v.x, v.y, v.z, v.w};
    union { unsigned short us[4]; ushort4 v4; } H, L, M;
#pragma unroll
    for (int q = 0; q < 4; q++) {
        unsigned short a = f2bf(vv[q]);
        float r1 = vv[q] - bf2f(a);
        unsigned short b = f2bf(r1);
        H.us[q] = a; L.us[q] = b;
        M.us[q] = f2bf(r1 - bf2f(b));
    }
    ((ushort4*)o1)[i] = H.v4;
    ((ushort4*)o2)[i] = L.v4;
    if (o3) ((ushort4*)o3)[i] = M.v4;
}

// ---------------------------------------------------------------------------
// Bucket kernel v2 (all 4 rounds per block) — reads fp32 qk
// ---------------------------------------------------------------------------
__global__ __launch_bounds__(256) void bucket_k(
    const float* __restrict__ qk, const float* __restrict__ rot,
    int* __restrict__ bkt)
{
    __shared__ float rs[NH][64][32];    // 32 KB
    const int bh = blockIdx.y;
    const int t = blockIdx.x * 256 + threadIdx.x;
    for (int i = threadIdx.x; i < NH * 64 * 32; i += 256) {
        int r = i >> 11, f = (i >> 5) & 63, j = i & 31;
        rs[r][f][j] = rot[(f * NH + r) * 32 + j];
    }
    __syncthreads();
    const int b = bh >> 3, h = bh & 7;
    const float* q = qk + ((size_t)(b * TT + t)) * DD + h * DHH;
    float qv[64];
#pragma unroll
    for (int f4 = 0; f4 < 16; f4++) {
        float4 tmp = ((const float4*)q)[f4];
        qv[f4 * 4 + 0] = tmp.x; qv[f4 * 4 + 1] = tmp.y;
        qv[f4 * 4 + 2] = tmp.z; qv[f4 * 4 + 3] = tmp.w;
    }
    for (int r = 0; r < NH; r++) {
        float rv[32];
#pragma unroll
        for (int j = 0; j < 32; j++) rv[j] = 0.f;
        for (int f = 0; f < 64; f++) {
            float qf = qv[f];
#pragma unroll
            for (int j = 0; j < 32; j++) rv[j] = fmaf(qf, rs[r][f][j], rv[j]);
        }
        float best = rv[0];
        int bi = 0;
#pragma unroll
        for (int j = 1; j < 32; j++) { if (rv[j] > best) { best = rv[j]; bi = j; } }
#pragma unroll
        for (int j = 0; j < 32; j++) { float v = -rv[j]; if (v > best) { best = v; bi = 32 + j; } }
        bkt[((size_t)bh * NH + r) * TT + t] = bi;
    }
}

// ---------------------------------------------------------------------------
// Parallel stable counting sort per (bh, round). (verified R4)
// ---------------------------------------------------------------------------
__global__ __launch_bounds__(256) void sort_k(
    const int* __restrict__ bkt, int* __restrict__ st)
{
    __shared__ int lb[TT];
    __shared__ unsigned short cnt[128][64];
    __shared__ int base[64];
    const int r = blockIdx.x, bh = blockIdx.y;
    const int tid = threadIdx.x;
    const int* src = bkt + ((size_t)bh * NH + r) * TT;

    const int4* s4 = (const int4*)src;
    int4* l4 = (int4*)lb;
#pragma unroll
    for (int q = 0; q < 4; q++) l4[tid + q * 256] = s4[tid + q * 256];
    unsigned* cz = (unsigned*)cnt;
#pragma unroll
    for (int q = 0; q < 16; q++) cz[tid + q * 256] = 0;
    __syncthreads();

    if (tid < 128) {
        for (int it = 0; it < 32; it++) {
            int bb = lb[tid * 32 + it];
            cnt[tid][bb]++;
        }
    }
    __syncthreads();

    if (tid < 64) {
        const int bb = tid;
        int run = 0;
        for (int s = 0; s < 128; s++) {
            int t = cnt[s][bb];
            cnt[s][bb] = (unsigned short)run;
            run += t;
        }
        int inc = run;
#pragma unroll
        for (int off = 1; off < 64; off <<= 1) {
            int n = __shfl_up(inc, off, 64);
            if (tid >= off) inc += n;
        }
        base[bb] = inc - run;
    }
    __syncthreads();

    if (tid < 128) {
        int* dst = st + (size_t)bh * (NH * TT) + (size_t)r * TT;
        for (int it = 0; it < 32; it++) {
            int t = tid * 32 + it;
            int bb = lb[t];
            int pos = base[bb] + (int)cnt[tid][bb];
            cnt[tid][bb]++;
            dst[pos] = t;
        }
    }
}

// ---------------------------------------------------------------------------
// Attention v5: packed u32 inputs; V verbatim to LDS; K unpacked hi/lo.
// Strip of 8 bh. T5 setprio around MFMA clusters.
// ---------------------------------------------------------------------------
__global__ __launch_bounds__(256, 2) void attn_k(
    const unsigned* __restrict__ qkp, const unsigned* __restrict__ vp,
    const int* __restrict__ st, float* __restrict__ obuf,
    float* __restrict__ lseb, int bh0)
{
    __shared__ __align__(16) ushort_t ksh[128 * 72];
    __shared__ __align__(16) ushort_t ksl[128 * 72];
    __shared__ __align__(16) unsigned vsp[128 * 66];
    __shared__ float invn[128];
    __shared__ int   tks[128];

    const int c   = blockIdx.x;
    const int bhl = blockIdx.y;
    const int bh  = bh0 + bhl;
    const int b   = bh >> 3, h = bh & 7;
    const int tid = threadIdx.x;
    const int* stb = st + (size_t)bh * (NH * TT);

    if (tid < 128) {
        int cc = (tid < 64) ? c : ((c + NC - 1) & (NC - 1));
        tks[tid] = stb[cc * 64 + (tid & 63)];
    }
    __syncthreads();

    {   // stage K (unpack hi/lo) + V (verbatim) + inv k-norms
        const int row = tid >> 1, c0 = (tid & 1) * 32;
        const int t = tks[row];
        const uint4* kg = (const uint4*)(qkp + ((size_t)(b * TT + t)) * DD + h * DHH + c0);
        const uint4* vg = (const uint4*)(vp  + ((size_t)(b * TT + t)) * DD + h * DHH + c0);
        unsigned kp[32];
        uint4 vq[8];
        float ss = 0.f;
#pragma unroll
        for (int q = 0; q < 8; q++) {
            uint4 kq = kg[q];
            kp[4 * q + 0] = kq.x; kp[4 * q + 1] = kq.y;
            kp[4 * q + 2] = kq.z; kp[4 * q + 3] = kq.w;
            vq[q] = vg[q];
        }
#pragma unroll
        for (int e = 0; e < 32; e++) {
            float f = __uint_as_float(kp[e] << 16) + __uint_as_float(kp[e] & 0xffff0000u);
            ss = fmaf(f, f, ss);
        }
        ss += __shfl_xor(ss, 1);
        if ((tid & 1) == 0) invn[row] = 1.0f / fmaxf(sqrtf(ss), 1e-12f);

        unsigned hw[16], lw[16];
#pragma unroll
        for (int e = 0; e < 16; e++) {
            hw[e] = (kp[2 * e] & 0xffffu) | (kp[2 * e + 1] << 16);
            lw[e] = (kp[2 * e] >> 16) | (kp[2 * e + 1] & 0xffff0000u);
        }
        uint4* kdh = (uint4*)&ksh[row * 72 + c0];
        uint4* kdl = (uint4*)&ksl[row * 72 + c0];
#pragma unroll
        for (int q = 0; q < 4; q++) {
            kdh[q] = make_uint4(hw[4 * q], hw[4 * q + 1], hw[4 * q + 2], hw[4 * q + 3]);
            kdl[q] = make_uint4(lw[4 * q], lw[4 * q + 1], lw[4 * q + 2], lw[4 * q + 3]);
        }
        uint2* vd = (uint2*)&vsp[row * 66 + c0];
#pragma unroll
        for (int q = 0; q < 8; q++) {
            vd[2 * q]     = make_uint2(vq[q].x, vq[q].y);
            vd[2 * q + 1] = make_uint2(vq[q].z, vq[q].w);
        }
    }
    __syncthreads();

    const int lane = tid & 63;
    const int wv   = tid >> 6;
    const int cc16 = lane & 15;
    const int g    = lane >> 4;
    const int rr   = c >> 6;

    f32x4 stt[8];
#pragma unroll
    for (int jt = 0; jt < 8; jt++) stt[jt] = (f32x4)(0.f);

    const int qrow = wv * 16 + cc16;
#pragma unroll
    for (int ks = 0; ks < 2; ks++) {
        s16x8 qh = *(const s16x8*)&ksh[qrow * 72 + ks * 32 + g * 8];
        s16x8 ql = *(const s16x8*)&ksl[qrow * 72 + ks * 32 + g * 8];
        __builtin_amdgcn_s_setprio(1);
#pragma unroll
        for (int jt = 0; jt < 8; jt++) {
            const int krow = jt * 16 + cc16;
            s16x8 ah = *(const s16x8*)&ksh[krow * 72 + ks * 32 + g * 8];
            s16x8 al = *(const s16x8*)&ksl[krow * 72 + ks * 32 + g * 8];
            stt[jt] = __builtin_amdgcn_mfma_f32_16x16x32_bf16(ah, qh, stt[jt], 0, 0, 0);
            stt[jt] = __builtin_amdgcn_mfma_f32_16x16x32_bf16(al, qh, stt[jt], 0, 0, 0);
            stt[jt] = __builtin_amdgcn_mfma_f32_16x16x32_bf16(ah, ql, stt[jt], 0, 0, 0);
        }
        __builtin_amdgcn_s_setprio(0);
    }

    const int tqi = tks[wv * 16 + cc16];
    float m = -INFINITY;
#pragma unroll
    for (int jt = 0; jt < 8; jt++) {
#pragma unroll
        for (int r4 = 0; r4 < 4; r4++) {
            const int j = jt * 16 + g * 4 + r4;
            float d = stt[jt][r4] * invn[j] * 0.125f;
            if (tqi == tks[j]) d = -5e4f;
            stt[jt][r4] = d;
            m = fmaxf(m, d);
        }
    }
    m = fmaxf(m, __shfl_xor(m, 16));
    m = fmaxf(m, __shfl_xor(m, 32));
    float s = 0.f;
#pragma unroll
    for (int jt = 0; jt < 8; jt++) {
#pragma unroll
        for (int r4 = 0; r4 < 4; r4++) {
            float e = expf(stt[jt][r4] - m);
            stt[jt][r4] = e;
            s += e;
        }
    }
    s += __shfl_xor(s, 16);
    s += __shfl_xor(s, 32);
    const float is = 1.0f / s;
    if (g == 0) lseb[((size_t)bh * NH + rr) * TT + tqi] = m + logf(s);

    unsigned ph[8][2], pl[8][2];
#pragma unroll
    for (int jt = 0; jt < 8; jt++) {
#pragma unroll
        for (int w2 = 0; w2 < 2; w2++) {
            float p0 = stt[jt][2 * w2] * is;
            float p1 = stt[jt][2 * w2 + 1] * is;
            unsigned short h0 = f2bf(p0), h1 = f2bf(p1);
            ph[jt][w2] = (unsigned)h0 | ((unsigned)h1 << 16);
            pl[jt][w2] = (unsigned)f2bf(p0 - bf2f(h0)) | ((unsigned)f2bf(p1 - bf2f(h1)) << 16);
        }
    }

    f32x4 occ[4];
#pragma unroll
    for (int nt = 0; nt < 4; nt++) occ[nt] = (f32x4)(0.f);

    const int srcLow  = ((g & 1) << 5) + cc16;
    const int srcHigh = srcLow + 16;
    const bool hiT = (lane & 32) != 0;

#pragma unroll
    for (int ks = 0; ks < 4; ks++) {
        U4 Phi, Plo;
        {
            unsigned a0 = (unsigned)__shfl((int)ph[2 * ks][0], srcLow);
            unsigned a1 = (unsigned)__shfl((int)ph[2 * ks][1], srcLow);
            unsigned a2 = (unsigned)__shfl((int)ph[2 * ks][0], srcHigh);
            unsigned a3 = (unsigned)__shfl((int)ph[2 * ks][1], srcHigh);
            unsigned b0 = (unsigned)__shfl((int)ph[2 * ks + 1][0], srcLow);
            unsigned b1 = (unsigned)__shfl((int)ph[2 * ks + 1][1], srcLow);
            unsigned b2 = (unsigned)__shfl((int)ph[2 * ks + 1][0], srcHigh);
            unsigned b3 = (unsigned)__shfl((int)ph[2 * ks + 1][1], srcHigh);
            Phi.u[0] = hiT ? b0 : a0; Phi.u[1] = hiT ? b1 : a1;
            Phi.u[2] = hiT ? b2 : a2; Phi.u[3] = hiT ? b3 : a3;
            unsigned c0 = (unsigned)__shfl((int)pl[2 * ks][0], srcLow);
            unsigned c1 = (unsigned)__shfl((int)pl[2 * ks][1], srcLow);
            unsigned c2 = (unsigned)__shfl((int)pl[2 * ks][0], srcHigh);
            unsigned c3 = (unsigned)__shfl((int)pl[2 * ks][1], srcHigh);
            unsigned d0 = (unsigned)__shfl((int)pl[2 * ks + 1][0], srcLow);
            unsigned d1 = (unsigned)__shfl((int)pl[2 * ks + 1][1], srcLow);
            unsigned d2 = (unsigned)__shfl((int)pl[2 * ks + 1][0], srcHigh);
            unsigned d3 = (unsigned)__shfl((int)pl[2 * ks + 1][1], srcHigh);
            Plo.u[0] = hiT ? d0 : c0; Plo.u[1] = hiT ? d1 : c1;
            Plo.u[2] = hiT ? d2 : c2; Plo.u[3] = hiT ? d3 : c3;
        }
#pragma unroll
        for (int nt = 0; nt < 4; nt++) {
            unsigned u[8];
#pragma unroll
            for (int e = 0; e < 8; e++)
                u[e] = vsp[(32 * ks + 8 * g + e) * 66 + nt * 16 + cc16];
            U4 Vh, Vl;
#pragma unroll
            for (int m2 = 0; m2 < 4; m2++) {
                Vh.u[m2] = (u[2 * m2] & 0xffffu) | (u[2 * m2 + 1] << 16);
                Vl.u[m2] = (u[2 * m2] >> 16) | (u[2 * m2 + 1] & 0xffff0000u);
            }
            __builtin_amdgcn_s_setprio(1);
            occ[nt] = __builtin_amdgcn_mfma_f32_16x16x32_bf16(Phi.v, Vh.v, occ[nt], 0, 0, 0);
            occ[nt] = __builtin_amdgcn_mfma_f32_16x16x32_bf16(Plo.v, Vh.v, occ[nt], 0, 0, 0);
            occ[nt] = __builtin_amdgcn_mfma_f32_16x16x32_bf16(Phi.v, Vl.v, occ[nt], 0, 0, 0);
            __builtin_amdgcn_s_setprio(0);
        }
    }

#pragma unroll
    for (int r4 = 0; r4 < 4; r4++) {
        const int i = wv * 16 + g * 4 + r4;
        const int ti = tks[i];
        float* dst = obuf + (((size_t)bhl * NH + rr) * TT + ti) * DHH + cc16;
        dst[0]  = occ[0][r4];
        dst[16] = occ[1][r4];
        dst[32] = occ[2][r4];
        dst[48] = occ[3][r4];
    }
}

// ---------------------------------------------------------------------------
// Combine rounds for an 8-bh strip
// ---------------------------------------------------------------------------
__global__ __launch_bounds__(256) void combine_k(
    const float* __restrict__ obuf, const float* __restrict__ lseb,
    ushort_t* __restrict__ att, int bh0)
{
    int idx = blockIdx.x * 256 + threadIdx.x;
    int d = idx & 63;
    int t = (idx >> 6) & (TT - 1);
    int bhl = idx >> 18;
    int bh = bh0 + bhl;
    float l0 = lseb[((size_t)bh * NH + 0) * TT + t];
    float l1 = lseb[((size_t)bh * NH + 1) * TT + t];
    float l2 = lseb[((size_t)bh * NH + 2) * TT + t];
    float l3 = lseb[((size_t)bh * NH + 3) * TT + t];
    float m = fmaxf(fmaxf(l0, l1), fmaxf(l2, l3));
    float e0 = expf(l0 - m), e1 = expf(l1 - m), e2 = expf(l2 - m), e3 = expf(l3 - m);
    float inv = 1.0f / (e0 + e1 + e2 + e3);
    float o0 = obuf[(((size_t)bhl * NH + 0) * TT + t) * DHH + d];
    float o1 = obuf[(((size_t)bhl * NH + 1) * TT + t) * DHH + d];
    float o2 = obuf[(((size_t)bhl * NH + 2) * TT + t) * DHH + d];
    float o3 = obuf[(((size_t)bhl * NH + 3) * TT + t) * DHH + d];
    float o = (e0 * o0 + e1 * o1 + e2 * o2 + e3 * o3) * inv;
    int b = bh >> 3, h = bh & 7;
    size_t base = (size_t)(b * TT + t) * 1024 + h * DHH + d;
    unsigned short hi = f2bf(o);
    att[base]       = hi;
    att[base + 512] = f2bf(o - bf2f(hi));
}

// ---------------------------------------------------------------------------
// LayerNorm over D=512; optional 3-way bf16 split output. Safe in-place.
// ---------------------------------------------------------------------------
__global__ __launch_bounds__(64) void ln_k(
    const float* __restrict__ in, const float* __restrict__ g,
    const float* __restrict__ be, float* __restrict__ out,
    ushort_t* __restrict__ oh, ushort_t* __restrict__ ol,
    ushort_t* __restrict__ ol2)
{
    const int row = blockIdx.x;
    const int tid = threadIdx.x;
    const float* x = in + (size_t)row * DD;
    float4 a = *(const float4*)(x + tid * 8);
    float4 b = *(const float4*)(x + tid * 8 + 4);
    float s = a.x + a.y + a.z + a.w + b.x + b.y + b.z + b.w;
#pragma unroll
    for (int o = 32; o >= 1; o >>= 1) s += __shfl_xor(s, o, 64);
    float mean = s * (1.0f / 512.0f);
    float dx[8];
    dx[0] = a.x - mean; dx[1] = a.y - mean; dx[2] = a.z - mean; dx[3] = a.w - mean;
    dx[4] = b.x - mean; dx[5] = b.y - mean; dx[6] = b.z - mean; dx[7] = b.w - mean;
    float ss = 0.f;
#pragma unroll
    for (int q = 0; q < 8; q++) ss += dx[q] * dx[q];
#pragma unroll
    for (int o = 32; o >= 1; o >>= 1) ss += __shfl_xor(ss, o, 64);
    float var = ss * (1.0f / 512.0f);
    float inv = 1.0f / sqrtf(var + 1e-6f);
    const float* gp = g + tid * 8;
    const float* bp = be + tid * 8;
    float y[8];
#pragma unroll
    for (int q = 0; q < 8; q++) y[q] = dx[q] * inv * gp[q] + bp[q];
    float* yp = out + (size_t)row * DD + tid * 8;
    *(float4*)(yp)     = make_float4(y[0], y[1], y[2], y[3]);
    *(float4*)(yp + 4) = make_float4(y[4], y[5], y[6], y[7]);
    if (oh) {
        union { unsigned short us[8]; ushort4 v4[2]; } H, L, M;
#pragma unroll
        for (int q = 0; q < 8; q++) {
            unsigned short h = f2bf(y[q]);
            float r1 = y[q] - bf2f(h);
            unsigned short l = f2bf(r1);
            H.us[q] = h; L.us[q] = l;
            M.us[q] = f2bf(r1 - bf2f(l));
        }
        size_t e = (size_t)row * DD + tid * 8;
        *(ushort4*)(oh + e)      = H.v4[0];
        *(ushort4*)(oh + e + 4)  = H.v4[1];
        *(ushort4*)(ol + e)      = L.v4[0];
        *(ushort4*)(ol + e + 4)  = L.v4[1];
        *(ushort4*)(ol2 + e)     = M.v4[0];
        *(ushort4*)(ol2 + e + 4) = M.v4[1];
    }
}

// ---------------------------------------------------------------------------
extern "C" void kernel_launch(void* const* d_in, const int* in_sizes, int n_in,
                              void* d_out, int out_size, void* d_ws, size_t ws_size,
                              hipStream_t stream)
{
    const float* src  = (const float*)d_in[0];
    const float* rots = (const float*)d_in[1];
    const float* Wqk  = (const float*)d_in[2];
    const float* Wv   = (const float*)d_in[3];
    const float* Wout = (const float*)d_in[4];
    const float* bout = (const float*)d_in[5];
    const float* W1   = (const float*)d_in[6];
    const float* b1   = (const float*)d_in[7];
    const float* W2   = (const float*)d_in[8];
    const float* b2   = (const float*)d_in[9];
    const float* g2   = (const float*)d_in[10];
    const float* be2  = (const float*)d_in[11];
    const float* gf   = (const float*)d_in[12];
    const float* bf   = (const float*)d_in[13];
    float* out = (float*)d_out;

    // ---- workspace layout (~234 MB) ----
    char* w = (char*)d_ws;
    const size_t SZ_X = (size_t)MROWS * DD * 4;               // 33.55 MB
    const size_t XHALF = (size_t)MROWS * DD;
    float*    x     = (float*)(w);
    ushort_t* xs    = (ushort_t*)(w + SZ_X);
    ushort_t* xh    = xs;
    ushort_t* xl    = xs + XHALF;
    ushort_t* xl2   = xs + 2 * XHALF;
    char*     p     = w + SZ_X + 3 * XHALF * 2;
    float*    qkb   = (float*)(p);
    ushort_t* attb  = (ushort_t*)(p);
    unsigned* vp    = (unsigned*)(p + SZ_X);
    unsigned* qkp   = (unsigned*)(p + 2 * SZ_X);
    float*    obuf  = (float*)(p + 3 * SZ_X);
    ushort_t* h1h   = (ushort_t*)(p);                         // FFN: spans p..p+2SZ_X
    ushort_t* h1l   = (ushort_t*)(p + 2 * SZ_X);              // FFN: spans p+2..p+4SZ_X
    ushort_t* wb    = (ushort_t*)(p + 4 * SZ_X);
    char*     tail  = p + 4 * SZ_X + 6029312 * 2;
    int*      bkt   = (int*)(tail);
    int*      st    = (int*)(tail + (size_t)BHH * NH * TT * 4);
    float*    lseb  = (float*)(tail + 2 * (size_t)BHH * NH * TT * 4);

    ushort_t* wvh = wb;            ushort_t* wvl = wb + 262144;
    ushort_t* woh = wb + 524288;   ushort_t* wol = wb + 786432;
    ushort_t* w1h = wb + 1048576;  ushort_t* w1l = wb + 2097152;
    ushort_t* w2h = wb + 3145728;  ushort_t* w2l = wb + 4194304;
    ushort_t* wq1 = wb + 5242880;  ushort_t* wq2 = wb + 5505024;
    ushort_t* wq3 = wb + 5767168;

    // x copy + 3-way split in one pass
    cvt_k<<<(MROWS * DD / 4 + 255) / 256, 256, 0, stream>>>(src, xh, xl, xl2, x,
                                                            MROWS * DD / 4);

    for (int i = 0; i < LLAY; i++) {
        const float* Wqk_i = Wqk + (size_t)i * DD * DD;
        const float* Wv_i  = Wv  + (size_t)i * DD * DD;
        const float* Wout_i= Wout+ (size_t)i * DD * DD;
        const float* bout_i= bout+ (size_t)i * DD;
        const float* W1_i  = W1  + (size_t)i * DFFN * DD;
        const float* b1_i  = b1  + (size_t)i * DFFN;
        const float* W2_i  = W2  + (size_t)i * DD * DFFN;
        const float* b2_i  = b2  + (size_t)i * DD;
        const float* g2_i  = g2  + (size_t)i * DD;
        const float* be2_i = be2 + (size_t)i * DD;
        const float* rot_i = rots + (size_t)i * DHH * NH * 32;

        // all 5 weight conversions in one launch
        cvtw_k<<<2816, 256, 0, stream>>>(Wqk_i, Wv_i, Wout_i, W1_i, W2_i,
                                         wq1, wq2, wq3, wvh, wvl, woh, wol,
                                         w1h, w1l, w2h, w2l);

        // qk = x @ Wqk^T  (bf16x6, fp32 for bucket + packed for attn)
        gemm_bf6_k<<<dim3(4, 128), 256, 0, stream>>>(xh, xl, xl2, DD, wq1, wq2, wq3,
                                                     qkb, qkp, MROWS, DD, DD);
        // v = x @ Wv^T  (bf16x3, 2-phase, packed output)
        gemm_bf3_k<<<dim3(4, 128), 256, 0, stream>>>(xh, xl, DD, wvh, wvl, DD,
                                                     nullptr, nullptr,
                                                     nullptr, nullptr, nullptr, vp,
                                                     MROWS, DD, DD, 0);
        bucket_k<<<dim3(16, BHH), 256, 0, stream>>>(qkb, rot_i, bkt);
        sort_k<<<dim3(NH, BHH), 256, 0, stream>>>(bkt, st);

        // attention in 4 strips of 8 bh; combine -> att hi/lo
        for (int s = 0; s < 4; s++) {
            attn_k<<<dim3(NC, 8), 256, 0, stream>>>(qkp, vp, st, obuf, lseb, s * 8);
            combine_k<<<8192, 256, 0, stream>>>(obuf, lseb, attb, s * 8);
        }

        // x = x + att @ Wout^T + bout ; emit x hi/lo (for FFN input)
        gemm_bf3_k<<<dim3(4, 128), 256, 0, stream>>>(attb, attb + 512, 1024, woh, wol, DD,
                                                     bout_i, x, x, xh, xl, nullptr,
                                                     MROWS, DD, DD, 0);
        // FFN1 full-N: h1 = relu(x @ W1^T + b1)
        gemm_bf3_k<<<dim3(16, 128), 256, 0, stream>>>(xh, xl, DD, w1h, w1l, DD,
                                                      b1_i, nullptr,
                                                      nullptr, h1h, h1l, nullptr,
                                                      MROWS, DFFN, DD, 1);
        // FFN2 full-K: x = x + h1 @ W2^T + b2  (in-place residual on x)
        gemm_bf3_k<<<dim3(4, 128), 256, 0, stream>>>(h1h, h1l, DFFN, w2h, w2l, DFFN,
                                                     b2_i, x,
                                                     x, nullptr, nullptr, nullptr,
                                                     MROWS, DD, DFFN, 0);
        // x = LN(x) in-place; emit 3-way split for next layer's qk/v
        ln_k<<<MROWS, 64, 0, stream>>>(x, g2_i, be2_i, x, xh, xl, xl2);
    }
    ln_k<<<MROWS, 64, 0, stream>>>(x, gf, bf, out, nullptr, nullptr, nullptr);
}

// Round 13
// 3036.075 us; speedup vs baseline: 1.0515x; 1.0005x over previous
//
#include <hip/hip_runtime.h>
#include <math.h>

#define TT    4096
#define DD    512
#define HH    8
#define DHH   64
#define NH    4
#define LLAY  4
#define DFFN  2048
#define BHH   32          // B*H
#define NC    256         // chunks per bh (NH*NB)
#define MROWS 16384       // B*T

typedef __attribute__((ext_vector_type(8))) short s16x8;
typedef __attribute__((ext_vector_type(4))) float f32x4;
typedef unsigned short ushort_t;

union U4 { unsigned u[4]; s16x8 v; };

__device__ __forceinline__ unsigned short f2bf(float f) {
    unsigned u = __float_as_uint(f);
    unsigned r = (u + 0x7FFFu + ((u >> 16) & 1u)) >> 16;
    return (unsigned short)r;
}
__device__ __forceinline__ float bf2f(unsigned short h) {
    return __uint_as_float(((unsigned)h) << 16);
}

// XCD-aware bijective swizzle (T1, m157): nwg must be divisible by 8.
__device__ __forceinline__ void xcd_swz(int& bx, int& by) {
    const int gx = gridDim.x;
    const int nwg = gx * gridDim.y;
    const int flat = by * gx + bx;
    const int q = nwg >> 3;
    const int swz = (flat & 7) * q + (flat >> 3);
    bx = swz % gx;
    by = swz / gx;
}

// ---------------------------------------------------------------------------
// bf16x3 MFMA GEMM, 2-phase double-buffered: C = op(A @ W^T + b)[+r]
// ---------------------------------------------------------------------------
__global__ __launch_bounds__(256) void gemm_bf3_k(
    const ushort_t* __restrict__ Ah, const ushort_t* __restrict__ Al, int lda,
    const ushort_t* __restrict__ Wh, const ushort_t* __restrict__ Wl, int ldw,
    const float* __restrict__ bias, const float* __restrict__ resid,
    float* __restrict__ outf, ushort_t* __restrict__ outh, ushort_t* __restrict__ outl,
    unsigned* __restrict__ outp,
    int M, int N, int K, int relu)
{
    __shared__ __align__(16) ushort_t lds[2][4 * 128 * 32];   // 2 x 32KB
    const int tid  = threadIdx.x;
    const int lane = tid & 63;
    const int wv   = tid >> 6;
    const int wm   = wv >> 1, wn = wv & 1;
    int bx = blockIdx.x, by = blockIdx.y;
    xcd_swz(bx, by);
    const int row0 = by * 128, col0 = bx * 128;
    const int g    = lane >> 4;
    const int srow0 = wv * 32;

    f32x4 acc[4][4];
#pragma unroll
    for (int mi = 0; mi < 4; mi++)
#pragma unroll
        for (int ni = 0; ni < 4; ni++) acc[mi][ni] = (f32x4)(0.f);

    auto STAGE = [&](int buf, int k0) {
#pragma unroll
        for (int ii = 0; ii < 2; ii++) {
            const int r   = srow0 + ii * 16 + (lane >> 2);
            const int ug  = (((lane & 3) ^ ((r >> 1) & 3)) << 3);
            const size_t ga = (size_t)(row0 + r) * lda + k0 + ug;
            const size_t gw = (size_t)(col0 + r) * ldw + k0 + ug;
            const int lo  = (srow0 + ii * 16) * 32;
            __builtin_amdgcn_global_load_lds(
                (const __attribute__((address_space(1))) void*)(Ah + ga),
                (__attribute__((address_space(3))) void*)&lds[buf][0 * 4096 + lo], 16, 0, 0);
            __builtin_amdgcn_global_load_lds(
                (const __attribute__((address_space(1))) void*)(Al + ga),
                (__attribute__((address_space(3))) void*)&lds[buf][1 * 4096 + lo], 16, 0, 0);
            __builtin_amdgcn_global_load_lds(
                (const __attribute__((address_space(1))) void*)(Wh + gw),
                (__attribute__((address_space(3))) void*)&lds[buf][2 * 4096 + lo], 16, 0, 0);
            __builtin_amdgcn_global_load_lds(
                (const __attribute__((address_space(1))) void*)(Wl + gw),
                (__attribute__((address_space(3))) void*)&lds[buf][3 * 4096 + lo], 16, 0, 0);
        }
    };

    const int nt = K >> 5;
    STAGE(0, 0);

    for (int t = 0; t < nt; ++t) {
        const int cur = t & 1;
        if (t + 1 < nt) {
            STAGE(cur ^ 1, (t + 1) << 5);
            asm volatile("s_waitcnt vmcnt(8)" ::: "memory");
        } else {
            asm volatile("s_waitcnt vmcnt(0)" ::: "memory");
        }
        __builtin_amdgcn_s_barrier();
        __builtin_amdgcn_sched_barrier(0);

        s16x8 ah[4], al[4], wh[4], wl[4];
#pragma unroll
        for (int mi = 0; mi < 4; mi++) {
            const int m  = wm * 64 + mi * 16 + (lane & 15);
            const int pu = ((g ^ ((m >> 1) & 3)) << 3);
            ah[mi] = *(const s16x8*)&lds[cur][0 * 4096 + m * 32 + pu];
            al[mi] = *(const s16x8*)&lds[cur][1 * 4096 + m * 32 + pu];
            const int n  = wn * 64 + mi * 16 + (lane & 15);
            const int pn = ((g ^ ((n >> 1) & 3)) << 3);
            wh[mi] = *(const s16x8*)&lds[cur][2 * 4096 + n * 32 + pn];
            wl[mi] = *(const s16x8*)&lds[cur][3 * 4096 + n * 32 + pn];
        }
        __builtin_amdgcn_s_setprio(1);
#pragma unroll
        for (int mi = 0; mi < 4; mi++)
#pragma unroll
            for (int ni = 0; ni < 4; ni++) {
                acc[mi][ni] = __builtin_amdgcn_mfma_f32_16x16x32_bf16(ah[mi], wh[ni], acc[mi][ni], 0, 0, 0);
                acc[mi][ni] = __builtin_amdgcn_mfma_f32_16x16x32_bf16(al[mi], wh[ni], acc[mi][ni], 0, 0, 0);
                acc[mi][ni] = __builtin_amdgcn_mfma_f32_16x16x32_bf16(ah[mi], wl[ni], acc[mi][ni], 0, 0, 0);
            }
        __builtin_amdgcn_s_setprio(0);

        __builtin_amdgcn_sched_barrier(0);
        __builtin_amdgcn_s_barrier();     // WAR: lds[cur] overwritten at t+1's STAGE
    }

#pragma unroll
    for (int mi = 0; mi < 4; mi++) {
#pragma unroll
        for (int ni = 0; ni < 4; ni++) {
#pragma unroll
            for (int r = 0; r < 4; r++) {
                const int row = row0 + wm * 64 + mi * 16 + g * 4 + r;
                const int col = col0 + wn * 64 + ni * 16 + (lane & 15);
                float v = acc[mi][ni][r];
                if (bias)  v += bias[col];
                if (relu)  v = fmaxf(v, 0.f);
                if (resid) v += resid[(size_t)row * N + col];
                if (outf)  outf[(size_t)row * N + col] = v;
                if (outh) {
                    unsigned short h = f2bf(v);
                    outh[(size_t)row * N + col] = h;
                    outl[(size_t)row * N + col] = f2bf(v - bf2f(h));
                }
                if (outp) {
                    unsigned short h = f2bf(v);
                    outp[(size_t)row * N + col] =
                        (unsigned)h | ((unsigned)f2bf(v - bf2f(h)) << 16);
                }
            }
        }
    }
}

// ---------------------------------------------------------------------------
// bf16x6 MFMA GEMM (qk only): ~2^-26 rel err. Emits fp32 + packed hi/lo.
// ---------------------------------------------------------------------------
__global__ __launch_bounds__(256) void gemm_bf6_k(
    const ushort_t* __restrict__ A1, const ushort_t* __restrict__ A2,
    const ushort_t* __restrict__ A3, int lda,
    const ushort_t* __restrict__ W1, const ushort_t* __restrict__ W2,
    const ushort_t* __restrict__ W3,
    float* __restrict__ outf, unsigned* __restrict__ outp, int M, int N, int K)
{
    __shared__ __align__(16) ushort_t lds[6 * 128 * 32];   // A1,A2,A3,W1,W2,W3
    const int tid  = threadIdx.x;
    const int lane = tid & 63;
    const int wv   = tid >> 6;
    const int wm   = wv >> 1, wn = wv & 1;
    int bx = blockIdx.x, by = blockIdx.y;
    xcd_swz(bx, by);
    const int row0 = by * 128, col0 = bx * 128;
    const int g    = lane >> 4;

    f32x4 acc[4][4];
#pragma unroll
    for (int mi = 0; mi < 4; mi++)
#pragma unroll
        for (int ni = 0; ni < 4; ni++) acc[mi][ni] = (f32x4)(0.f);

    const int srow0 = wv * 32;

    for (int k0 = 0; k0 < K; k0 += 32) {
        __syncthreads();
#pragma unroll
        for (int ii = 0; ii < 2; ii++) {
            const int r   = srow0 + ii * 16 + (lane >> 2);
            const int ug  = (((lane & 3) ^ ((r >> 1) & 3)) << 3);
            const size_t ga = (size_t)(row0 + r) * lda + k0 + ug;
            const size_t gw = (size_t)(col0 + r) * K   + k0 + ug;
            const int lo  = (srow0 + ii * 16) * 32;
            __builtin_amdgcn_global_load_lds(
                (const __attribute__((address_space(1))) void*)(A1 + ga),
                (__attribute__((address_space(3))) void*)&lds[0 * 4096 + lo], 16, 0, 0);
            __builtin_amdgcn_global_load_lds(
                (const __attribute__((address_space(1))) void*)(A2 + ga),
                (__attribute__((address_space(3))) void*)&lds[1 * 4096 + lo], 16, 0, 0);
            __builtin_amdgcn_global_load_lds(
                (const __attribute__((address_space(1))) void*)(A3 + ga),
                (__attribute__((address_space(3))) void*)&lds[2 * 4096 + lo], 16, 0, 0);
            __builtin_amdgcn_global_load_lds(
                (const __attribute__((address_space(1))) void*)(W1 + gw),
                (__attribute__((address_space(3))) void*)&lds[3 * 4096 + lo], 16, 0, 0);
            __builtin_amdgcn_global_load_lds(
                (const __attribute__((address_space(1))) void*)(W2 + gw),
                (__attribute__((address_space(3))) void*)&lds[4 * 4096 + lo], 16, 0, 0);
            __builtin_amdgcn_global_load_lds(
                (const __attribute__((address_space(1))) void*)(W3 + gw),
                (__attribute__((address_space(3))) void*)&lds[5 * 4096 + lo], 16, 0, 0);
        }
        __syncthreads();

        s16x8 a1[4], a2[4], a3[4], w1[4], w2[4], w3[4];
#pragma unroll
        for (int mi = 0; mi < 4; mi++) {
            const int m  = wm * 64 + mi * 16 + (lane & 15);
            const int pu = ((g ^ ((m >> 1) & 3)) << 3);
            a1[mi] = *(const s16x8*)&lds[0 * 4096 + m * 32 + pu];
            a2[mi] = *(const s16x8*)&lds[1 * 4096 + m * 32 + pu];
            a3[mi] = *(const s16x8*)&lds[2 * 4096 + m * 32 + pu];
            const int n  = wn * 64 + mi * 16 + (lane & 15);
            const int pn = ((g ^ ((n >> 1) & 3)) << 3);
            w1[mi] = *(const s16x8*)&lds[3 * 4096 + n * 32 + pn];
            w2[mi] = *(const s16x8*)&lds[4 * 4096 + n * 32 + pn];
            w3[mi] = *(const s16x8*)&lds[5 * 4096 + n * 32 + pn];
        }
        __builtin_amdgcn_s_setprio(1);
#pragma unroll
        for (int mi = 0; mi < 4; mi++)
#pragma unroll
            for (int ni = 0; ni < 4; ni++) {
                acc[mi][ni] = __builtin_amdgcn_mfma_f32_16x16x32_bf16(a1[mi], w1[ni], acc[mi][ni], 0, 0, 0);
                acc[mi][ni] = __builtin_amdgcn_mfma_f32_16x16x32_bf16(a2[mi], w1[ni], acc[mi][ni], 0, 0, 0);
                acc[mi][ni] = __builtin_amdgcn_mfma_f32_16x16x32_bf16(a1[mi], w2[ni], acc[mi][ni], 0, 0, 0);
                acc[mi][ni] = __builtin_amdgcn_mfma_f32_16x16x32_bf16(a2[mi], w2[ni], acc[mi][ni], 0, 0, 0);
                acc[mi][ni] = __builtin_amdgcn_mfma_f32_16x16x32_bf16(a1[mi], w3[ni], acc[mi][ni], 0, 0, 0);
                acc[mi][ni] = __builtin_amdgcn_mfma_f32_16x16x32_bf16(a3[mi], w1[ni], acc[mi][ni], 0, 0, 0);
            }
        __builtin_amdgcn_s_setprio(0);
    }

#pragma unroll
    for (int mi = 0; mi < 4; mi++) {
#pragma unroll
        for (int ni = 0; ni < 4; ni++) {
#pragma unroll
            for (int r = 0; r < 4; r++) {
                const int row = row0 + wm * 64 + mi * 16 + g * 4 + r;
                const int col = col0 + wn * 64 + ni * 16 + (lane & 15);
                float v = acc[mi][ni][r];
                outf[(size_t)row * N + col] = v;
                unsigned short h = f2bf(v);
                outp[(size_t)row * N + col] =
                    (unsigned)h | ((unsigned)f2bf(v - bf2f(h)) << 16);
            }
        }
    }
}

// ---------------------------------------------------------------------------
// fp32 -> bf16 split converter (+ optional fp32 copy)
// ---------------------------------------------------------------------------
__global__ __launch_bounds__(256) void cvt_k(
    const float* __restrict__ in, ushort_t* __restrict__ o1,
    ushort_t* __restrict__ o2, ushort_t* __restrict__ o3,
    float* __restrict__ ocopy, int n4)
{
    int i = blockIdx.x * 256 + threadIdx.x;
    if (i >= n4) return;
    float4 v = ((const float4*)in)[i];
    if (ocopy) ((float4*)ocopy)[i] = v;
    float vv[4] = {v.x, v.y, v.z, v.w};
    union { unsigned short us[4]; ushort4 v4; } H, L, M;
#pragma unroll
    for (int q = 0; q < 4; q++) {
        unsigned short a = f2bf(vv[q]);
        float r1 = vv[q] - bf2f(a);
        unsigned short b = f2bf(r1);
        H.us[q] = a; L.us[q] = b;
        M.us[q] = f2bf(r1 - bf2f(b));
    }
    ((ushort4*)o1)[i] = H.v4;
    ((ushort4*)o2)[i] = L.v4;
    if (o3) ((ushort4*)o3)[i] = M.v4;
}

// ---------------------------------------------------------------------------
// Batched per-layer weight split conversion (one launch, 2816 blocks)
// ---------------------------------------------------------------------------
__global__ __launch_bounds__(256) void cvtw_k(
    const float* __restrict__ Wqk_i, const float* __restrict__ Wv_i,
    const float* __restrict__ Wout_i, const float* __restrict__ W1_i,
    const float* __restrict__ W2_i,
    ushort_t* __restrict__ wq1, ushort_t* __restrict__ wq2, ushort_t* __restrict__ wq3,
    ushort_t* __restrict__ wvh, ushort_t* __restrict__ wvl,
    ushort_t* __restrict__ woh, ushort_t* __restrict__ wol,
    ushort_t* __restrict__ w1h, ushort_t* __restrict__ w1l,
    ushort_t* __restrict__ w2h, ushort_t* __restrict__ w2l)
{
    const int blk = blockIdx.x;
    const float* in;
    ushort_t *o1, *o2, *o3 = nullptr;
    int i;
    if (blk < 256)       { in = Wqk_i;  o1 = wq1; o2 = wq2; o3 = wq3; i = blk * 256; }
    else if (blk < 512)  { in = Wv_i;   o1 = wvh; o2 = wvl; i = (blk - 256) * 256; }
    else if (blk < 768)  { in = Wout_i; o1 = woh; o2 = wol; i = (blk - 512) * 256; }
    else if (blk < 1792) { in = W1_i;   o1 = w1h; o2 = w1l; i = (blk - 768) * 256; }
    else                 { in = W2_i;   o1 = w2h; o2 = w2l; i = (blk - 1792) * 256; }
    i += threadIdx.x;
    float4 v = ((const float4*)in)[i];
    float vv[4] = {v.x, v.y, v.z, v.w};
    union { unsigned short us[4]; ushort4 v4; } H, L, M;
#pragma unroll
    for (int q = 0; q < 4; q++) {
        unsigned short a = f2bf(vv[q]);
        float r1 = vv[q] - bf2f(a);
        unsigned short b = f2bf(r1);
        H.us[q] = a; L.us[q] = b;
        M.us[q] = f2bf(r1 - bf2f(b));
    }
    ((ushort4*)o1)[i] = H.v4;
    ((ushort4*)o2)[i] = L.v4;
    if (o3) ((ushort4*)o3)[i] = M.v4;
}

// ---------------------------------------------------------------------------
// Bucket kernel v2 (all 4 rounds per block) — reads fp32 qk
// ---------------------------------------------------------------------------
__global__ __launch_bounds__(256) void bucket_k(
    const float* __restrict__ qk, const float* __restrict__ rot,
    int* __restrict__ bkt)
{
    __shared__ float rs[NH][64][32];    // 32 KB
    const int bh = blockIdx.y;
    const int t = blockIdx.x * 256 + threadIdx.x;
    for (int i = threadIdx.x; i < NH * 64 * 32; i += 256) {
        int r = i >> 11, f = (i >> 5) & 63, j = i & 31;
        rs[r][f][j] = rot[(f * NH + r) * 32 + j];
    }
    __syncthreads();
    const int b = bh >> 3, h = bh & 7;
    const float* q = qk + ((size_t)(b * TT + t)) * DD + h * DHH;
    float qv[64];
#pragma unroll
    for (int f4 = 0; f4 < 16; f4++) {
        float4 tmp = ((const float4*)q)[f4];
        qv[f4 * 4 + 0] = tmp.x; qv[f4 * 4 + 1] = tmp.y;
        qv[f4 * 4 + 2] = tmp.z; qv[f4 * 4 + 3] = tmp.w;
    }
    for (int r = 0; r < NH; r++) {
        float rv[32];
#pragma unroll
        for (int j = 0; j < 32; j++) rv[j] = 0.f;
        for (int f = 0; f < 64; f++) {
            float qf = qv[f];
#pragma unroll
            for (int j = 0; j < 32; j++) rv[j] = fmaf(qf, rs[r][f][j], rv[j]);
        }
        float best = rv[0];
        int bi = 0;
#pragma unroll
        for (int j = 1; j < 32; j++) { if (rv[j] > best) { best = rv[j]; bi = j; } }
#pragma unroll
        for (int j = 0; j < 32; j++) { float v = -rv[j]; if (v > best) { best = v; bi = 32 + j; } }
        bkt[((size_t)bh * NH + r) * TT + t] = bi;
    }
}

// ---------------------------------------------------------------------------
// Parallel stable counting sort per (bh, round). (verified R4)
// ---------------------------------------------------------------------------
__global__ __launch_bounds__(256) void sort_k(
    const int* __restrict__ bkt, int* __restrict__ st)
{
    __shared__ int lb[TT];
    __shared__ unsigned short cnt[128][64];
    __shared__ int base[64];
    const int r = blockIdx.x, bh = blockIdx.y;
    const int tid = threadIdx.x;
    const int* src = bkt + ((size_t)bh * NH + r) * TT;

    const int4* s4 = (const int4*)src;
    int4* l4 = (int4*)lb;
#pragma unroll
    for (int q = 0; q < 4; q++) l4[tid + q * 256] = s4[tid + q * 256];
    unsigned* cz = (unsigned*)cnt;
#pragma unroll
    for (int q = 0; q < 16; q++) cz[tid + q * 256] = 0;
    __syncthreads();

    if (tid < 128) {
        for (int it = 0; it < 32; it++) {
            int bb = lb[tid * 32 + it];
            cnt[tid][bb]++;
        }
    }
    __syncthreads();

    if (tid < 64) {
        const int bb = tid;
        int run = 0;
        for (int s = 0; s < 128; s++) {
            int t = cnt[s][bb];
            cnt[s][bb] = (unsigned short)run;
            run += t;
        }
        int inc = run;
#pragma unroll
        for (int off = 1; off < 64; off <<= 1) {
            int n = __shfl_up(inc, off, 64);
            if (tid >= off) inc += n;
        }
        base[bb] = inc - run;
    }
    __syncthreads();

    if (tid < 128) {
        int* dst = st + (size_t)bh * (NH * TT) + (size_t)r * TT;
        for (int it = 0; it < 32; it++) {
            int t = tid * 32 + it;
            int bb = lb[t];
            int pos = base[bb] + (int)cnt[tid][bb];
            cnt[tid][bb]++;
            dst[pos] = t;
        }
    }
}

// ---------------------------------------------------------------------------
// Attention v6: packed u32 inputs; bh pinned to one XCD for K/V L2 reuse.
// 1-D grid of 2048 blocks: XCD = bid%8 (HW round-robin) handles bhl = bid&7,
// chunk c = bid>>3. Per-XCD working set (one bh's K+V) = 2MB < 4MB L2.
// ---------------------------------------------------------------------------
__global__ __launch_bounds__(256, 2) void attn_k(
    const unsigned* __restrict__ qkp, const unsigned* __restrict__ vp,
    const int* __restrict__ st, float* __restrict__ obuf,
    float* __restrict__ lseb, int bh0)
{
    __shared__ __align__(16) ushort_t ksh[128 * 72];
    __shared__ __align__(16) ushort_t ksl[128 * 72];
    __shared__ __align__(16) unsigned vsp[128 * 66];
    __shared__ float invn[128];
    __shared__ int   tks[128];

    const int bid = blockIdx.x;
    const int bhl = bid & 7;
    const int c   = bid >> 3;
    const int bh  = bh0 + bhl;
    const int b   = bh >> 3, h = bh & 7;
    const int tid = threadIdx.x;
    const int* stb = st + (size_t)bh * (NH * TT);

    if (tid < 128) {
        int cc = (tid < 64) ? c : ((c + NC - 1) & (NC - 1));
        tks[tid] = stb[cc * 64 + (tid & 63)];
    }
    __syncthreads();

    {   // stage K (unpack hi/lo) + V (verbatim) + inv k-norms
        const int row = tid >> 1, c0 = (tid & 1) * 32;
        const int t = tks[row];
        const uint4* kg = (const uint4*)(qkp + ((size_t)(b * TT + t)) * DD + h * DHH + c0);
        const uint4* vg = (const uint4*)(vp  + ((size_t)(b * TT + t)) * DD + h * DHH + c0);
        unsigned kp[32];
        uint4 vq[8];
        float ss = 0.f;
#pragma unroll
        for (int q = 0; q < 8; q++) {
            uint4 kq = kg[q];
            kp[4 * q + 0] = kq.x; kp[4 * q + 1] = kq.y;
            kp[4 * q + 2] = kq.z; kp[4 * q + 3] = kq.w;
            vq[q] = vg[q];
        }
#pragma unroll
        for (int e = 0; e < 32; e++) {
            float f = __uint_as_float(kp[e] << 16) + __uint_as_float(kp[e] & 0xffff0000u);
            ss = fmaf(f, f, ss);
        }
        ss += __shfl_xor(ss, 1);
        if ((tid & 1) == 0) invn[row] = 1.0f / fmaxf(sqrtf(ss), 1e-12f);

        unsigned hw[16], lw[16];
#pragma unroll
        for (int e = 0; e < 16; e++) {
            hw[e] = (kp[2 * e] & 0xffffu) | (kp[2 * e + 1] << 16);
            lw[e] = (kp[2 * e] >> 16) | (kp[2 * e + 1] & 0xffff0000u);
        }
        uint4* kdh = (uint4*)&ksh[row * 72 + c0];
        uint4* kdl = (uint4*)&ksl[row * 72 + c0];
#pragma unroll
        for (int q = 0; q < 4; q++) {
            kdh[q] = make_uint4(hw[4 * q], hw[4 * q + 1], hw[4 * q + 2], hw[4 * q + 3]);
            kdl[q] = make_uint4(lw[4 * q], lw[4 * q + 1], lw[4 * q + 2], lw[4 * q + 3]);
        }
        uint2* vd = (uint2*)&vsp[row * 66 + c0];
#pragma unroll
        for (int q = 0; q < 8; q++) {
            vd[2 * q]     = make_uint2(vq[q].x, vq[q].y);
            vd[2 * q + 1] = make_uint2(vq[q].z, vq[q].w);
        }
    }
    __syncthreads();

    const int lane = tid & 63;
    const int wv   = tid >> 6;
    const int cc16 = lane & 15;
    const int g    = lane >> 4;
    const int rr   = c >> 6;

    f32x4 stt[8];
#pragma unroll
    for (int jt = 0; jt < 8; jt++) stt[jt] = (f32x4)(0.f);

    const int qrow = wv * 16 + cc16;
#pragma unroll
    for (int ks = 0; ks < 2; ks++) {
        s16x8 qh = *(const s16x8*)&ksh[qrow * 72 + ks * 32 + g * 8];
        s16x8 ql = *(const s16x8*)&ksl[qrow * 72 + ks * 32 + g * 8];
        __builtin_amdgcn_s_setprio(1);
#pragma unroll
        for (int jt = 0; jt < 8; jt++) {
            const int krow = jt * 16 + cc16;
            s16x8 ah = *(const s16x8*)&ksh[krow * 72 + ks * 32 + g * 8];
            s16x8 al = *(const s16x8*)&ksl[krow * 72 + ks * 32 + g * 8];
            stt[jt] = __builtin_amdgcn_mfma_f32_16x16x32_bf16(ah, qh, stt[jt], 0, 0, 0);
            stt[jt] = __builtin_amdgcn_mfma_f32_16x16x32_bf16(al, qh, stt[jt], 0, 0, 0);
            stt[jt] = __builtin_amdgcn_mfma_f32_16x16x32_bf16(ah, ql, stt[jt], 0, 0, 0);
        }
        __builtin_amdgcn_s_setprio(0);
    }

    const int tqi = tks[wv * 16 + cc16];
    float m = -INFINITY;
#pragma unroll
    for (int jt = 0; jt < 8; jt++) {
#pragma unroll
        for (int r4 = 0; r4 < 4; r4++) {
            const int j = jt * 16 + g * 4 + r4;
            float d = stt[jt][r4] * invn[j] * 0.125f;
            if (tqi == tks[j]) d = -5e4f;
            stt[jt][r4] = d;
            m = fmaxf(m, d);
        }
    }
    m = fmaxf(m, __shfl_xor(m, 16));
    m = fmaxf(m, __shfl_xor(m, 32));
    float s = 0.f;
#pragma unroll
    for (int jt = 0; jt < 8; jt++) {
#pragma unroll
        for (int r4 = 0; r4 < 4; r4++) {
            float e = expf(stt[jt][r4] - m);
            stt[jt][r4] = e;
            s += e;
        }
    }
    s += __shfl_xor(s, 16);
    s += __shfl_xor(s, 32);
    const float is = 1.0f / s;
    if (g == 0) lseb[((size_t)bh * NH + rr) * TT + tqi] = m + logf(s);

    unsigned ph[8][2], pl[8][2];
#pragma unroll
    for (int jt = 0; jt < 8; jt++) {
#pragma unroll
        for (int w2 = 0; w2 < 2; w2++) {
            float p0 = stt[jt][2 * w2] * is;
            float p1 = stt[jt][2 * w2 + 1] * is;
            unsigned short h0 = f2bf(p0), h1 = f2bf(p1);
            ph[jt][w2] = (unsigned)h0 | ((unsigned)h1 << 16);
            pl[jt][w2] = (unsigned)f2bf(p0 - bf2f(h0)) | ((unsigned)f2bf(p1 - bf2f(h1)) << 16);
        }
    }

    f32x4 occ[4];
#pragma unroll
    for (int nt = 0; nt < 4; nt++) occ[nt] = (f32x4)(0.f);

    const int srcLow  = ((g & 1) << 5) + cc16;
    const int srcHigh = srcLow + 16;
    const bool hiT = (lane & 32) != 0;

#pragma unroll
    for (int ks = 0; ks < 4; ks++) {
        U4 Phi, Plo;
        {
            unsigned a0 = (unsigned)__shfl((int)ph[2 * ks][0], srcLow);
            unsigned a1 = (unsigned)__shfl((int)ph[2 * ks][1], srcLow);
            unsigned a2 = (unsigned)__shfl((int)ph[2 * ks][0], srcHigh);
            unsigned a3 = (unsigned)__shfl((int)ph[2 * ks][1], srcHigh);
            unsigned b0 = (unsigned)__shfl((int)ph[2 * ks + 1][0], srcLow);
            unsigned b1 = (unsigned)__shfl((int)ph[2 * ks + 1][1], srcLow);
            unsigned b2 = (unsigned)__shfl((int)ph[2 * ks + 1][0], srcHigh);
            unsigned b3 = (unsigned)__shfl((int)ph[2 * ks + 1][1], srcHigh);
            Phi.u[0] = hiT ? b0 : a0; Phi.u[1] = hiT ? b1 : a1;
            Phi.u[2] = hiT ? b2 : a2; Phi.u[3] = hiT ? b3 : a3;
            unsigned c0 = (unsigned)__shfl((int)pl[2 * ks][0], srcLow);
            unsigned c1 = (unsigned)__shfl((int)pl[2 * ks][1], srcLow);
            unsigned c2 = (unsigned)__shfl((int)pl[2 * ks][0], srcHigh);
            unsigned c3 = (unsigned)__shfl((int)pl[2 * ks][1], srcHigh);
            unsigned d0 = (unsigned)__shfl((int)pl[2 * ks + 1][0], srcLow);
            unsigned d1 = (unsigned)__shfl((int)pl[2 * ks + 1][1], srcLow);
            unsigned d2 = (unsigned)__shfl((int)pl[2 * ks + 1][0], srcHigh);
            unsigned d3 = (unsigned)__shfl((int)pl[2 * ks + 1][1], srcHigh);
            Plo.u[0] = hiT ? d0 : c0; Plo.u[1] = hiT ? d1 : c1;
            Plo.u[2] = hiT ? d2 : c2; Plo.u[3] = hiT ? d3 : c3;
        }
#pragma unroll
        for (int nt = 0; nt < 4; nt++) {
            unsigned u[8];
#pragma unroll
            for (int e = 0; e < 8; e++)
                u[e] = vsp[(32 * ks + 8 * g + e) * 66 + nt * 16 + cc16];
            U4 Vh, Vl;
#pragma unroll
            for (int m2 = 0; m2 < 4; m2++) {
                Vh.u[m2] = (u[2 * m2] & 0xffffu) | (u[2 * m2 + 1] << 16);
                Vl.u[m2] = (u[2 * m2] >> 16) | (u[2 * m2 + 1] & 0xffff0000u);
            }
            __builtin_amdgcn_s_setprio(1);
            occ[nt] = __builtin_amdgcn_mfma_f32_16x16x32_bf16(Phi.v, Vh.v, occ[nt], 0, 0, 0);
            occ[nt] = __builtin_amdgcn_mfma_f32_16x16x32_bf16(Plo.v, Vh.v, occ[nt], 0, 0, 0);
            occ[nt] = __builtin_amdgcn_mfma_f32_16x16x32_bf16(Phi.v, Vl.v, occ[nt], 0, 0, 0);
            __builtin_amdgcn_s_setprio(0);
        }
    }

#pragma unroll
    for (int r4 = 0; r4 < 4; r4++) {
        const int i = wv * 16 + g * 4 + r4;
        const int ti = tks[i];
        float* dst = obuf + (((size_t)bhl * NH + rr) * TT + ti) * DHH + cc16;
        dst[0]  = occ[0][r4];
        dst[16] = occ[1][r4];
        dst[32] = occ[2][r4];
        dst[48] = occ[3][r4];
    }
}

// ---------------------------------------------------------------------------
// Combine rounds for an 8-bh strip
// ---------------------------------------------------------------------------
__global__ __launch_bounds__(256) void combine_k(
    const float* __restrict__ obuf, const float* __restrict__ lseb,
    ushort_t* __restrict__ att, int bh0)
{
    int idx = blockIdx.x * 256 + threadIdx.x;
    int d = idx & 63;
    int t = (idx >> 6) & (TT - 1);
    int bhl = idx >> 18;
    int bh = bh0 + bhl;
    float l0 = lseb[((size_t)bh * NH + 0) * TT + t];
    float l1 = lseb[((size_t)bh * NH + 1) * TT + t];
    float l2 = lseb[((size_t)bh * NH + 2) * TT + t];
    float l3 = lseb[((size_t)bh * NH + 3) * TT + t];
    float m = fmaxf(fmaxf(l0, l1), fmaxf(l2, l3));
    float e0 = expf(l0 - m), e1 = expf(l1 - m), e2 = expf(l2 - m), e3 = expf(l3 - m);
    float inv = 1.0f / (e0 + e1 + e2 + e3);
    float o0 = obuf[(((size_t)bhl * NH + 0) * TT + t) * DHH + d];
    float o1 = obuf[(((size_t)bhl * NH + 1) * TT + t) * DHH + d];
    float o2 = obuf[(((size_t)bhl * NH + 2) * TT + t) * DHH + d];
    float o3 = obuf[(((size_t)bhl * NH + 3) * TT + t) * DHH + d];
    float o = (e0 * o0 + e1 * o1 + e2 * o2 + e3 * o3) * inv;
    int b = bh >> 3, h = bh & 7;
    size_t base = (size_t)(b * TT + t) * 1024 + h * DHH + d;
    unsigned short hi = f2bf(o);
    att[base]       = hi;
    att[base + 512] = f2bf(o - bf2f(hi));
}

// ---------------------------------------------------------------------------
// LayerNorm over D=512; optional 3-way bf16 split output. Safe in-place.
// ---------------------------------------------------------------------------
__global__ __launch_bounds__(64) void ln_k(
    const float* __restrict__ in, const float* __restrict__ g,
    const float* __restrict__ be, float* __restrict__ out,
    ushort_t* __restrict__ oh, ushort_t* __restrict__ ol,
    ushort_t* __restrict__ ol2)
{
    const int row = blockIdx.x;
    const int tid = threadIdx.x;
    const float* x = in + (size_t)row * DD;
    float4 a = *(const float4*)(x + tid * 8);
    float4 b = *(const float4*)(x + tid * 8 + 4);
    float s = a.x + a.y + a.z + a.w + b.x + b.y + b.z + b.w;
#pragma unroll
    for (int o = 32; o >= 1; o >>= 1) s += __shfl_xor(s, o, 64);
    float mean = s * (1.0f / 512.0f);
    float dx[8];
    dx[0] = a.x - mean; dx[1] = a.y - mean; dx[2] = a.z - mean; dx[3] = a.w - mean;
    dx[4] = b.x - mean; dx[5] = b.y - mean; dx[6] = b.z - mean; dx[7] = b.w - mean;
    float ss = 0.f;
#pragma unroll
    for (int q = 0; q < 8; q++) ss += dx[q] * dx[q];
#pragma unroll
    for (int o = 32; o >= 1; o >>= 1) ss += __shfl_xor(ss, o, 64);
    float var = ss * (1.0f / 512.0f);
    float inv = 1.0f / sqrtf(var + 1e-6f);
    const float* gp = g + tid * 8;
    const float* bp = be + tid * 8;
    float y[8];
#pragma unroll
    for (int q = 0; q < 8; q++) y[q] = dx[q] * inv * gp[q] + bp[q];
    float* yp = out + (size_t)row * DD + tid * 8;
    *(float4*)(yp)     = make_float4(y[0], y[1], y[2], y[3]);
    *(float4*)(yp + 4) = make_float4(y[4], y[5], y[6], y[7]);
    if (oh) {
        union { unsigned short us[8]; ushort4 v4[2]; } H, L, M;
#pragma unroll
        for (int q = 0; q < 8; q++) {
            unsigned short h = f2bf(y[q]);
            float r1 = y[q] - bf2f(h);
            unsigned short l = f2bf(r1);
            H.us[q] = h; L.us[q] = l;
            M.us[q] = f2bf(r1 - bf2f(l));
        }
        size_t e = (size_t)row * DD + tid * 8;
        *(ushort4*)(oh + e)      = H.v4[0];
        *(ushort4*)(oh + e + 4)  = H.v4[1];
        *(ushort4*)(ol + e)      = L.v4[0];
        *(ushort4*)(ol + e + 4)  = L.v4[1];
        *(ushort4*)(ol2 + e)     = M.v4[0];
        *(ushort4*)(ol2 + e + 4) = M.v4[1];
    }
}

// ---------------------------------------------------------------------------
extern "C" void kernel_launch(void* const* d_in, const int* in_sizes, int n_in,
                              void* d_out, int out_size, void* d_ws, size_t ws_size,
                              hipStream_t stream)
{
    const float* src  = (const float*)d_in[0];
    const float* rots = (const float*)d_in[1];
    const float* Wqk  = (const float*)d_in[2];
    const float* Wv   = (const float*)d_in[3];
    const float* Wout = (const float*)d_in[4];
    const float* bout = (const float*)d_in[5];
    const float* W1   = (const float*)d_in[6];
    const float* b1   = (const float*)d_in[7];
    const float* W2   = (const float*)d_in[8];
    const float* b2   = (const float*)d_in[9];
    const float* g2   = (const float*)d_in[10];
    const float* be2  = (const float*)d_in[11];
    const float* gf   = (const float*)d_in[12];
    const float* bf   = (const float*)d_in[13];
    float* out = (float*)d_out;

    // ---- workspace layout (~234 MB) ----
    char* w = (char*)d_ws;
    const size_t SZ_X = (size_t)MROWS * DD * 4;               // 33.55 MB
    const size_t XHALF = (size_t)MROWS * DD;
    float*    x     = (float*)(w);
    ushort_t* xs    = (ushort_t*)(w + SZ_X);
    ushort_t* xh    = xs;
    ushort_t* xl    = xs + XHALF;
    ushort_t* xl2   = xs + 2 * XHALF;
    char*     p     = w + SZ_X + 3 * XHALF * 2;
    float*    qkb   = (float*)(p);
    ushort_t* attb  = (ushort_t*)(p);
    unsigned* vp    = (unsigned*)(p + SZ_X);
    unsigned* qkp   = (unsigned*)(p + 2 * SZ_X);
    float*    obuf  = (float*)(p + 3 * SZ_X);
    ushort_t* h1h   = (ushort_t*)(p);                         // FFN: spans p..p+2SZ_X
    ushort_t* h1l   = (ushort_t*)(p + 2 * SZ_X);              // FFN: spans p+2..p+4SZ_X
    ushort_t* wb    = (ushort_t*)(p + 4 * SZ_X);
    char*     tail  = p + 4 * SZ_X + 6029312 * 2;
    int*      bkt   = (int*)(tail);
    int*      st    = (int*)(tail + (size_t)BHH * NH * TT * 4);
    float*    lseb  = (float*)(tail + 2 * (size_t)BHH * NH * TT * 4);

    ushort_t* wvh = wb;            ushort_t* wvl = wb + 262144;
    ushort_t* woh = wb + 524288;   ushort_t* wol = wb + 786432;
    ushort_t* w1h = wb + 1048576;  ushort_t* w1l = wb + 2097152;
    ushort_t* w2h = wb + 3145728;  ushort_t* w2l = wb + 4194304;
    ushort_t* wq1 = wb + 5242880;  ushort_t* wq2 = wb + 5505024;
    ushort_t* wq3 = wb + 5767168;

    // x copy + 3-way split in one pass
    cvt_k<<<(MROWS * DD / 4 + 255) / 256, 256, 0, stream>>>(src, xh, xl, xl2, x,
                                                            MROWS * DD / 4);

    for (int i = 0; i < LLAY; i++) {
        const float* Wqk_i = Wqk + (size_t)i * DD * DD;
        const float* Wv_i  = Wv  + (size_t)i * DD * DD;
        const float* Wout_i= Wout+ (size_t)i * DD * DD;
        const float* bout_i= bout+ (size_t)i * DD;
        const float* W1_i  = W1  + (size_t)i * DFFN * DD;
        const float* b1_i  = b1  + (size_t)i * DFFN;
        const float* W2_i  = W2  + (size_t)i * DD * DFFN;
        const float* b2_i  = b2  + (size_t)i * DD;
        const float* g2_i  = g2  + (size_t)i * DD;
        const float* be2_i = be2 + (size_t)i * DD;
        const float* rot_i = rots + (size_t)i * DHH * NH * 32;

        cvtw_k<<<2816, 256, 0, stream>>>(Wqk_i, Wv_i, Wout_i, W1_i, W2_i,
                                         wq1, wq2, wq3, wvh, wvl, woh, wol,
                                         w1h, w1l, w2h, w2l);

        // qk = x @ Wqk^T  (bf16x6, fp32 for bucket + packed for attn)
        gemm_bf6_k<<<dim3(4, 128), 256, 0, stream>>>(xh, xl, xl2, DD, wq1, wq2, wq3,
                                                     qkb, qkp, MROWS, DD, DD);
        // v = x @ Wv^T  (bf16x3, 2-phase, packed output)
        gemm_bf3_k<<<dim3(4, 128), 256, 0, stream>>>(xh, xl, DD, wvh, wvl, DD,
                                                     nullptr, nullptr,
                                                     nullptr, nullptr, nullptr, vp,
                                                     MROWS, DD, DD, 0);
        bucket_k<<<dim3(16, BHH), 256, 0, stream>>>(qkb, rot_i, bkt);
        sort_k<<<dim3(NH, BHH), 256, 0, stream>>>(bkt, st);

        // attention in 4 strips of 8 bh; bh pinned to XCD; combine -> att hi/lo
        for (int s = 0; s < 4; s++) {
            attn_k<<<2048, 256, 0, stream>>>(qkp, vp, st, obuf, lseb, s * 8);
            combine_k<<<8192, 256, 0, stream>>>(obuf, lseb, attb, s * 8);
        }

        // x = x + att @ Wout^T + bout ; emit x hi/lo (for FFN input)
        gemm_bf3_k<<<dim3(4, 128), 256, 0, stream>>>(attb, attb + 512, 1024, woh, wol, DD,
                                                     bout_i, x, x, xh, xl, nullptr,
                                                     MROWS, DD, DD, 0);
        // FFN1 full-N: h1 = relu(x @ W1^T + b1)
        gemm_bf3_k<<<dim3(16, 128), 256, 0, stream>>>(xh, xl, DD, w1h, w1l, DD,
                                                      b1_i, nullptr,
                                                      nullptr, h1h, h1l, nullptr,
                                                      MROWS, DFFN, DD, 1);
        // FFN2 full-K: x = x + h1 @ W2^T + b2  (in-place residual on x)
        gemm_bf3_k<<<dim3(4, 128), 256, 0, stream>>>(h1h, h1l, DFFN, w2h, w2l, DFFN,
                                                     b2_i, x,
                                                     x, nullptr, nullptr, nullptr,
                                                     MROWS, DD, DFFN, 0);
        // x = LN(x) in-place; emit 3-way split for next layer's qk/v
        ln_k<<<MROWS, 64, 0, stream>>>(x, g2_i, be2_i, x, xh, xl, xl2);
    }
    ln_k<<<MROWS, 64, 0, stream>>>(x, gf, bf, out, nullptr, nullptr, nullptr);
}

// Round 14
// 2978.074 us; speedup vs baseline: 1.0719x; 1.0195x over previous
//
#include <hip/hip_runtime.h>
#include <math.h>

#define TT    4096
#define DD    512
#define HH    8
#define DHH   64
#define NH    4
#define LLAY  4
#define DFFN  2048
#define BHH   32          // B*H
#define NC    256         // chunks per bh (NH*NB)
#define MROWS 16384       // B*T

typedef __attribute__((ext_vector_type(8))) short s16x8;
typedef __attribute__((ext_vector_type(4))) float f32x4;
typedef unsigned short ushort_t;

union U4 { unsigned u[4]; s16x8 v; };

__device__ __forceinline__ unsigned short f2bf(float f) {
    unsigned u = __float_as_uint(f);
    unsigned r = (u + 0x7FFFu + ((u >> 16) & 1u)) >> 16;
    return (unsigned short)r;
}
__device__ __forceinline__ float bf2f(unsigned short h) {
    return __uint_as_float(((unsigned)h) << 16);
}

// XCD-aware bijective swizzle (T1, m157): nwg must be divisible by 8.
__device__ __forceinline__ void xcd_swz(int& bx, int& by) {
    const int gx = gridDim.x;
    const int nwg = gx * gridDim.y;
    const int flat = by * gx + bx;
    const int q = nwg >> 3;
    const int swz = (flat & 7) * q + (flat >> 3);
    bx = swz % gx;
    by = swz / gx;
}

// ---------------------------------------------------------------------------
// bf16x3 MFMA GEMM, 2-phase double-buffered, 128x128 tile (verified R9+)
// ---------------------------------------------------------------------------
__global__ __launch_bounds__(256) void gemm_bf3_k(
    const ushort_t* __restrict__ Ah, const ushort_t* __restrict__ Al, int lda,
    const ushort_t* __restrict__ Wh, const ushort_t* __restrict__ Wl, int ldw,
    const float* __restrict__ bias, const float* __restrict__ resid,
    float* __restrict__ outf, ushort_t* __restrict__ outh, ushort_t* __restrict__ outl,
    unsigned* __restrict__ outp,
    int M, int N, int K, int relu)
{
    __shared__ __align__(16) ushort_t lds[2][4 * 128 * 32];   // 2 x 32KB
    const int tid  = threadIdx.x;
    const int lane = tid & 63;
    const int wv   = tid >> 6;
    const int wm   = wv >> 1, wn = wv & 1;
    int bx = blockIdx.x, by = blockIdx.y;
    xcd_swz(bx, by);
    const int row0 = by * 128, col0 = bx * 128;
    const int g    = lane >> 4;
    const int srow0 = wv * 32;

    f32x4 acc[4][4];
#pragma unroll
    for (int mi = 0; mi < 4; mi++)
#pragma unroll
        for (int ni = 0; ni < 4; ni++) acc[mi][ni] = (f32x4)(0.f);

    auto STAGE = [&](int buf, int k0) {
#pragma unroll
        for (int ii = 0; ii < 2; ii++) {
            const int r   = srow0 + ii * 16 + (lane >> 2);
            const int ug  = (((lane & 3) ^ ((r >> 1) & 3)) << 3);
            const size_t ga = (size_t)(row0 + r) * lda + k0 + ug;
            const size_t gw = (size_t)(col0 + r) * ldw + k0 + ug;
            const int lo  = (srow0 + ii * 16) * 32;
            __builtin_amdgcn_global_load_lds(
                (const __attribute__((address_space(1))) void*)(Ah + ga),
                (__attribute__((address_space(3))) void*)&lds[buf][0 * 4096 + lo], 16, 0, 0);
            __builtin_amdgcn_global_load_lds(
                (const __attribute__((address_space(1))) void*)(Al + ga),
                (__attribute__((address_space(3))) void*)&lds[buf][1 * 4096 + lo], 16, 0, 0);
            __builtin_amdgcn_global_load_lds(
                (const __attribute__((address_space(1))) void*)(Wh + gw),
                (__attribute__((address_space(3))) void*)&lds[buf][2 * 4096 + lo], 16, 0, 0);
            __builtin_amdgcn_global_load_lds(
                (const __attribute__((address_space(1))) void*)(Wl + gw),
                (__attribute__((address_space(3))) void*)&lds[buf][3 * 4096 + lo], 16, 0, 0);
        }
    };

    const int nt = K >> 5;
    STAGE(0, 0);

    for (int t = 0; t < nt; ++t) {
        const int cur = t & 1;
        if (t + 1 < nt) {
            STAGE(cur ^ 1, (t + 1) << 5);
            asm volatile("s_waitcnt vmcnt(8)" ::: "memory");
        } else {
            asm volatile("s_waitcnt vmcnt(0)" ::: "memory");
        }
        __builtin_amdgcn_s_barrier();
        __builtin_amdgcn_sched_barrier(0);

        s16x8 ah[4], al[4], wh[4], wl[4];
#pragma unroll
        for (int mi = 0; mi < 4; mi++) {
            const int m  = wm * 64 + mi * 16 + (lane & 15);
            const int pu = ((g ^ ((m >> 1) & 3)) << 3);
            ah[mi] = *(const s16x8*)&lds[cur][0 * 4096 + m * 32 + pu];
            al[mi] = *(const s16x8*)&lds[cur][1 * 4096 + m * 32 + pu];
            const int n  = wn * 64 + mi * 16 + (lane & 15);
            const int pn = ((g ^ ((n >> 1) & 3)) << 3);
            wh[mi] = *(const s16x8*)&lds[cur][2 * 4096 + n * 32 + pn];
            wl[mi] = *(const s16x8*)&lds[cur][3 * 4096 + n * 32 + pn];
        }
        __builtin_amdgcn_s_setprio(1);
#pragma unroll
        for (int mi = 0; mi < 4; mi++)
#pragma unroll
            for (int ni = 0; ni < 4; ni++) {
                acc[mi][ni] = __builtin_amdgcn_mfma_f32_16x16x32_bf16(ah[mi], wh[ni], acc[mi][ni], 0, 0, 0);
                acc[mi][ni] = __builtin_amdgcn_mfma_f32_16x16x32_bf16(al[mi], wh[ni], acc[mi][ni], 0, 0, 0);
                acc[mi][ni] = __builtin_amdgcn_mfma_f32_16x16x32_bf16(ah[mi], wl[ni], acc[mi][ni], 0, 0, 0);
            }
        __builtin_amdgcn_s_setprio(0);

        __builtin_amdgcn_sched_barrier(0);
        __builtin_amdgcn_s_barrier();     // WAR: lds[cur] overwritten at t+1's STAGE
    }

#pragma unroll
    for (int mi = 0; mi < 4; mi++) {
#pragma unroll
        for (int ni = 0; ni < 4; ni++) {
#pragma unroll
            for (int r = 0; r < 4; r++) {
                const int row = row0 + wm * 64 + mi * 16 + g * 4 + r;
                const int col = col0 + wn * 64 + ni * 16 + (lane & 15);
                float v = acc[mi][ni][r];
                if (bias)  v += bias[col];
                if (relu)  v = fmaxf(v, 0.f);
                if (resid) v += resid[(size_t)row * N + col];
                if (outf)  outf[(size_t)row * N + col] = v;
                if (outh) {
                    unsigned short h = f2bf(v);
                    outh[(size_t)row * N + col] = h;
                    outl[(size_t)row * N + col] = f2bf(v - bf2f(h));
                }
                if (outp) {
                    unsigned short h = f2bf(v);
                    outp[(size_t)row * N + col] =
                        (unsigned)h | ((unsigned)f2bf(v - bf2f(h)) << 16);
                }
            }
        }
    }
}

// ---------------------------------------------------------------------------
// bf16x3 MFMA GEMM, 256x256 tile, 8 waves (2Mx4N), BK=32, 2-phase dbuf.
// Same sync structure & LDS swizzle as gemm_bf3_k; 96 MFMA/K-step/wave.
// LDS 128KB -> 1 block/CU (8 waves). For large-N GEMMs (FFN1).
// ---------------------------------------------------------------------------
__global__ __launch_bounds__(512) void gemm_bf3_256_k(
    const ushort_t* __restrict__ Ah, const ushort_t* __restrict__ Al, int lda,
    const ushort_t* __restrict__ Wh, const ushort_t* __restrict__ Wl, int ldw,
    const float* __restrict__ bias,
    ushort_t* __restrict__ outh, ushort_t* __restrict__ outl,
    int M, int N, int K, int relu)
{
    __shared__ __align__(16) ushort_t lds[2][4 * 256 * 32];   // 2 x 64KB
    const int tid  = threadIdx.x;
    const int lane = tid & 63;
    const int wv   = tid >> 6;          // 0..7
    const int wm   = wv >> 2;           // 0..1  (128-row half)
    const int wn   = wv & 3;            // 0..3  (64-col quarter)
    int bx = blockIdx.x, by = blockIdx.y;
    xcd_swz(bx, by);
    const int row0 = by * 256, col0 = bx * 256;
    const int g    = lane >> 4;
    const int srow0 = wv * 32;

    f32x4 acc[8][4];
#pragma unroll
    for (int mi = 0; mi < 8; mi++)
#pragma unroll
        for (int ni = 0; ni < 4; ni++) acc[mi][ni] = (f32x4)(0.f);

    // stage one 256x32 K-tile for all 4 streams; 8 loads/thread
    auto STAGE = [&](int buf, int k0) {
#pragma unroll
        for (int ii = 0; ii < 2; ii++) {
            const int r   = srow0 + ii * 16 + (lane >> 2);
            const int ug  = (((lane & 3) ^ ((r >> 1) & 3)) << 3);
            const size_t ga = (size_t)(row0 + r) * lda + k0 + ug;
            const size_t gw = (size_t)(col0 + r) * ldw + k0 + ug;
            const int lo  = (srow0 + ii * 16) * 32;
            __builtin_amdgcn_global_load_lds(
                (const __attribute__((address_space(1))) void*)(Ah + ga),
                (__attribute__((address_space(3))) void*)&lds[buf][0 * 8192 + lo], 16, 0, 0);
            __builtin_amdgcn_global_load_lds(
                (const __attribute__((address_space(1))) void*)(Al + ga),
                (__attribute__((address_space(3))) void*)&lds[buf][1 * 8192 + lo], 16, 0, 0);
            __builtin_amdgcn_global_load_lds(
                (const __attribute__((address_space(1))) void*)(Wh + gw),
                (__attribute__((address_space(3))) void*)&lds[buf][2 * 8192 + lo], 16, 0, 0);
            __builtin_amdgcn_global_load_lds(
                (const __attribute__((address_space(1))) void*)(Wl + gw),
                (__attribute__((address_space(3))) void*)&lds[buf][3 * 8192 + lo], 16, 0, 0);
        }
    };

    const int nt = K >> 5;
    STAGE(0, 0);

    for (int t = 0; t < nt; ++t) {
        const int cur = t & 1;
        if (t + 1 < nt) {
            STAGE(cur ^ 1, (t + 1) << 5);
            asm volatile("s_waitcnt vmcnt(8)" ::: "memory");
        } else {
            asm volatile("s_waitcnt vmcnt(0)" ::: "memory");
        }
        __builtin_amdgcn_s_barrier();
        __builtin_amdgcn_sched_barrier(0);

        s16x8 wh[4], wl[4];
#pragma unroll
        for (int ni = 0; ni < 4; ni++) {
            const int n  = wn * 64 + ni * 16 + (lane & 15);
            const int pn = ((g ^ ((n >> 1) & 3)) << 3);
            wh[ni] = *(const s16x8*)&lds[cur][2 * 8192 + n * 32 + pn];
            wl[ni] = *(const s16x8*)&lds[cur][3 * 8192 + n * 32 + pn];
        }
#pragma unroll
        for (int half = 0; half < 2; half++) {
            s16x8 ah[4], al[4];
#pragma unroll
            for (int mj = 0; mj < 4; mj++) {
                const int m  = wm * 128 + (half * 4 + mj) * 16 + (lane & 15);
                const int pu = ((g ^ ((m >> 1) & 3)) << 3);
                ah[mj] = *(const s16x8*)&lds[cur][0 * 8192 + m * 32 + pu];
                al[mj] = *(const s16x8*)&lds[cur][1 * 8192 + m * 32 + pu];
            }
            __builtin_amdgcn_s_setprio(1);
#pragma unroll
            for (int mj = 0; mj < 4; mj++)
#pragma unroll
                for (int ni = 0; ni < 4; ni++) {
                    acc[half * 4 + mj][ni] = __builtin_amdgcn_mfma_f32_16x16x32_bf16(ah[mj], wh[ni], acc[half * 4 + mj][ni], 0, 0, 0);
                    acc[half * 4 + mj][ni] = __builtin_amdgcn_mfma_f32_16x16x32_bf16(al[mj], wh[ni], acc[half * 4 + mj][ni], 0, 0, 0);
                    acc[half * 4 + mj][ni] = __builtin_amdgcn_mfma_f32_16x16x32_bf16(ah[mj], wl[ni], acc[half * 4 + mj][ni], 0, 0, 0);
                }
            __builtin_amdgcn_s_setprio(0);
        }

        __builtin_amdgcn_sched_barrier(0);
        __builtin_amdgcn_s_barrier();     // WAR before next STAGE overwrite
    }

#pragma unroll
    for (int mi = 0; mi < 8; mi++) {
#pragma unroll
        for (int ni = 0; ni < 4; ni++) {
#pragma unroll
            for (int r = 0; r < 4; r++) {
                const int row = row0 + wm * 128 + mi * 16 + g * 4 + r;
                const int col = col0 + wn * 64 + ni * 16 + (lane & 15);
                float v = acc[mi][ni][r];
                if (bias) v += bias[col];
                if (relu) v = fmaxf(v, 0.f);
                unsigned short h = f2bf(v);
                outh[(size_t)row * N + col] = h;
                outl[(size_t)row * N + col] = f2bf(v - bf2f(h));
            }
        }
    }
}

// ---------------------------------------------------------------------------
// bf16x6 MFMA GEMM (qk only): ~2^-26 rel err. Emits fp32 + packed hi/lo.
// ---------------------------------------------------------------------------
__global__ __launch_bounds__(256) void gemm_bf6_k(
    const ushort_t* __restrict__ A1, const ushort_t* __restrict__ A2,
    const ushort_t* __restrict__ A3, int lda,
    const ushort_t* __restrict__ W1, const ushort_t* __restrict__ W2,
    const ushort_t* __restrict__ W3,
    float* __restrict__ outf, unsigned* __restrict__ outp, int M, int N, int K)
{
    __shared__ __align__(16) ushort_t lds[6 * 128 * 32];   // A1,A2,A3,W1,W2,W3
    const int tid  = threadIdx.x;
    const int lane = tid & 63;
    const int wv   = tid >> 6;
    const int wm   = wv >> 1, wn = wv & 1;
    int bx = blockIdx.x, by = blockIdx.y;
    xcd_swz(bx, by);
    const int row0 = by * 128, col0 = bx * 128;
    const int g    = lane >> 4;

    f32x4 acc[4][4];
#pragma unroll
    for (int mi = 0; mi < 4; mi++)
#pragma unroll
        for (int ni = 0; ni < 4; ni++) acc[mi][ni] = (f32x4)(0.f);

    const int srow0 = wv * 32;

    for (int k0 = 0; k0 < K; k0 += 32) {
        __syncthreads();
#pragma unroll
        for (int ii = 0; ii < 2; ii++) {
            const int r   = srow0 + ii * 16 + (lane >> 2);
            const int ug  = (((lane & 3) ^ ((r >> 1) & 3)) << 3);
            const size_t ga = (size_t)(row0 + r) * lda + k0 + ug;
            const size_t gw = (size_t)(col0 + r) * K   + k0 + ug;
            const int lo  = (srow0 + ii * 16) * 32;
            __builtin_amdgcn_global_load_lds(
                (const __attribute__((address_space(1))) void*)(A1 + ga),
                (__attribute__((address_space(3))) void*)&lds[0 * 4096 + lo], 16, 0, 0);
            __builtin_amdgcn_global_load_lds(
                (const __attribute__((address_space(1))) void*)(A2 + ga),
                (__attribute__((address_space(3))) void*)&lds[1 * 4096 + lo], 16, 0, 0);
            __builtin_amdgcn_global_load_lds(
                (const __attribute__((address_space(1))) void*)(A3 + ga),
                (__attribute__((address_space(3))) void*)&lds[2 * 4096 + lo], 16, 0, 0);
            __builtin_amdgcn_global_load_lds(
                (const __attribute__((address_space(1))) void*)(W1 + gw),
                (__attribute__((address_space(3))) void*)&lds[3 * 4096 + lo], 16, 0, 0);
            __builtin_amdgcn_global_load_lds(
                (const __attribute__((address_space(1))) void*)(W2 + gw),
                (__attribute__((address_space(3))) void*)&lds[4 * 4096 + lo], 16, 0, 0);
            __builtin_amdgcn_global_load_lds(
                (const __attribute__((address_space(1))) void*)(W3 + gw),
                (__attribute__((address_space(3))) void*)&lds[5 * 4096 + lo], 16, 0, 0);
        }
        __syncthreads();

        s16x8 a1[4], a2[4], a3[4], w1[4], w2[4], w3[4];
#pragma unroll
        for (int mi = 0; mi < 4; mi++) {
            const int m  = wm * 64 + mi * 16 + (lane & 15);
            const int pu = ((g ^ ((m >> 1) & 3)) << 3);
            a1[mi] = *(const s16x8*)&lds[0 * 4096 + m * 32 + pu];
            a2[mi] = *(const s16x8*)&lds[1 * 4096 + m * 32 + pu];
            a3[mi] = *(const s16x8*)&lds[2 * 4096 + m * 32 + pu];
            const int n  = wn * 64 + mi * 16 + (lane & 15);
            const int pn = ((g ^ ((n >> 1) & 3)) << 3);
            w1[mi] = *(const s16x8*)&lds[3 * 4096 + n * 32 + pn];
            w2[mi] = *(const s16x8*)&lds[4 * 4096 + n * 32 + pn];
            w3[mi] = *(const s16x8*)&lds[5 * 4096 + n * 32 + pn];
        }
        __builtin_amdgcn_s_setprio(1);
#pragma unroll
        for (int mi = 0; mi < 4; mi++)
#pragma unroll
            for (int ni = 0; ni < 4; ni++) {
                acc[mi][ni] = __builtin_amdgcn_mfma_f32_16x16x32_bf16(a1[mi], w1[ni], acc[mi][ni], 0, 0, 0);
                acc[mi][ni] = __builtin_amdgcn_mfma_f32_16x16x32_bf16(a2[mi], w1[ni], acc[mi][ni], 0, 0, 0);
                acc[mi][ni] = __builtin_amdgcn_mfma_f32_16x16x32_bf16(a1[mi], w2[ni], acc[mi][ni], 0, 0, 0);
                acc[mi][ni] = __builtin_amdgcn_mfma_f32_16x16x32_bf16(a2[mi], w2[ni], acc[mi][ni], 0, 0, 0);
                acc[mi][ni] = __builtin_amdgcn_mfma_f32_16x16x32_bf16(a1[mi], w3[ni], acc[mi][ni], 0, 0, 0);
                acc[mi][ni] = __builtin_amdgcn_mfma_f32_16x16x32_bf16(a3[mi], w1[ni], acc[mi][ni], 0, 0, 0);
            }
        __builtin_amdgcn_s_setprio(0);
    }

#pragma unroll
    for (int mi = 0; mi < 4; mi++) {
#pragma unroll
        for (int ni = 0; ni < 4; ni++) {
#pragma unroll
            for (int r = 0; r < 4; r++) {
                const int row = row0 + wm * 64 + mi * 16 + g * 4 + r;
                const int col = col0 + wn * 64 + ni * 16 + (lane & 15);
                float v = acc[mi][ni][r];
                outf[(size_t)row * N + col] = v;
                unsigned short h = f2bf(v);
                outp[(size_t)row * N + col] =
                    (unsigned)h | ((unsigned)f2bf(v - bf2f(h)) << 16);
            }
        }
    }
}

// ---------------------------------------------------------------------------
// fp32 -> bf16 split converter (+ optional fp32 copy)
// ---------------------------------------------------------------------------
__global__ __launch_bounds__(256) void cvt_k(
    const float* __restrict__ in, ushort_t* __restrict__ o1,
    ushort_t* __restrict__ o2, ushort_t* __restrict__ o3,
    float* __restrict__ ocopy, int n4)
{
    int i = blockIdx.x * 256 + threadIdx.x;
    if (i >= n4) return;
    float4 v = ((const float4*)in)[i];
    if (ocopy) ((float4*)ocopy)[i] = v;
    float vv[4] = {v.x, v.y, v.z, v.w};
    union { unsigned short us[4]; ushort4 v4; } H, L, M;
#pragma unroll
    for (int q = 0; q < 4; q++) {
        unsigned short a = f2bf(vv[q]);
        float r1 = vv[q] - bf2f(a);
        unsigned short b = f2bf(r1);
        H.us[q] = a; L.us[q] = b;
        M.us[q] = f2bf(r1 - bf2f(b));
    }
    ((ushort4*)o1)[i] = H.v4;
    ((ushort4*)o2)[i] = L.v4;
    if (o3) ((ushort4*)o3)[i] = M.v4;
}

// ---------------------------------------------------------------------------
// Batched per-layer weight split conversion (one launch, 2816 blocks)
// ---------------------------------------------------------------------------
__global__ __launch_bounds__(256) void cvtw_k(
    const float* __restrict__ Wqk_i, const float* __restrict__ Wv_i,
    const float* __restrict__ Wout_i, const float* __restrict__ W1_i,
    const float* __restrict__ W2_i,
    ushort_t* __restrict__ wq1, ushort_t* __restrict__ wq2, ushort_t* __restrict__ wq3,
    ushort_t* __restrict__ wvh, ushort_t* __restrict__ wvl,
    ushort_t* __restrict__ woh, ushort_t* __restrict__ wol,
    ushort_t* __restrict__ w1h, ushort_t* __restrict__ w1l,
    ushort_t* __restrict__ w2h, ushort_t* __restrict__ w2l)
{
    const int blk = blockIdx.x;
    const float* in;
    ushort_t *o1, *o2, *o3 = nullptr;
    int i;
    if (blk < 256)       { in = Wqk_i;  o1 = wq1; o2 = wq2; o3 = wq3; i = blk * 256; }
    else if (blk < 512)  { in = Wv_i;   o1 = wvh; o2 = wvl; i = (blk - 256) * 256; }
    else if (blk < 768)  { in = Wout_i; o1 = woh; o2 = wol; i = (blk - 512) * 256; }
    else if (blk < 1792) { in = W1_i;   o1 = w1h; o2 = w1l; i = (blk - 768) * 256; }
    else                 { in = W2_i;   o1 = w2h; o2 = w2l; i = (blk - 1792) * 256; }
    i += threadIdx.x;
    float4 v = ((const float4*)in)[i];
    float vv[4] = {v.x, v.y, v.z, v.w};
    union { unsigned short us[4]; ushort4 v4; } H, L, M;
#pragma unroll
    for (int q = 0; q < 4; q++) {
        unsigned short a = f2bf(vv[q]);
        float r1 = vv[q] - bf2f(a);
        unsigned short b = f2bf(r1);
        H.us[q] = a; L.us[q] = b;
        M.us[q] = f2bf(r1 - bf2f(b));
    }
    ((ushort4*)o1)[i] = H.v4;
    ((ushort4*)o2)[i] = L.v4;
    if (o3) ((ushort4*)o3)[i] = M.v4;
}

// ---------------------------------------------------------------------------
// Bucket kernel v2 (all 4 rounds per block) — reads fp32 qk
// ---------------------------------------------------------------------------
__global__ __launch_bounds__(256) void bucket_k(
    const float* __restrict__ qk, const float* __restrict__ rot,
    int* __restrict__ bkt)
{
    __shared__ float rs[NH][64][32];    // 32 KB
    const int bh = blockIdx.y;
    const int t = blockIdx.x * 256 + threadIdx.x;
    for (int i = threadIdx.x; i < NH * 64 * 32; i += 256) {
        int r = i >> 11, f = (i >> 5) & 63, j = i & 31;
        rs[r][f][j] = rot[(f * NH + r) * 32 + j];
    }
    __syncthreads();
    const int b = bh >> 3, h = bh & 7;
    const float* q = qk + ((size_t)(b * TT + t)) * DD + h * DHH;
    float qv[64];
#pragma unroll
    for (int f4 = 0; f4 < 16; f4++) {
        float4 tmp = ((const float4*)q)[f4];
        qv[f4 * 4 + 0] = tmp.x; qv[f4 * 4 + 1] = tmp.y;
        qv[f4 * 4 + 2] = tmp.z; qv[f4 * 4 + 3] = tmp.w;
    }
    for (int r = 0; r < NH; r++) {
        float rv[32];
#pragma unroll
        for (int j = 0; j < 32; j++) rv[j] = 0.f;
        for (int f = 0; f < 64; f++) {
            float qf = qv[f];
#pragma unroll
            for (int j = 0; j < 32; j++) rv[j] = fmaf(qf, rs[r][f][j], rv[j]);
        }
        float best = rv[0];
        int bi = 0;
#pragma unroll
        for (int j = 1; j < 32; j++) { if (rv[j] > best) { best = rv[j]; bi = j; } }
#pragma unroll
        for (int j = 0; j < 32; j++) { float v = -rv[j]; if (v > best) { best = v; bi = 32 + j; } }
        bkt[((size_t)bh * NH + r) * TT + t] = bi;
    }
}

// ---------------------------------------------------------------------------
// Parallel stable counting sort per (bh, round). (verified R4)
// ---------------------------------------------------------------------------
__global__ __launch_bounds__(256) void sort_k(
    const int* __restrict__ bkt, int* __restrict__ st)
{
    __shared__ int lb[TT];
    __shared__ unsigned short cnt[128][64];
    __shared__ int base[64];
    const int r = blockIdx.x, bh = blockIdx.y;
    const int tid = threadIdx.x;
    const int* src = bkt + ((size_t)bh * NH + r) * TT;

    const int4* s4 = (const int4*)src;
    int4* l4 = (int4*)lb;
#pragma unroll
    for (int q = 0; q < 4; q++) l4[tid + q * 256] = s4[tid + q * 256];
    unsigned* cz = (unsigned*)cnt;
#pragma unroll
    for (int q = 0; q < 16; q++) cz[tid + q * 256] = 0;
    __syncthreads();

    if (tid < 128) {
        for (int it = 0; it < 32; it++) {
            int bb = lb[tid * 32 + it];
            cnt[tid][bb]++;
        }
    }
    __syncthreads();

    if (tid < 64) {
        const int bb = tid;
        int run = 0;
        for (int s = 0; s < 128; s++) {
            int t = cnt[s][bb];
            cnt[s][bb] = (unsigned short)run;
            run += t;
        }
        int inc = run;
#pragma unroll
        for (int off = 1; off < 64; off <<= 1) {
            int n = __shfl_up(inc, off, 64);
            if (tid >= off) inc += n;
        }
        base[bb] = inc - run;
    }
    __syncthreads();

    if (tid < 128) {
        int* dst = st + (size_t)bh * (NH * TT) + (size_t)r * TT;
        for (int it = 0; it < 32; it++) {
            int t = tid * 32 + it;
            int bb = lb[t];
            int pos = base[bb] + (int)cnt[tid][bb];
            cnt[tid][bb]++;
            dst[pos] = t;
        }
    }
}

// ---------------------------------------------------------------------------
// Attention v6: packed u32 inputs; 1-D grid, bhl = bid&7, c = bid>>3.
// ---------------------------------------------------------------------------
__global__ __launch_bounds__(256, 2) void attn_k(
    const unsigned* __restrict__ qkp, const unsigned* __restrict__ vp,
    const int* __restrict__ st, float* __restrict__ obuf,
    float* __restrict__ lseb, int bh0)
{
    __shared__ __align__(16) ushort_t ksh[128 * 72];
    __shared__ __align__(16) ushort_t ksl[128 * 72];
    __shared__ __align__(16) unsigned vsp[128 * 66];
    __shared__ float invn[128];
    __shared__ int   tks[128];

    const int bid = blockIdx.x;
    const int bhl = bid & 7;
    const int c   = bid >> 3;
    const int bh  = bh0 + bhl;
    const int b   = bh >> 3, h = bh & 7;
    const int tid = threadIdx.x;
    const int* stb = st + (size_t)bh * (NH * TT);

    if (tid < 128) {
        int cc = (tid < 64) ? c : ((c + NC - 1) & (NC - 1));
        tks[tid] = stb[cc * 64 + (tid & 63)];
    }
    __syncthreads();

    {   // stage K (unpack hi/lo) + V (verbatim) + inv k-norms
        const int row = tid >> 1, c0 = (tid & 1) * 32;
        const int t = tks[row];
        const uint4* kg = (const uint4*)(qkp + ((size_t)(b * TT + t)) * DD + h * DHH + c0);
        const uint4* vg = (const uint4*)(vp  + ((size_t)(b * TT + t)) * DD + h * DHH + c0);
        unsigned kp[32];
        uint4 vq[8];
        float ss = 0.f;
#pragma unroll
        for (int q = 0; q < 8; q++) {
            uint4 kq = kg[q];
            kp[4 * q + 0] = kq.x; kp[4 * q + 1] = kq.y;
            kp[4 * q + 2] = kq.z; kp[4 * q + 3] = kq.w;
            vq[q] = vg[q];
        }
#pragma unroll
        for (int e = 0; e < 32; e++) {
            float f = __uint_as_float(kp[e] << 16) + __uint_as_float(kp[e] & 0xffff0000u);
            ss = fmaf(f, f, ss);
        }
        ss += __shfl_xor(ss, 1);
        if ((tid & 1) == 0) invn[row] = 1.0f / fmaxf(sqrtf(ss), 1e-12f);

        unsigned hw[16], lw[16];
#pragma unroll
        for (int e = 0; e < 16; e++) {
            hw[e] = (kp[2 * e] & 0xffffu) | (kp[2 * e + 1] << 16);
            lw[e] = (kp[2 * e] >> 16) | (kp[2 * e + 1] & 0xffff0000u);
        }
        uint4* kdh = (uint4*)&ksh[row * 72 + c0];
        uint4* kdl = (uint4*)&ksl[row * 72 + c0];
#pragma unroll
        for (int q = 0; q < 4; q++) {
            kdh[q] = make_uint4(hw[4 * q], hw[4 * q + 1], hw[4 * q + 2], hw[4 * q + 3]);
            kdl[q] = make_uint4(lw[4 * q], lw[4 * q + 1], lw[4 * q + 2], lw[4 * q + 3]);
        }
        uint2* vd = (uint2*)&vsp[row * 66 + c0];
#pragma unroll
        for (int q = 0; q < 8; q++) {
            vd[2 * q]     = make_uint2(vq[q].x, vq[q].y);
            vd[2 * q + 1] = make_uint2(vq[q].z, vq[q].w);
        }
    }
    __syncthreads();

    const int lane = tid & 63;
    const int wv   = tid >> 6;
    const int cc16 = lane & 15;
    const int g    = lane >> 4;
    const int rr   = c >> 6;

    f32x4 stt[8];
#pragma unroll
    for (int jt = 0; jt < 8; jt++) stt[jt] = (f32x4)(0.f);

    const int qrow = wv * 16 + cc16;
#pragma unroll
    for (int ks = 0; ks < 2; ks++) {
        s16x8 qh = *(const s16x8*)&ksh[qrow * 72 + ks * 32 + g * 8];
        s16x8 ql = *(const s16x8*)&ksl[qrow * 72 + ks * 32 + g * 8];
        __builtin_amdgcn_s_setprio(1);
#pragma unroll
        for (int jt = 0; jt < 8; jt++) {
            const int krow = jt * 16 + cc16;
            s16x8 ah = *(const s16x8*)&ksh[krow * 72 + ks * 32 + g * 8];
            s16x8 al = *(const s16x8*)&ksl[krow * 72 + ks * 32 + g * 8];
            stt[jt] = __builtin_amdgcn_mfma_f32_16x16x32_bf16(ah, qh, stt[jt], 0, 0, 0);
            stt[jt] = __builtin_amdgcn_mfma_f32_16x16x32_bf16(al, qh, stt[jt], 0, 0, 0);
            stt[jt] = __builtin_amdgcn_mfma_f32_16x16x32_bf16(ah, ql, stt[jt], 0, 0, 0);
        }
        __builtin_amdgcn_s_setprio(0);
    }

    const int tqi = tks[wv * 16 + cc16];
    float m = -INFINITY;
#pragma unroll
    for (int jt = 0; jt < 8; jt++) {
#pragma unroll
        for (int r4 = 0; r4 < 4; r4++) {
            const int j = jt * 16 + g * 4 + r4;
            float d = stt[jt][r4] * invn[j] * 0.125f;
            if (tqi == tks[j]) d = -5e4f;
            stt[jt][r4] = d;
            m = fmaxf(m, d);
        }
    }
    m = fmaxf(m, __shfl_xor(m, 16));
    m = fmaxf(m, __shfl_xor(m, 32));
    float s = 0.f;
#pragma unroll
    for (int jt = 0; jt < 8; jt++) {
#pragma unroll
        for (int r4 = 0; r4 < 4; r4++) {
            float e = expf(stt[jt][r4] - m);
            stt[jt][r4] = e;
            s += e;
        }
    }
    s += __shfl_xor(s, 16);
    s += __shfl_xor(s, 32);
    const float is = 1.0f / s;
    if (g == 0) lseb[((size_t)bh * NH + rr) * TT + tqi] = m + logf(s);

    unsigned ph[8][2], pl[8][2];
#pragma unroll
    for (int jt = 0; jt < 8; jt++) {
#pragma unroll
        for (int w2 = 0; w2 < 2; w2++) {
            float p0 = stt[jt][2 * w2] * is;
            float p1 = stt[jt][2 * w2 + 1] * is;
            unsigned short h0 = f2bf(p0), h1 = f2bf(p1);
            ph[jt][w2] = (unsigned)h0 | ((unsigned)h1 << 16);
            pl[jt][w2] = (unsigned)f2bf(p0 - bf2f(h0)) | ((unsigned)f2bf(p1 - bf2f(h1)) << 16);
        }
    }

    f32x4 occ[4];
#pragma unroll
    for (int nt = 0; nt < 4; nt++) occ[nt] = (f32x4)(0.f);

    const int srcLow  = ((g & 1) << 5) + cc16;
    const int srcHigh = srcLow + 16;
    const bool hiT = (lane & 32) != 0;

#pragma unroll
    for (int ks = 0; ks < 4; ks++) {
        U4 Phi, Plo;
        {
            unsigned a0 = (unsigned)__shfl((int)ph[2 * ks][0], srcLow);
            unsigned a1 = (unsigned)__shfl((int)ph[2 * ks][1], srcLow);
            unsigned a2 = (unsigned)__shfl((int)ph[2 * ks][0], srcHigh);
            unsigned a3 = (unsigned)__shfl((int)ph[2 * ks][1], srcHigh);
            unsigned b0 = (unsigned)__shfl((int)ph[2 * ks + 1][0], srcLow);
            unsigned b1 = (unsigned)__shfl((int)ph[2 * ks + 1][1], srcLow);
            unsigned b2 = (unsigned)__shfl((int)ph[2 * ks + 1][0], srcHigh);
            unsigned b3 = (unsigned)__shfl((int)ph[2 * ks + 1][1], srcHigh);
            Phi.u[0] = hiT ? b0 : a0; Phi.u[1] = hiT ? b1 : a1;
            Phi.u[2] = hiT ? b2 : a2; Phi.u[3] = hiT ? b3 : a3;
            unsigned c0 = (unsigned)__shfl((int)pl[2 * ks][0], srcLow);
            unsigned c1 = (unsigned)__shfl((int)pl[2 * ks][1], srcLow);
            unsigned c2 = (unsigned)__shfl((int)pl[2 * ks][0], srcHigh);
            unsigned c3 = (unsigned)__shfl((int)pl[2 * ks][1], srcHigh);
            unsigned d0 = (unsigned)__shfl((int)pl[2 * ks + 1][0], srcLow);
            unsigned d1 = (unsigned)__shfl((int)pl[2 * ks + 1][1], srcLow);
            unsigned d2 = (unsigned)__shfl((int)pl[2 * ks + 1][0], srcHigh);
            unsigned d3 = (unsigned)__shfl((int)pl[2 * ks + 1][1], srcHigh);
            Plo.u[0] = hiT ? d0 : c0; Plo.u[1] = hiT ? d1 : c1;
            Plo.u[2] = hiT ? d2 : c2; Plo.u[3] = hiT ? d3 : c3;
        }
#pragma unroll
        for (int nt = 0; nt < 4; nt++) {
            unsigned u[8];
#pragma unroll
            for (int e = 0; e < 8; e++)
                u[e] = vsp[(32 * ks + 8 * g + e) * 66 + nt * 16 + cc16];
            U4 Vh, Vl;
#pragma unroll
            for (int m2 = 0; m2 < 4; m2++) {
                Vh.u[m2] = (u[2 * m2] & 0xffffu) | (u[2 * m2 + 1] << 16);
                Vl.u[m2] = (u[2 * m2] >> 16) | (u[2 * m2 + 1] & 0xffff0000u);
            }
            __builtin_amdgcn_s_setprio(1);
            occ[nt] = __builtin_amdgcn_mfma_f32_16x16x32_bf16(Phi.v, Vh.v, occ[nt], 0, 0, 0);
            occ[nt] = __builtin_amdgcn_mfma_f32_16x16x32_bf16(Plo.v, Vh.v, occ[nt], 0, 0, 0);
            occ[nt] = __builtin_amdgcn_mfma_f32_16x16x32_bf16(Phi.v, Vl.v, occ[nt], 0, 0, 0);
            __builtin_amdgcn_s_setprio(0);
        }
    }

#pragma unroll
    for (int r4 = 0; r4 < 4; r4++) {
        const int i = wv * 16 + g * 4 + r4;
        const int ti = tks[i];
        float* dst = obuf + (((size_t)bhl * NH + rr) * TT + ti) * DHH + cc16;
        dst[0]  = occ[0][r4];
        dst[16] = occ[1][r4];
        dst[32] = occ[2][r4];
        dst[48] = occ[3][r4];
    }
}

// ---------------------------------------------------------------------------
// Combine rounds for an 8-bh strip
// ---------------------------------------------------------------------------
__global__ __launch_bounds__(256) void combine_k(
    const float* __restrict__ obuf, const float* __restrict__ lseb,
    ushort_t* __restrict__ att, int bh0)
{
    int idx = blockIdx.x * 256 + threadIdx.x;
    int d = idx & 63;
    int t = (idx >> 6) & (TT - 1);
    int bhl = idx >> 18;
    int bh = bh0 + bhl;
    float l0 = lseb[((size_t)bh * NH + 0) * TT + t];
    float l1 = lseb[((size_t)bh * NH + 1) * TT + t];
    float l2 = lseb[((size_t)bh * NH + 2) * TT + t];
    float l3 = lseb[((size_t)bh * NH + 3) * TT + t];
    float m = fmaxf(fmaxf(l0, l1), fmaxf(l2, l3));
    float e0 = expf(l0 - m), e1 = expf(l1 - m), e2 = expf(l2 - m), e3 = expf(l3 - m);
    float inv = 1.0f / (e0 + e1 + e2 + e3);
    float o0 = obuf[(((size_t)bhl * NH + 0) * TT + t) * DHH + d];
    float o1 = obuf[(((size_t)bhl * NH + 1) * TT + t) * DHH + d];
    float o2 = obuf[(((size_t)bhl * NH + 2) * TT + t) * DHH + d];
    float o3 = obuf[(((size_t)bhl * NH + 3) * TT + t) * DHH + d];
    float o = (e0 * o0 + e1 * o1 + e2 * o2 + e3 * o3) * inv;
    int b = bh >> 3, h = bh & 7;
    size_t base = (size_t)(b * TT + t) * 1024 + h * DHH + d;
    unsigned short hi = f2bf(o);
    att[base]       = hi;
    att[base + 512] = f2bf(o - bf2f(hi));
}

// ---------------------------------------------------------------------------
// LayerNorm over D=512; optional 3-way bf16 split output. Safe in-place.
// ---------------------------------------------------------------------------
__global__ __launch_bounds__(64) void ln_k(
    const float* __restrict__ in, const float* __restrict__ g,
    const float* __restrict__ be, float* __restrict__ out,
    ushort_t* __restrict__ oh, ushort_t* __restrict__ ol,
    ushort_t* __restrict__ ol2)
{
    const int row = blockIdx.x;
    const int tid = threadIdx.x;
    const float* x = in + (size_t)row * DD;
    float4 a = *(const float4*)(x + tid * 8);
    float4 b = *(const float4*)(x + tid * 8 + 4);
    float s = a.x + a.y + a.z + a.w + b.x + b.y + b.z + b.w;
#pragma unroll
    for (int o = 32; o >= 1; o >>= 1) s += __shfl_xor(s, o, 64);
    float mean = s * (1.0f / 512.0f);
    float dx[8];
    dx[0] = a.x - mean; dx[1] = a.y - mean; dx[2] = a.z - mean; dx[3] = a.w - mean;
    dx[4] = b.x - mean; dx[5] = b.y - mean; dx[6] = b.z - mean; dx[7] = b.w - mean;
    float ss = 0.f;
#pragma unroll
    for (int q = 0; q < 8; q++) ss += dx[q] * dx[q];
#pragma unroll
    for (int o = 32; o >= 1; o >>= 1) ss += __shfl_xor(ss, o, 64);
    float var = ss * (1.0f / 512.0f);
    float inv = 1.0f / sqrtf(var + 1e-6f);
    const float* gp = g + tid * 8;
    const float* bp = be + tid * 8;
    float y[8];
#pragma unroll
    for (int q = 0; q < 8; q++) y[q] = dx[q] * inv * gp[q] + bp[q];
    float* yp = out + (size_t)row * DD + tid * 8;
    *(float4*)(yp)     = make_float4(y[0], y[1], y[2], y[3]);
    *(float4*)(yp + 4) = make_float4(y[4], y[5], y[6], y[7]);
    if (oh) {
        union { unsigned short us[8]; ushort4 v4[2]; } H, L, M;
#pragma unroll
        for (int q = 0; q < 8; q++) {
            unsigned short h = f2bf(y[q]);
            float r1 = y[q] - bf2f(h);
            unsigned short l = f2bf(r1);
            H.us[q] = h; L.us[q] = l;
            M.us[q] = f2bf(r1 - bf2f(l));
        }
        size_t e = (size_t)row * DD + tid * 8;
        *(ushort4*)(oh + e)      = H.v4[0];
        *(ushort4*)(oh + e + 4)  = H.v4[1];
        *(ushort4*)(ol + e)      = L.v4[0];
        *(ushort4*)(ol + e + 4)  = L.v4[1];
        *(ushort4*)(ol2 + e)     = M.v4[0];
        *(ushort4*)(ol2 + e + 4) = M.v4[1];
    }
}

// ---------------------------------------------------------------------------
extern "C" void kernel_launch(void* const* d_in, const int* in_sizes, int n_in,
                              void* d_out, int out_size, void* d_ws, size_t ws_size,
                              hipStream_t stream)
{
    const float* src  = (const float*)d_in[0];
    const float* rots = (const float*)d_in[1];
    const float* Wqk  = (const float*)d_in[2];
    const float* Wv   = (const float*)d_in[3];
    const float* Wout = (const float*)d_in[4];
    const float* bout = (const float*)d_in[5];
    const float* W1   = (const float*)d_in[6];
    const float* b1   = (const float*)d_in[7];
    const float* W2   = (const float*)d_in[8];
    const float* b2   = (const float*)d_in[9];
    const float* g2   = (const float*)d_in[10];
    const float* be2  = (const float*)d_in[11];
    const float* gf   = (const float*)d_in[12];
    const float* bf   = (const float*)d_in[13];
    float* out = (float*)d_out;

    // ---- workspace layout (~234 MB) ----
    char* w = (char*)d_ws;
    const size_t SZ_X = (size_t)MROWS * DD * 4;               // 33.55 MB
    const size_t XHALF = (size_t)MROWS * DD;
    float*    x     = (float*)(w);
    ushort_t* xs    = (ushort_t*)(w + SZ_X);
    ushort_t* xh    = xs;
    ushort_t* xl    = xs + XHALF;
    ushort_t* xl2   = xs + 2 * XHALF;
    char*     p     = w + SZ_X + 3 * XHALF * 2;
    float*    qkb   = (float*)(p);
    ushort_t* attb  = (ushort_t*)(p);
    unsigned* vp    = (unsigned*)(p + SZ_X);
    unsigned* qkp   = (unsigned*)(p + 2 * SZ_X);
    float*    obuf  = (float*)(p + 3 * SZ_X);
    ushort_t* h1h   = (ushort_t*)(p);                         // FFN: spans p..p+2SZ_X
    ushort_t* h1l   = (ushort_t*)(p + 2 * SZ_X);              // FFN: spans p+2..p+4SZ_X
    ushort_t* wb    = (ushort_t*)(p + 4 * SZ_X);
    char*     tail  = p + 4 * SZ_X + 6029312 * 2;
    int*      bkt   = (int*)(tail);
    int*      st    = (int*)(tail + (size_t)BHH * NH * TT * 4);
    float*    lseb  = (float*)(tail + 2 * (size_t)BHH * NH * TT * 4);

    ushort_t* wvh = wb;            ushort_t* wvl = wb + 262144;
    ushort_t* woh = wb + 524288;   ushort_t* wol = wb + 786432;
    ushort_t* w1h = wb + 1048576;  ushort_t* w1l = wb + 2097152;
    ushort_t* w2h = wb + 3145728;  ushort_t* w2l = wb + 4194304;
    ushort_t* wq1 = wb + 5242880;  ushort_t* wq2 = wb + 5505024;
    ushort_t* wq3 = wb + 5767168;

    // x copy + 3-way split in one pass
    cvt_k<<<(MROWS * DD / 4 + 255) / 256, 256, 0, stream>>>(src, xh, xl, xl2, x,
                                                            MROWS * DD / 4);

    for (int i = 0; i < LLAY; i++) {
        const float* Wqk_i = Wqk + (size_t)i * DD * DD;
        const float* Wv_i  = Wv  + (size_t)i * DD * DD;
        const float* Wout_i= Wout+ (size_t)i * DD * DD;
        const float* bout_i= bout+ (size_t)i * DD;
        const float* W1_i  = W1  + (size_t)i * DFFN * DD;
        const float* b1_i  = b1  + (size_t)i * DFFN;
        const float* W2_i  = W2  + (size_t)i * DD * DFFN;
        const float* b2_i  = b2  + (size_t)i * DD;
        const float* g2_i  = g2  + (size_t)i * DD;
        const float* be2_i = be2 + (size_t)i * DD;
        const float* rot_i = rots + (size_t)i * DHH * NH * 32;

        cvtw_k<<<2816, 256, 0, stream>>>(Wqk_i, Wv_i, Wout_i, W1_i, W2_i,
                                         wq1, wq2, wq3, wvh, wvl, woh, wol,
                                         w1h, w1l, w2h, w2l);

        // qk = x @ Wqk^T  (bf16x6, fp32 for bucket + packed for attn)
        gemm_bf6_k<<<dim3(4, 128), 256, 0, stream>>>(xh, xl, xl2, DD, wq1, wq2, wq3,
                                                     qkb, qkp, MROWS, DD, DD);
        // v = x @ Wv^T  (bf16x3, 2-phase, packed output)
        gemm_bf3_k<<<dim3(4, 128), 256, 0, stream>>>(xh, xl, DD, wvh, wvl, DD,
                                                     nullptr, nullptr,
                                                     nullptr, nullptr, nullptr, vp,
                                                     MROWS, DD, DD, 0);
        bucket_k<<<dim3(16, BHH), 256, 0, stream>>>(qkb, rot_i, bkt);
        sort_k<<<dim3(NH, BHH), 256, 0, stream>>>(bkt, st);

        // attention in 4 strips of 8 bh; combine -> att hi/lo
        for (int s = 0; s < 4; s++) {
            attn_k<<<2048, 256, 0, stream>>>(qkp, vp, st, obuf, lseb, s * 8);
            combine_k<<<8192, 256, 0, stream>>>(obuf, lseb, attb, s * 8);
        }

        // x = x + att @ Wout^T + bout ; emit x hi/lo (for FFN input)
        gemm_bf3_k<<<dim3(4, 128), 256, 0, stream>>>(attb, attb + 512, 1024, woh, wol, DD,
                                                     bout_i, x, x, xh, xl, nullptr,
                                                     MROWS, DD, DD, 0);
        // FFN1 full-N via 256x256 tile / 8-wave kernel: h1 = relu(x @ W1^T + b1)
        gemm_bf3_256_k<<<dim3(8, 64), 512, 0, stream>>>(xh, xl, DD, w1h, w1l, DD,
                                                        b1_i, h1h, h1l,
                                                        MROWS, DFFN, DD, 1);
        // FFN2 full-K: x = x + h1 @ W2^T + b2  (in-place residual on x)
        gemm_bf3_k<<<dim3(4, 128), 256, 0, stream>>>(h1h, h1l, DFFN, w2h, w2l, DFFN,
                                                     b2_i, x,
                                                     x, nullptr, nullptr, nullptr,
                                                     MROWS, DD, DFFN, 0);
        // x = LN(x) in-place; emit 3-way split for next layer's qk/v
        ln_k<<<MROWS, 64, 0, stream>>>(x, g2_i, be2_i, x, xh, xl, xl2);
    }
    ln_k<<<MROWS, 64, 0, stream>>>(x, gf, bf, out, nullptr, nullptr, nullptr);
}

// Round 15
// 2961.401 us; speedup vs baseline: 1.0780x; 1.0056x over previous
//
#include <hip/hip_runtime.h>
#include <math.h>

#define TT    4096
#define DD    512
#define HH    8
#define DHH   64
#define NH    4
#define LLAY  4
#define DFFN  2048
#define BHH   32          // B*H
#define NC    256         // chunks per bh (NH*NB)
#define MROWS 16384       // B*T

typedef __attribute__((ext_vector_type(8))) short s16x8;
typedef __attribute__((ext_vector_type(4))) float f32x4;
typedef unsigned short ushort_t;

union U4 { unsigned u[4]; s16x8 v; };

__device__ __forceinline__ unsigned short f2bf(float f) {
    unsigned u = __float_as_uint(f);
    unsigned r = (u + 0x7FFFu + ((u >> 16) & 1u)) >> 16;
    return (unsigned short)r;
}
__device__ __forceinline__ float bf2f(unsigned short h) {
    return __uint_as_float(((unsigned)h) << 16);
}

// XCD-aware bijective swizzle (T1, m157): nwg must be divisible by 8.
__device__ __forceinline__ void xcd_swz(int& bx, int& by) {
    const int gx = gridDim.x;
    const int nwg = gx * gridDim.y;
    const int flat = by * gx + bx;
    const int q = nwg >> 3;
    const int swz = (flat & 7) * q + (flat >> 3);
    bx = swz % gx;
    by = swz / gx;
}

// ---------------------------------------------------------------------------
// bf16x3 MFMA GEMM, 2-phase double-buffered, 128x128 tile (verified R9+)
// outp (if set) writes packed hi|lo<<16 into KV-interleaved layout:
// idx = row*1024 + (col>>6)*128 + (col&63); base pointer selects K vs V half.
// ---------------------------------------------------------------------------
__global__ __launch_bounds__(256) void gemm_bf3_k(
    const ushort_t* __restrict__ Ah, const ushort_t* __restrict__ Al, int lda,
    const ushort_t* __restrict__ Wh, const ushort_t* __restrict__ Wl, int ldw,
    const float* __restrict__ bias, const float* __restrict__ resid,
    float* __restrict__ outf, ushort_t* __restrict__ outh, ushort_t* __restrict__ outl,
    unsigned* __restrict__ outp,
    int M, int N, int K, int relu)
{
    __shared__ __align__(16) ushort_t lds[2][4 * 128 * 32];   // 2 x 32KB
    const int tid  = threadIdx.x;
    const int lane = tid & 63;
    const int wv   = tid >> 6;
    const int wm   = wv >> 1, wn = wv & 1;
    int bx = blockIdx.x, by = blockIdx.y;
    xcd_swz(bx, by);
    const int row0 = by * 128, col0 = bx * 128;
    const int g    = lane >> 4;
    const int srow0 = wv * 32;

    f32x4 acc[4][4];
#pragma unroll
    for (int mi = 0; mi < 4; mi++)
#pragma unroll
        for (int ni = 0; ni < 4; ni++) acc[mi][ni] = (f32x4)(0.f);

    auto STAGE = [&](int buf, int k0) {
#pragma unroll
        for (int ii = 0; ii < 2; ii++) {
            const int r   = srow0 + ii * 16 + (lane >> 2);
            const int ug  = (((lane & 3) ^ ((r >> 1) & 3)) << 3);
            const size_t ga = (size_t)(row0 + r) * lda + k0 + ug;
            const size_t gw = (size_t)(col0 + r) * ldw + k0 + ug;
            const int lo  = (srow0 + ii * 16) * 32;
            __builtin_amdgcn_global_load_lds(
                (const __attribute__((address_space(1))) void*)(Ah + ga),
                (__attribute__((address_space(3))) void*)&lds[buf][0 * 4096 + lo], 16, 0, 0);
            __builtin_amdgcn_global_load_lds(
                (const __attribute__((address_space(1))) void*)(Al + ga),
                (__attribute__((address_space(3))) void*)&lds[buf][1 * 4096 + lo], 16, 0, 0);
            __builtin_amdgcn_global_load_lds(
                (const __attribute__((address_space(1))) void*)(Wh + gw),
                (__attribute__((address_space(3))) void*)&lds[buf][2 * 4096 + lo], 16, 0, 0);
            __builtin_amdgcn_global_load_lds(
                (const __attribute__((address_space(1))) void*)(Wl + gw),
                (__attribute__((address_space(3))) void*)&lds[buf][3 * 4096 + lo], 16, 0, 0);
        }
    };

    const int nt = K >> 5;
    STAGE(0, 0);

    for (int t = 0; t < nt; ++t) {
        const int cur = t & 1;
        if (t + 1 < nt) {
            STAGE(cur ^ 1, (t + 1) << 5);
            asm volatile("s_waitcnt vmcnt(8)" ::: "memory");
        } else {
            asm volatile("s_waitcnt vmcnt(0)" ::: "memory");
        }
        __builtin_amdgcn_s_barrier();
        __builtin_amdgcn_sched_barrier(0);

        s16x8 ah[4], al[4], wh[4], wl[4];
#pragma unroll
        for (int mi = 0; mi < 4; mi++) {
            const int m  = wm * 64 + mi * 16 + (lane & 15);
            const int pu = ((g ^ ((m >> 1) & 3)) << 3);
            ah[mi] = *(const s16x8*)&lds[cur][0 * 4096 + m * 32 + pu];
            al[mi] = *(const s16x8*)&lds[cur][1 * 4096 + m * 32 + pu];
            const int n  = wn * 64 + mi * 16 + (lane & 15);
            const int pn = ((g ^ ((n >> 1) & 3)) << 3);
            wh[mi] = *(const s16x8*)&lds[cur][2 * 4096 + n * 32 + pn];
            wl[mi] = *(const s16x8*)&lds[cur][3 * 4096 + n * 32 + pn];
        }
        __builtin_amdgcn_s_setprio(1);
#pragma unroll
        for (int mi = 0; mi < 4; mi++)
#pragma unroll
            for (int ni = 0; ni < 4; ni++) {
                acc[mi][ni] = __builtin_amdgcn_mfma_f32_16x16x32_bf16(ah[mi], wh[ni], acc[mi][ni], 0, 0, 0);
                acc[mi][ni] = __builtin_amdgcn_mfma_f32_16x16x32_bf16(al[mi], wh[ni], acc[mi][ni], 0, 0, 0);
                acc[mi][ni] = __builtin_amdgcn_mfma_f32_16x16x32_bf16(ah[mi], wl[ni], acc[mi][ni], 0, 0, 0);
            }
        __builtin_amdgcn_s_setprio(0);

        __builtin_amdgcn_sched_barrier(0);
        __builtin_amdgcn_s_barrier();     // WAR: lds[cur] overwritten at t+1's STAGE
    }

#pragma unroll
    for (int mi = 0; mi < 4; mi++) {
#pragma unroll
        for (int ni = 0; ni < 4; ni++) {
#pragma unroll
            for (int r = 0; r < 4; r++) {
                const int row = row0 + wm * 64 + mi * 16 + g * 4 + r;
                const int col = col0 + wn * 64 + ni * 16 + (lane & 15);
                float v = acc[mi][ni][r];
                if (bias)  v += bias[col];
                if (relu)  v = fmaxf(v, 0.f);
                if (resid) v += resid[(size_t)row * N + col];
                if (outf)  outf[(size_t)row * N + col] = v;
                if (outh) {
                    unsigned short h = f2bf(v);
                    outh[(size_t)row * N + col] = h;
                    outl[(size_t)row * N + col] = f2bf(v - bf2f(h));
                }
                if (outp) {
                    unsigned short h = f2bf(v);
                    outp[(size_t)row * 1024 + ((col >> 6) << 7) + (col & 63)] =
                        (unsigned)h | ((unsigned)f2bf(v - bf2f(h)) << 16);
                }
            }
        }
    }
}

// ---------------------------------------------------------------------------
// bf16x3 MFMA GEMM, 256x256 tile, 8 waves, BK=32, 2-phase dbuf (verified R14)
// ---------------------------------------------------------------------------
__global__ __launch_bounds__(512) void gemm_bf3_256_k(
    const ushort_t* __restrict__ Ah, const ushort_t* __restrict__ Al, int lda,
    const ushort_t* __restrict__ Wh, const ushort_t* __restrict__ Wl, int ldw,
    const float* __restrict__ bias,
    ushort_t* __restrict__ outh, ushort_t* __restrict__ outl,
    int M, int N, int K, int relu)
{
    __shared__ __align__(16) ushort_t lds[2][4 * 256 * 32];   // 2 x 64KB
    const int tid  = threadIdx.x;
    const int lane = tid & 63;
    const int wv   = tid >> 6;          // 0..7
    const int wm   = wv >> 2;           // 0..1
    const int wn   = wv & 3;            // 0..3
    int bx = blockIdx.x, by = blockIdx.y;
    xcd_swz(bx, by);
    const int row0 = by * 256, col0 = bx * 256;
    const int g    = lane >> 4;
    const int srow0 = wv * 32;

    f32x4 acc[8][4];
#pragma unroll
    for (int mi = 0; mi < 8; mi++)
#pragma unroll
        for (int ni = 0; ni < 4; ni++) acc[mi][ni] = (f32x4)(0.f);

    auto STAGE = [&](int buf, int k0) {
#pragma unroll
        for (int ii = 0; ii < 2; ii++) {
            const int r   = srow0 + ii * 16 + (lane >> 2);
            const int ug  = (((lane & 3) ^ ((r >> 1) & 3)) << 3);
            const size_t ga = (size_t)(row0 + r) * lda + k0 + ug;
            const size_t gw = (size_t)(col0 + r) * ldw + k0 + ug;
            const int lo  = (srow0 + ii * 16) * 32;
            __builtin_amdgcn_global_load_lds(
                (const __attribute__((address_space(1))) void*)(Ah + ga),
                (__attribute__((address_space(3))) void*)&lds[buf][0 * 8192 + lo], 16, 0, 0);
            __builtin_amdgcn_global_load_lds(
                (const __attribute__((address_space(1))) void*)(Al + ga),
                (__attribute__((address_space(3))) void*)&lds[buf][1 * 8192 + lo], 16, 0, 0);
            __builtin_amdgcn_global_load_lds(
                (const __attribute__((address_space(1))) void*)(Wh + gw),
                (__attribute__((address_space(3))) void*)&lds[buf][2 * 8192 + lo], 16, 0, 0);
            __builtin_amdgcn_global_load_lds(
                (const __attribute__((address_space(1))) void*)(Wl + gw),
                (__attribute__((address_space(3))) void*)&lds[buf][3 * 8192 + lo], 16, 0, 0);
        }
    };

    const int nt = K >> 5;
    STAGE(0, 0);

    for (int t = 0; t < nt; ++t) {
        const int cur = t & 1;
        if (t + 1 < nt) {
            STAGE(cur ^ 1, (t + 1) << 5);
            asm volatile("s_waitcnt vmcnt(8)" ::: "memory");
        } else {
            asm volatile("s_waitcnt vmcnt(0)" ::: "memory");
        }
        __builtin_amdgcn_s_barrier();
        __builtin_amdgcn_sched_barrier(0);

        s16x8 wh[4], wl[4];
#pragma unroll
        for (int ni = 0; ni < 4; ni++) {
            const int n  = wn * 64 + ni * 16 + (lane & 15);
            const int pn = ((g ^ ((n >> 1) & 3)) << 3);
            wh[ni] = *(const s16x8*)&lds[cur][2 * 8192 + n * 32 + pn];
            wl[ni] = *(const s16x8*)&lds[cur][3 * 8192 + n * 32 + pn];
        }
#pragma unroll
        for (int half = 0; half < 2; half++) {
            s16x8 ah[4], al[4];
#pragma unroll
            for (int mj = 0; mj < 4; mj++) {
                const int m  = wm * 128 + (half * 4 + mj) * 16 + (lane & 15);
                const int pu = ((g ^ ((m >> 1) & 3)) << 3);
                ah[mj] = *(const s16x8*)&lds[cur][0 * 8192 + m * 32 + pu];
                al[mj] = *(const s16x8*)&lds[cur][1 * 8192 + m * 32 + pu];
            }
            __builtin_amdgcn_s_setprio(1);
#pragma unroll
            for (int mj = 0; mj < 4; mj++)
#pragma unroll
                for (int ni = 0; ni < 4; ni++) {
                    acc[half * 4 + mj][ni] = __builtin_amdgcn_mfma_f32_16x16x32_bf16(ah[mj], wh[ni], acc[half * 4 + mj][ni], 0, 0, 0);
                    acc[half * 4 + mj][ni] = __builtin_amdgcn_mfma_f32_16x16x32_bf16(al[mj], wh[ni], acc[half * 4 + mj][ni], 0, 0, 0);
                    acc[half * 4 + mj][ni] = __builtin_amdgcn_mfma_f32_16x16x32_bf16(ah[mj], wl[ni], acc[half * 4 + mj][ni], 0, 0, 0);
                }
            __builtin_amdgcn_s_setprio(0);
        }

        __builtin_amdgcn_sched_barrier(0);
        __builtin_amdgcn_s_barrier();     // WAR before next STAGE overwrite
    }

#pragma unroll
    for (int mi = 0; mi < 8; mi++) {
#pragma unroll
        for (int ni = 0; ni < 4; ni++) {
#pragma unroll
            for (int r = 0; r < 4; r++) {
                const int row = row0 + wm * 128 + mi * 16 + g * 4 + r;
                const int col = col0 + wn * 64 + ni * 16 + (lane & 15);
                float v = acc[mi][ni][r];
                if (bias) v += bias[col];
                if (relu) v = fmaxf(v, 0.f);
                unsigned short h = f2bf(v);
                outh[(size_t)row * N + col] = h;
                outl[(size_t)row * N + col] = f2bf(v - bf2f(h));
            }
        }
    }
}

// ---------------------------------------------------------------------------
// bf16x6 MFMA GEMM (qk only): emits fp32 + packed KV-interleaved (K half).
// ---------------------------------------------------------------------------
__global__ __launch_bounds__(256) void gemm_bf6_k(
    const ushort_t* __restrict__ A1, const ushort_t* __restrict__ A2,
    const ushort_t* __restrict__ A3, int lda,
    const ushort_t* __restrict__ W1, const ushort_t* __restrict__ W2,
    const ushort_t* __restrict__ W3,
    float* __restrict__ outf, unsigned* __restrict__ outp, int M, int N, int K)
{
    __shared__ __align__(16) ushort_t lds[6 * 128 * 32];   // A1,A2,A3,W1,W2,W3
    const int tid  = threadIdx.x;
    const int lane = tid & 63;
    const int wv   = tid >> 6;
    const int wm   = wv >> 1, wn = wv & 1;
    int bx = blockIdx.x, by = blockIdx.y;
    xcd_swz(bx, by);
    const int row0 = by * 128, col0 = bx * 128;
    const int g    = lane >> 4;

    f32x4 acc[4][4];
#pragma unroll
    for (int mi = 0; mi < 4; mi++)
#pragma unroll
        for (int ni = 0; ni < 4; ni++) acc[mi][ni] = (f32x4)(0.f);

    const int srow0 = wv * 32;

    for (int k0 = 0; k0 < K; k0 += 32) {
        __syncthreads();
#pragma unroll
        for (int ii = 0; ii < 2; ii++) {
            const int r   = srow0 + ii * 16 + (lane >> 2);
            const int ug  = (((lane & 3) ^ ((r >> 1) & 3)) << 3);
            const size_t ga = (size_t)(row0 + r) * lda + k0 + ug;
            const size_t gw = (size_t)(col0 + r) * K   + k0 + ug;
            const int lo  = (srow0 + ii * 16) * 32;
            __builtin_amdgcn_global_load_lds(
                (const __attribute__((address_space(1))) void*)(A1 + ga),
                (__attribute__((address_space(3))) void*)&lds[0 * 4096 + lo], 16, 0, 0);
            __builtin_amdgcn_global_load_lds(
                (const __attribute__((address_space(1))) void*)(A2 + ga),
                (__attribute__((address_space(3))) void*)&lds[1 * 4096 + lo], 16, 0, 0);
            __builtin_amdgcn_global_load_lds(
                (const __attribute__((address_space(1))) void*)(A3 + ga),
                (__attribute__((address_space(3))) void*)&lds[2 * 4096 + lo], 16, 0, 0);
            __builtin_amdgcn_global_load_lds(
                (const __attribute__((address_space(1))) void*)(W1 + gw),
                (__attribute__((address_space(3))) void*)&lds[3 * 4096 + lo], 16, 0, 0);
            __builtin_amdgcn_global_load_lds(
                (const __attribute__((address_space(1))) void*)(W2 + gw),
                (__attribute__((address_space(3))) void*)&lds[4 * 4096 + lo], 16, 0, 0);
            __builtin_amdgcn_global_load_lds(
                (const __attribute__((address_space(1))) void*)(W3 + gw),
                (__attribute__((address_space(3))) void*)&lds[5 * 4096 + lo], 16, 0, 0);
        }
        __syncthreads();

        s16x8 a1[4], a2[4], a3[4], w1[4], w2[4], w3[4];
#pragma unroll
        for (int mi = 0; mi < 4; mi++) {
            const int m  = wm * 64 + mi * 16 + (lane & 15);
            const int pu = ((g ^ ((m >> 1) & 3)) << 3);
            a1[mi] = *(const s16x8*)&lds[0 * 4096 + m * 32 + pu];
            a2[mi] = *(const s16x8*)&lds[1 * 4096 + m * 32 + pu];
            a3[mi] = *(const s16x8*)&lds[2 * 4096 + m * 32 + pu];
            const int n  = wn * 64 + mi * 16 + (lane & 15);
            const int pn = ((g ^ ((n >> 1) & 3)) << 3);
            w1[mi] = *(const s16x8*)&lds[3 * 4096 + n * 32 + pn];
            w2[mi] = *(const s16x8*)&lds[4 * 4096 + n * 32 + pn];
            w3[mi] = *(const s16x8*)&lds[5 * 4096 + n * 32 + pn];
        }
        __builtin_amdgcn_s_setprio(1);
#pragma unroll
        for (int mi = 0; mi < 4; mi++)
#pragma unroll
            for (int ni = 0; ni < 4; ni++) {
                acc[mi][ni] = __builtin_amdgcn_mfma_f32_16x16x32_bf16(a1[mi], w1[ni], acc[mi][ni], 0, 0, 0);
                acc[mi][ni] = __builtin_amdgcn_mfma_f32_16x16x32_bf16(a2[mi], w1[ni], acc[mi][ni], 0, 0, 0);
                acc[mi][ni] = __builtin_amdgcn_mfma_f32_16x16x32_bf16(a1[mi], w2[ni], acc[mi][ni], 0, 0, 0);
                acc[mi][ni] = __builtin_amdgcn_mfma_f32_16x16x32_bf16(a2[mi], w2[ni], acc[mi][ni], 0, 0, 0);
                acc[mi][ni] = __builtin_amdgcn_mfma_f32_16x16x32_bf16(a1[mi], w3[ni], acc[mi][ni], 0, 0, 0);
                acc[mi][ni] = __builtin_amdgcn_mfma_f32_16x16x32_bf16(a3[mi], w1[ni], acc[mi][ni], 0, 0, 0);
            }
        __builtin_amdgcn_s_setprio(0);
    }

#pragma unroll
    for (int mi = 0; mi < 4; mi++) {
#pragma unroll
        for (int ni = 0; ni < 4; ni++) {
#pragma unroll
            for (int r = 0; r < 4; r++) {
                const int row = row0 + wm * 64 + mi * 16 + g * 4 + r;
                const int col = col0 + wn * 64 + ni * 16 + (lane & 15);
                float v = acc[mi][ni][r];
                outf[(size_t)row * N + col] = v;
                unsigned short h = f2bf(v);
                outp[(size_t)row * 1024 + ((col >> 6) << 7) + (col & 63)] =
                    (unsigned)h | ((unsigned)f2bf(v - bf2f(h)) << 16);
            }
        }
    }
}

// ---------------------------------------------------------------------------
// fp32 -> bf16 split converter (+ optional fp32 copy)
// ---------------------------------------------------------------------------
__global__ __launch_bounds__(256) void cvt_k(
    const float* __restrict__ in, ushort_t* __restrict__ o1,
    ushort_t* __restrict__ o2, ushort_t* __restrict__ o3,
    float* __restrict__ ocopy, int n4)
{
    int i = blockIdx.x * 256 + threadIdx.x;
    if (i >= n4) return;
    float4 v = ((const float4*)in)[i];
    if (ocopy) ((float4*)ocopy)[i] = v;
    float vv[4] = {v.x, v.y, v.z, v.w};
    union { unsigned short us[4]; ushort4 v4; } H, L, M;
#pragma unroll
    for (int q = 0; q < 4; q++) {
        unsigned short a = f2bf(vv[q]);
        float r1 = vv[q] - bf2f(a);
        unsigned short b = f2bf(r1);
        H.us[q] = a; L.us[q] = b;
        M.us[q] = f2bf(r1 - bf2f(b));
    }
    ((ushort4*)o1)[i] = H.v4;
    ((ushort4*)o2)[i] = L.v4;
    if (o3) ((ushort4*)o3)[i] = M.v4;
}

// ---------------------------------------------------------------------------
// Batched per-layer weight split conversion (one launch, 2816 blocks)
// ---------------------------------------------------------------------------
__global__ __launch_bounds__(256) void cvtw_k(
    const float* __restrict__ Wqk_i, const float* __restrict__ Wv_i,
    const float* __restrict__ Wout_i, const float* __restrict__ W1_i,
    const float* __restrict__ W2_i,
    ushort_t* __restrict__ wq1, ushort_t* __restrict__ wq2, ushort_t* __restrict__ wq3,
    ushort_t* __restrict__ wvh, ushort_t* __restrict__ wvl,
    ushort_t* __restrict__ woh, ushort_t* __restrict__ wol,
    ushort_t* __restrict__ w1h, ushort_t* __restrict__ w1l,
    ushort_t* __restrict__ w2h, ushort_t* __restrict__ w2l)
{
    const int blk = blockIdx.x;
    const float* in;
    ushort_t *o1, *o2, *o3 = nullptr;
    int i;
    if (blk < 256)       { in = Wqk_i;  o1 = wq1; o2 = wq2; o3 = wq3; i = blk * 256; }
    else if (blk < 512)  { in = Wv_i;   o1 = wvh; o2 = wvl; i = (blk - 256) * 256; }
    else if (blk < 768)  { in = Wout_i; o1 = woh; o2 = wol; i = (blk - 512) * 256; }
    else if (blk < 1792) { in = W1_i;   o1 = w1h; o2 = w1l; i = (blk - 768) * 256; }
    else                 { in = W2_i;   o1 = w2h; o2 = w2l; i = (blk - 1792) * 256; }
    i += threadIdx.x;
    float4 v = ((const float4*)in)[i];
    float vv[4] = {v.x, v.y, v.z, v.w};
    union { unsigned short us[4]; ushort4 v4; } H, L, M;
#pragma unroll
    for (int q = 0; q < 4; q++) {
        unsigned short a = f2bf(vv[q]);
        float r1 = vv[q] - bf2f(a);
        unsigned short b = f2bf(r1);
        H.us[q] = a; L.us[q] = b;
        M.us[q] = f2bf(r1 - bf2f(b));
    }
    ((ushort4*)o1)[i] = H.v4;
    ((ushort4*)o2)[i] = L.v4;
    if (o3) ((ushort4*)o3)[i] = M.v4;
}

// ---------------------------------------------------------------------------
// Bucket kernel v2 (all 4 rounds per block) — reads fp32 qk
// ---------------------------------------------------------------------------
__global__ __launch_bounds__(256) void bucket_k(
    const float* __restrict__ qk, const float* __restrict__ rot,
    int* __restrict__ bkt)
{
    __shared__ float rs[NH][64][32];    // 32 KB
    const int bh = blockIdx.y;
    const int t = blockIdx.x * 256 + threadIdx.x;
    for (int i = threadIdx.x; i < NH * 64 * 32; i += 256) {
        int r = i >> 11, f = (i >> 5) & 63, j = i & 31;
        rs[r][f][j] = rot[(f * NH + r) * 32 + j];
    }
    __syncthreads();
    const int b = bh >> 3, h = bh & 7;
    const float* q = qk + ((size_t)(b * TT + t)) * DD + h * DHH;
    float qv[64];
#pragma unroll
    for (int f4 = 0; f4 < 16; f4++) {
        float4 tmp = ((const float4*)q)[f4];
        qv[f4 * 4 + 0] = tmp.x; qv[f4 * 4 + 1] = tmp.y;
        qv[f4 * 4 + 2] = tmp.z; qv[f4 * 4 + 3] = tmp.w;
    }
    for (int r = 0; r < NH; r++) {
        float rv[32];
#pragma unroll
        for (int j = 0; j < 32; j++) rv[j] = 0.f;
        for (int f = 0; f < 64; f++) {
            float qf = qv[f];
#pragma unroll
            for (int j = 0; j < 32; j++) rv[j] = fmaf(qf, rs[r][f][j], rv[j]);
        }
        float best = rv[0];
        int bi = 0;
#pragma unroll
        for (int j = 1; j < 32; j++) { if (rv[j] > best) { best = rv[j]; bi = j; } }
#pragma unroll
        for (int j = 0; j < 32; j++) { float v = -rv[j]; if (v > best) { best = v; bi = 32 + j; } }
        bkt[((size_t)bh * NH + r) * TT + t] = bi;
    }
}

// ---------------------------------------------------------------------------
// Parallel stable counting sort per (bh, round). (verified R4)
// ---------------------------------------------------------------------------
__global__ __launch_bounds__(256) void sort_k(
    const int* __restrict__ bkt, int* __restrict__ st)
{
    __shared__ int lb[TT];
    __shared__ unsigned short cnt[128][64];
    __shared__ int base[64];
    const int r = blockIdx.x, bh = blockIdx.y;
    const int tid = threadIdx.x;
    const int* src = bkt + ((size_t)bh * NH + r) * TT;

    const int4* s4 = (const int4*)src;
    int4* l4 = (int4*)lb;
#pragma unroll
    for (int q = 0; q < 4; q++) l4[tid + q * 256] = s4[tid + q * 256];
    unsigned* cz = (unsigned*)cnt;
#pragma unroll
    for (int q = 0; q < 16; q++) cz[tid + q * 256] = 0;
    __syncthreads();

    if (tid < 128) {
        for (int it = 0; it < 32; it++) {
            int bb = lb[tid * 32 + it];
            cnt[tid][bb]++;
        }
    }
    __syncthreads();

    if (tid < 64) {
        const int bb = tid;
        int run = 0;
        for (int s = 0; s < 128; s++) {
            int t = cnt[s][bb];
            cnt[s][bb] = (unsigned short)run;
            run += t;
        }
        int inc = run;
#pragma unroll
        for (int off = 1; off < 64; off <<= 1) {
            int n = __shfl_up(inc, off, 64);
            if (tid >= off) inc += n;
        }
        base[bb] = inc - run;
    }
    __syncthreads();

    if (tid < 128) {
        int* dst = st + (size_t)bh * (NH * TT) + (size_t)r * TT;
        for (int it = 0; it < 32; it++) {
            int t = tid * 32 + it;
            int bb = lb[t];
            int pos = base[bb] + (int)cnt[tid][bb];
            cnt[tid][bb]++;
            dst[pos] = t;
        }
    }
}

// ---------------------------------------------------------------------------
// Attention v7: KV-interleaved packed input (row t, head h: 512B slab
// [K 64xu32 | V 64xu32]) -> one contiguous gather per row.
// 1-D grid of 2048 blocks: bhl = bid&7, c = bid>>3.
// ---------------------------------------------------------------------------
__global__ __launch_bounds__(256, 2) void attn_k(
    const unsigned* __restrict__ kvp,
    const int* __restrict__ st, float* __restrict__ obuf,
    float* __restrict__ lseb, int bh0)
{
    __shared__ __align__(16) ushort_t ksh[128 * 72];
    __shared__ __align__(16) ushort_t ksl[128 * 72];
    __shared__ __align__(16) unsigned vsp[128 * 66];
    __shared__ float invn[128];
    __shared__ int   tks[128];

    const int bid = blockIdx.x;
    const int bhl = bid & 7;
    const int c   = bid >> 3;
    const int bh  = bh0 + bhl;
    const int b   = bh >> 3, h = bh & 7;
    const int tid = threadIdx.x;
    const int* stb = st + (size_t)bh * (NH * TT);

    if (tid < 128) {
        int cc = (tid < 64) ? c : ((c + NC - 1) & (NC - 1));
        tks[tid] = stb[cc * 64 + (tid & 63)];
    }
    __syncthreads();

    {   // stage K (unpack hi/lo) + V (verbatim) + inv k-norms
        const int row = tid >> 1, c0 = (tid & 1) * 32;
        const int t = tks[row];
        const unsigned* kr = kvp + ((size_t)(b * TT + t)) * 1024 + h * 128;
        const uint4* kg = (const uint4*)(kr + c0);
        const uint4* vg = (const uint4*)(kr + 64 + c0);
        unsigned kp[32];
        uint4 vq[8];
        float ss = 0.f;
#pragma unroll
        for (int q = 0; q < 8; q++) {
            uint4 kq = kg[q];
            kp[4 * q + 0] = kq.x; kp[4 * q + 1] = kq.y;
            kp[4 * q + 2] = kq.z; kp[4 * q + 3] = kq.w;
            vq[q] = vg[q];
        }
#pragma unroll
        for (int e = 0; e < 32; e++) {
            float f = __uint_as_float(kp[e] << 16) + __uint_as_float(kp[e] & 0xffff0000u);
            ss = fmaf(f, f, ss);
        }
        ss += __shfl_xor(ss, 1);
        if ((tid & 1) == 0) invn[row] = 1.0f / fmaxf(sqrtf(ss), 1e-12f);

        unsigned hw[16], lw[16];
#pragma unroll
        for (int e = 0; e < 16; e++) {
            hw[e] = (kp[2 * e] & 0xffffu) | (kp[2 * e + 1] << 16);
            lw[e] = (kp[2 * e] >> 16) | (kp[2 * e + 1] & 0xffff0000u);
        }
        uint4* kdh = (uint4*)&ksh[row * 72 + c0];
        uint4* kdl = (uint4*)&ksl[row * 72 + c0];
#pragma unroll
        for (int q = 0; q < 4; q++) {
            kdh[q] = make_uint4(hw[4 * q], hw[4 * q + 1], hw[4 * q + 2], hw[4 * q + 3]);
            kdl[q] = make_uint4(lw[4 * q], lw[4 * q + 1], lw[4 * q + 2], lw[4 * q + 3]);
        }
        uint2* vd = (uint2*)&vsp[row * 66 + c0];
#pragma unroll
        for (int q = 0; q < 8; q++) {
            vd[2 * q]     = make_uint2(vq[q].x, vq[q].y);
            vd[2 * q + 1] = make_uint2(vq[q].z, vq[q].w);
        }
    }
    __syncthreads();

    const int lane = tid & 63;
    const int wv   = tid >> 6;
    const int cc16 = lane & 15;
    const int g    = lane >> 4;
    const int rr   = c >> 6;

    f32x4 stt[8];
#pragma unroll
    for (int jt = 0; jt < 8; jt++) stt[jt] = (f32x4)(0.f);

    const int qrow = wv * 16 + cc16;
#pragma unroll
    for (int ks = 0; ks < 2; ks++) {
        s16x8 qh = *(const s16x8*)&ksh[qrow * 72 + ks * 32 + g * 8];
        s16x8 ql = *(const s16x8*)&ksl[qrow * 72 + ks * 32 + g * 8];
        __builtin_amdgcn_s_setprio(1);
#pragma unroll
        for (int jt = 0; jt < 8; jt++) {
            const int krow = jt * 16 + cc16;
            s16x8 ah = *(const s16x8*)&ksh[krow * 72 + ks * 32 + g * 8];
            s16x8 al = *(const s16x8*)&ksl[krow * 72 + ks * 32 + g * 8];
            stt[jt] = __builtin_amdgcn_mfma_f32_16x16x32_bf16(ah, qh, stt[jt], 0, 0, 0);
            stt[jt] = __builtin_amdgcn_mfma_f32_16x16x32_bf16(al, qh, stt[jt], 0, 0, 0);
            stt[jt] = __builtin_amdgcn_mfma_f32_16x16x32_bf16(ah, ql, stt[jt], 0, 0, 0);
        }
        __builtin_amdgcn_s_setprio(0);
    }

    const int tqi = tks[wv * 16 + cc16];
    float m = -INFINITY;
#pragma unroll
    for (int jt = 0; jt < 8; jt++) {
#pragma unroll
        for (int r4 = 0; r4 < 4; r4++) {
            const int j = jt * 16 + g * 4 + r4;
            float d = stt[jt][r4] * invn[j] * 0.125f;
            if (tqi == tks[j]) d = -5e4f;
            stt[jt][r4] = d;
            m = fmaxf(m, d);
        }
    }
    m = fmaxf(m, __shfl_xor(m, 16));
    m = fmaxf(m, __shfl_xor(m, 32));
    float s = 0.f;
#pragma unroll
    for (int jt = 0; jt < 8; jt++) {
#pragma unroll
        for (int r4 = 0; r4 < 4; r4++) {
            float e = expf(stt[jt][r4] - m);
            stt[jt][r4] = e;
            s += e;
        }
    }
    s += __shfl_xor(s, 16);
    s += __shfl_xor(s, 32);
    const float is = 1.0f / s;
    if (g == 0) lseb[((size_t)bh * NH + rr) * TT + tqi] = m + logf(s);

    unsigned ph[8][2], pl[8][2];
#pragma unroll
    for (int jt = 0; jt < 8; jt++) {
#pragma unroll
        for (int w2 = 0; w2 < 2; w2++) {
            float p0 = stt[jt][2 * w2] * is;
            float p1 = stt[jt][2 * w2 + 1] * is;
            unsigned short h0 = f2bf(p0), h1 = f2bf(p1);
            ph[jt][w2] = (unsigned)h0 | ((unsigned)h1 << 16);
            pl[jt][w2] = (unsigned)f2bf(p0 - bf2f(h0)) | ((unsigned)f2bf(p1 - bf2f(h1)) << 16);
        }
    }

    f32x4 occ[4];
#pragma unroll
    for (int nt = 0; nt < 4; nt++) occ[nt] = (f32x4)(0.f);

    const int srcLow  = ((g & 1) << 5) + cc16;
    const int srcHigh = srcLow + 16;
    const bool hiT = (lane & 32) != 0;

#pragma unroll
    for (int ks = 0; ks < 4; ks++) {
        U4 Phi, Plo;
        {
            unsigned a0 = (unsigned)__shfl((int)ph[2 * ks][0], srcLow);
            unsigned a1 = (unsigned)__shfl((int)ph[2 * ks][1], srcLow);
            unsigned a2 = (unsigned)__shfl((int)ph[2 * ks][0], srcHigh);
            unsigned a3 = (unsigned)__shfl((int)ph[2 * ks][1], srcHigh);
            unsigned b0 = (unsigned)__shfl((int)ph[2 * ks + 1][0], srcLow);
            unsigned b1 = (unsigned)__shfl((int)ph[2 * ks + 1][1], srcLow);
            unsigned b2 = (unsigned)__shfl((int)ph[2 * ks + 1][0], srcHigh);
            unsigned b3 = (unsigned)__shfl((int)ph[2 * ks + 1][1], srcHigh);
            Phi.u[0] = hiT ? b0 : a0; Phi.u[1] = hiT ? b1 : a1;
            Phi.u[2] = hiT ? b2 : a2; Phi.u[3] = hiT ? b3 : a3;
            unsigned c0 = (unsigned)__shfl((int)pl[2 * ks][0], srcLow);
            unsigned c1 = (unsigned)__shfl((int)pl[2 * ks][1], srcLow);
            unsigned c2 = (unsigned)__shfl((int)pl[2 * ks][0], srcHigh);
            unsigned c3 = (unsigned)__shfl((int)pl[2 * ks][1], srcHigh);
            unsigned d0 = (unsigned)__shfl((int)pl[2 * ks + 1][0], srcLow);
            unsigned d1 = (unsigned)__shfl((int)pl[2 * ks + 1][1], srcLow);
            unsigned d2 = (unsigned)__shfl((int)pl[2 * ks + 1][0], srcHigh);
            unsigned d3 = (unsigned)__shfl((int)pl[2 * ks + 1][1], srcHigh);
            Plo.u[0] = hiT ? d0 : c0; Plo.u[1] = hiT ? d1 : c1;
            Plo.u[2] = hiT ? d2 : c2; Plo.u[3] = hiT ? d3 : c3;
        }
#pragma unroll
        for (int nt = 0; nt < 4; nt++) {
            unsigned u[8];
#pragma unroll
            for (int e = 0; e < 8; e++)
                u[e] = vsp[(32 * ks + 8 * g + e) * 66 + nt * 16 + cc16];
            U4 Vh, Vl;
#pragma unroll
            for (int m2 = 0; m2 < 4; m2++) {
                Vh.u[m2] = (u[2 * m2] & 0xffffu) | (u[2 * m2 + 1] << 16);
                Vl.u[m2] = (u[2 * m2] >> 16) | (u[2 * m2 + 1] & 0xffff0000u);
            }
            __builtin_amdgcn_s_setprio(1);
            occ[nt] = __builtin_amdgcn_mfma_f32_16x16x32_bf16(Phi.v, Vh.v, occ[nt], 0, 0, 0);
            occ[nt] = __builtin_amdgcn_mfma_f32_16x16x32_bf16(Plo.v, Vh.v, occ[nt], 0, 0, 0);
            occ[nt] = __builtin_amdgcn_mfma_f32_16x16x32_bf16(Phi.v, Vl.v, occ[nt], 0, 0, 0);
            __builtin_amdgcn_s_setprio(0);
        }
    }

#pragma unroll
    for (int r4 = 0; r4 < 4; r4++) {
        const int i = wv * 16 + g * 4 + r4;
        const int ti = tks[i];
        float* dst = obuf + (((size_t)bhl * NH + rr) * TT + ti) * DHH + cc16;
        dst[0]  = occ[0][r4];
        dst[16] = occ[1][r4];
        dst[32] = occ[2][r4];
        dst[48] = occ[3][r4];
    }
}

// ---------------------------------------------------------------------------
// Combine rounds for an 8-bh strip
// ---------------------------------------------------------------------------
__global__ __launch_bounds__(256) void combine_k(
    const float* __restrict__ obuf, const float* __restrict__ lseb,
    ushort_t* __restrict__ att, int bh0)
{
    int idx = blockIdx.x * 256 + threadIdx.x;
    int d = idx & 63;
    int t = (idx >> 6) & (TT - 1);
    int bhl = idx >> 18;
    int bh = bh0 + bhl;
    float l0 = lseb[((size_t)bh * NH + 0) * TT + t];
    float l1 = lseb[((size_t)bh * NH + 1) * TT + t];
    float l2 = lseb[((size_t)bh * NH + 2) * TT + t];
    float l3 = lseb[((size_t)bh * NH + 3) * TT + t];
    float m = fmaxf(fmaxf(l0, l1), fmaxf(l2, l3));
    float e0 = expf(l0 - m), e1 = expf(l1 - m), e2 = expf(l2 - m), e3 = expf(l3 - m);
    float inv = 1.0f / (e0 + e1 + e2 + e3);
    float o0 = obuf[(((size_t)bhl * NH + 0) * TT + t) * DHH + d];
    float o1 = obuf[(((size_t)bhl * NH + 1) * TT + t) * DHH + d];
    float o2 = obuf[(((size_t)bhl * NH + 2) * TT + t) * DHH + d];
    float o3 = obuf[(((size_t)bhl * NH + 3) * TT + t) * DHH + d];
    float o = (e0 * o0 + e1 * o1 + e2 * o2 + e3 * o3) * inv;
    int b = bh >> 3, h = bh & 7;
    size_t base = (size_t)(b * TT + t) * 1024 + h * DHH + d;
    unsigned short hi = f2bf(o);
    att[base]       = hi;
    att[base + 512] = f2bf(o - bf2f(hi));
}

// ---------------------------------------------------------------------------
// LayerNorm over D=512; optional 3-way bf16 split output. Safe in-place.
// ---------------------------------------------------------------------------
__global__ __launch_bounds__(64) void ln_k(
    const float* __restrict__ in, const float* __restrict__ g,
    const float* __restrict__ be, float* __restrict__ out,
    ushort_t* __restrict__ oh, ushort_t* __restrict__ ol,
    ushort_t* __restrict__ ol2)
{
    const int row = blockIdx.x;
    const int tid = threadIdx.x;
    const float* x = in + (size_t)row * DD;
    float4 a = *(const float4*)(x + tid * 8);
    float4 b = *(const float4*)(x + tid * 8 + 4);
    float s = a.x + a.y + a.z + a.w + b.x + b.y + b.z + b.w;
#pragma unroll
    for (int o = 32; o >= 1; o >>= 1) s += __shfl_xor(s, o, 64);
    float mean = s * (1.0f / 512.0f);
    float dx[8];
    dx[0] = a.x - mean; dx[1] = a.y - mean; dx[2] = a.z - mean; dx[3] = a.w - mean;
    dx[4] = b.x - mean; dx[5] = b.y - mean; dx[6] = b.z - mean; dx[7] = b.w - mean;
    float ss = 0.f;
#pragma unroll
    for (int q = 0; q < 8; q++) ss += dx[q] * dx[q];
#pragma unroll
    for (int o = 32; o >= 1; o >>= 1) ss += __shfl_xor(ss, o, 64);
    float var = ss * (1.0f / 512.0f);
    float inv = 1.0f / sqrtf(var + 1e-6f);
    const float* gp = g + tid * 8;
    const float* bp = be + tid * 8;
    float y[8];
#pragma unroll
    for (int q = 0; q < 8; q++) y[q] = dx[q] * inv * gp[q] + bp[q];
    float* yp = out + (size_t)row * DD + tid * 8;
    *(float4*)(yp)     = make_float4(y[0], y[1], y[2], y[3]);
    *(float4*)(yp + 4) = make_float4(y[4], y[5], y[6], y[7]);
    if (oh) {
        union { unsigned short us[8]; ushort4 v4[2]; } H, L, M;
#pragma unroll
        for (int q = 0; q < 8; q++) {
            unsigned short h = f2bf(y[q]);
            float r1 = y[q] - bf2f(h);
            unsigned short l = f2bf(r1);
            H.us[q] = h; L.us[q] = l;
            M.us[q] = f2bf(r1 - bf2f(l));
        }
        size_t e = (size_t)row * DD + tid * 8;
        *(ushort4*)(oh + e)      = H.v4[0];
        *(ushort4*)(oh + e + 4)  = H.v4[1];
        *(ushort4*)(ol + e)      = L.v4[0];
        *(ushort4*)(ol + e + 4)  = L.v4[1];
        *(ushort4*)(ol2 + e)     = M.v4[0];
        *(ushort4*)(ol2 + e + 4) = M.v4[1];
    }
}

// ---------------------------------------------------------------------------
extern "C" void kernel_launch(void* const* d_in, const int* in_sizes, int n_in,
                              void* d_out, int out_size, void* d_ws, size_t ws_size,
                              hipStream_t stream)
{
    const float* src  = (const float*)d_in[0];
    const float* rots = (const float*)d_in[1];
    const float* Wqk  = (const float*)d_in[2];
    const float* Wv   = (const float*)d_in[3];
    const float* Wout = (const float*)d_in[4];
    const float* bout = (const float*)d_in[5];
    const float* W1   = (const float*)d_in[6];
    const float* b1   = (const float*)d_in[7];
    const float* W2   = (const float*)d_in[8];
    const float* b2   = (const float*)d_in[9];
    const float* g2   = (const float*)d_in[10];
    const float* be2  = (const float*)d_in[11];
    const float* gf   = (const float*)d_in[12];
    const float* bf   = (const float*)d_in[13];
    float* out = (float*)d_out;

    // ---- workspace layout (~234 MB) ----
    // During attn: p+0 qkb/attb, p+1..p+3 kvp (interleaved K|V), p+3 obuf.
    // During FFN:  p+0..p+2 h1h, p+2..p+4 h1l; yff in-place on x.
    char* w = (char*)d_ws;
    const size_t SZ_X = (size_t)MROWS * DD * 4;               // 33.55 MB
    const size_t XHALF = (size_t)MROWS * DD;
    float*    x     = (float*)(w);
    ushort_t* xs    = (ushort_t*)(w + SZ_X);
    ushort_t* xh    = xs;
    ushort_t* xl    = xs + XHALF;
    ushort_t* xl2   = xs + 2 * XHALF;
    char*     p     = w + SZ_X + 3 * XHALF * 2;
    float*    qkb   = (float*)(p);
    ushort_t* attb  = (ushort_t*)(p);
    unsigned* kvp   = (unsigned*)(p + SZ_X);                  // 2 SZ_X, interleaved
    float*    obuf  = (float*)(p + 3 * SZ_X);
    ushort_t* h1h   = (ushort_t*)(p);                         // FFN: spans p..p+2SZ_X
    ushort_t* h1l   = (ushort_t*)(p + 2 * SZ_X);              // FFN: spans p+2..p+4SZ_X
    ushort_t* wb    = (ushort_t*)(p + 4 * SZ_X);
    char*     tail  = p + 4 * SZ_X + 6029312 * 2;
    int*      bkt   = (int*)(tail);
    int*      st    = (int*)(tail + (size_t)BHH * NH * TT * 4);
    float*    lseb  = (float*)(tail + 2 * (size_t)BHH * NH * TT * 4);

    ushort_t* wvh = wb;            ushort_t* wvl = wb + 262144;
    ushort_t* woh = wb + 524288;   ushort_t* wol = wb + 786432;
    ushort_t* w1h = wb + 1048576;  ushort_t* w1l = wb + 2097152;
    ushort_t* w2h = wb + 3145728;  ushort_t* w2l = wb + 4194304;
    ushort_t* wq1 = wb + 5242880;  ushort_t* wq2 = wb + 5505024;
    ushort_t* wq3 = wb + 5767168;

    // x copy + 3-way split in one pass
    cvt_k<<<(MROWS * DD / 4 + 255) / 256, 256, 0, stream>>>(src, xh, xl, xl2, x,
                                                            MROWS * DD / 4);

    for (int i = 0; i < LLAY; i++) {
        const float* Wqk_i = Wqk + (size_t)i * DD * DD;
        const float* Wv_i  = Wv  + (size_t)i * DD * DD;
        const float* Wout_i= Wout+ (size_t)i * DD * DD;
        const float* bout_i= bout+ (size_t)i * DD;
        const float* W1_i  = W1  + (size_t)i * DFFN * DD;
        const float* b1_i  = b1  + (size_t)i * DFFN;
        const float* W2_i  = W2  + (size_t)i * DD * DFFN;
        const float* b2_i  = b2  + (size_t)i * DD;
        const float* g2_i  = g2  + (size_t)i * DD;
        const float* be2_i = be2 + (size_t)i * DD;
        const float* rot_i = rots + (size_t)i * DHH * NH * 32;

        cvtw_k<<<2816, 256, 0, stream>>>(Wqk_i, Wv_i, Wout_i, W1_i, W2_i,
                                         wq1, wq2, wq3, wvh, wvl, woh, wol,
                                         w1h, w1l, w2h, w2l);

        // qk = x @ Wqk^T  (bf16x6, fp32 for bucket + packed K-half of kvp)
        gemm_bf6_k<<<dim3(4, 128), 256, 0, stream>>>(xh, xl, xl2, DD, wq1, wq2, wq3,
                                                     qkb, kvp, MROWS, DD, DD);
        // v = x @ Wv^T  (bf16x3, 2-phase, packed V-half of kvp)
        gemm_bf3_k<<<dim3(4, 128), 256, 0, stream>>>(xh, xl, DD, wvh, wvl, DD,
                                                     nullptr, nullptr,
                                                     nullptr, nullptr, nullptr, kvp + 64,
                                                     MROWS, DD, DD, 0);
        bucket_k<<<dim3(16, BHH), 256, 0, stream>>>(qkb, rot_i, bkt);
        sort_k<<<dim3(NH, BHH), 256, 0, stream>>>(bkt, st);

        // attention in 4 strips of 8 bh; combine -> att hi/lo
        for (int s = 0; s < 4; s++) {
            attn_k<<<2048, 256, 0, stream>>>(kvp, st, obuf, lseb, s * 8);
            combine_k<<<8192, 256, 0, stream>>>(obuf, lseb, attb, s * 8);
        }

        // x = x + att @ Wout^T + bout ; emit x hi/lo (for FFN input)
        gemm_bf3_k<<<dim3(4, 128), 256, 0, stream>>>(attb, attb + 512, 1024, woh, wol, DD,
                                                     bout_i, x, x, xh, xl, nullptr,
                                                     MROWS, DD, DD, 0);
        // FFN1 full-N via 256x256 tile / 8-wave kernel: h1 = relu(x @ W1^T + b1)
        gemm_bf3_256_k<<<dim3(8, 64), 512, 0, stream>>>(xh, xl, DD, w1h, w1l, DD,
                                                        b1_i, h1h, h1l,
                                                        MROWS, DFFN, DD, 1);
        // FFN2 full-K: x = x + h1 @ W2^T + b2  (in-place residual on x)
        gemm_bf3_k<<<dim3(4, 128), 256, 0, stream>>>(h1h, h1l, DFFN, w2h, w2l, DFFN,
                                                     b2_i, x,
                                                     x, nullptr, nullptr, nullptr,
                                                     MROWS, DD, DFFN, 0);
        // x = LN(x) in-place; emit 3-way split for next layer's qk/v
        ln_k<<<MROWS, 64, 0, stream>>>(x, g2_i, be2_i, x, xh, xl, xl2);
    }
    ln_k<<<MROWS, 64, 0, stream>>>(x, gf, bf, out, nullptr, nullptr, nullptr);
}

// Round 16
// 2930.106 us; speedup vs baseline: 1.0895x; 1.0107x over previous
//
#include <hip/hip_runtime.h>
#include <math.h>

#define TT    4096
#define DD    512
#define HH    8
#define DHH   64
#define NH    4
#define LLAY  4
#define DFFN  2048
#define BHH   32          // B*H
#define NC    256         // chunks per bh (NH*NB)
#define MROWS 16384       // B*T

typedef __attribute__((ext_vector_type(8))) short s16x8;
typedef __attribute__((ext_vector_type(4))) float f32x4;
typedef unsigned short ushort_t;

union U4 { unsigned u[4]; s16x8 v; };

__device__ __forceinline__ unsigned short f2bf(float f) {
    unsigned u = __float_as_uint(f);
    unsigned r = (u + 0x7FFFu + ((u >> 16) & 1u)) >> 16;
    return (unsigned short)r;
}
__device__ __forceinline__ float bf2f(unsigned short h) {
    return __uint_as_float(((unsigned)h) << 16);
}

// XCD-aware bijective swizzle (T1, m157): nwg must be divisible by 8.
__device__ __forceinline__ void xcd_swz(int& bx, int& by) {
    const int gx = gridDim.x;
    const int nwg = gx * gridDim.y;
    const int flat = by * gx + bx;
    const int q = nwg >> 3;
    const int swz = (flat & 7) * q + (flat >> 3);
    bx = swz % gx;
    by = swz / gx;
}

// ---------------------------------------------------------------------------
// bf16x3 MFMA GEMM, 128x128 tile, single-barrier 2-phase schedule (T3-min):
// per K-step: STAGE(next) -> ds_read(cur) -> MFMA -> vmcnt(0) -> barrier.
// ---------------------------------------------------------------------------
__global__ __launch_bounds__(256) void gemm_bf3_k(
    const ushort_t* __restrict__ Ah, const ushort_t* __restrict__ Al, int lda,
    const ushort_t* __restrict__ Wh, const ushort_t* __restrict__ Wl, int ldw,
    const float* __restrict__ bias, const float* __restrict__ resid,
    float* __restrict__ outf, ushort_t* __restrict__ outh, ushort_t* __restrict__ outl,
    unsigned* __restrict__ outp,
    int M, int N, int K, int relu)
{
    __shared__ __align__(16) ushort_t lds[2][4 * 128 * 32];   // 2 x 32KB
    const int tid  = threadIdx.x;
    const int lane = tid & 63;
    const int wv   = tid >> 6;
    const int wm   = wv >> 1, wn = wv & 1;
    int bx = blockIdx.x, by = blockIdx.y;
    xcd_swz(bx, by);
    const int row0 = by * 128, col0 = bx * 128;
    const int g    = lane >> 4;
    const int srow0 = wv * 32;

    f32x4 acc[4][4];
#pragma unroll
    for (int mi = 0; mi < 4; mi++)
#pragma unroll
        for (int ni = 0; ni < 4; ni++) acc[mi][ni] = (f32x4)(0.f);

    auto STAGE = [&](int buf, int k0) {
#pragma unroll
        for (int ii = 0; ii < 2; ii++) {
            const int r   = srow0 + ii * 16 + (lane >> 2);
            const int ug  = (((lane & 3) ^ ((r >> 1) & 3)) << 3);
            const size_t ga = (size_t)(row0 + r) * lda + k0 + ug;
            const size_t gw = (size_t)(col0 + r) * ldw + k0 + ug;
            const int lo  = (srow0 + ii * 16) * 32;
            __builtin_amdgcn_global_load_lds(
                (const __attribute__((address_space(1))) void*)(Ah + ga),
                (__attribute__((address_space(3))) void*)&lds[buf][0 * 4096 + lo], 16, 0, 0);
            __builtin_amdgcn_global_load_lds(
                (const __attribute__((address_space(1))) void*)(Al + ga),
                (__attribute__((address_space(3))) void*)&lds[buf][1 * 4096 + lo], 16, 0, 0);
            __builtin_amdgcn_global_load_lds(
                (const __attribute__((address_space(1))) void*)(Wh + gw),
                (__attribute__((address_space(3))) void*)&lds[buf][2 * 4096 + lo], 16, 0, 0);
            __builtin_amdgcn_global_load_lds(
                (const __attribute__((address_space(1))) void*)(Wl + gw),
                (__attribute__((address_space(3))) void*)&lds[buf][3 * 4096 + lo], 16, 0, 0);
        }
    };

    const int nt = K >> 5;
    STAGE(0, 0);
    asm volatile("s_waitcnt vmcnt(0)" ::: "memory");
    __builtin_amdgcn_s_barrier();

    int cur = 0;
    for (int t = 0; t < nt; ++t) {
        if (t + 1 < nt) STAGE(cur ^ 1, (t + 1) << 5);

        s16x8 ah[4], al[4], wh[4], wl[4];
#pragma unroll
        for (int mi = 0; mi < 4; mi++) {
            const int m  = wm * 64 + mi * 16 + (lane & 15);
            const int pu = ((g ^ ((m >> 1) & 3)) << 3);
            ah[mi] = *(const s16x8*)&lds[cur][0 * 4096 + m * 32 + pu];
            al[mi] = *(const s16x8*)&lds[cur][1 * 4096 + m * 32 + pu];
            const int n  = wn * 64 + mi * 16 + (lane & 15);
            const int pn = ((g ^ ((n >> 1) & 3)) << 3);
            wh[mi] = *(const s16x8*)&lds[cur][2 * 4096 + n * 32 + pn];
            wl[mi] = *(const s16x8*)&lds[cur][3 * 4096 + n * 32 + pn];
        }
        __builtin_amdgcn_s_setprio(1);
#pragma unroll
        for (int mi = 0; mi < 4; mi++)
#pragma unroll
            for (int ni = 0; ni < 4; ni++) {
                acc[mi][ni] = __builtin_amdgcn_mfma_f32_16x16x32_bf16(ah[mi], wh[ni], acc[mi][ni], 0, 0, 0);
                acc[mi][ni] = __builtin_amdgcn_mfma_f32_16x16x32_bf16(al[mi], wh[ni], acc[mi][ni], 0, 0, 0);
                acc[mi][ni] = __builtin_amdgcn_mfma_f32_16x16x32_bf16(ah[mi], wl[ni], acc[mi][ni], 0, 0, 0);
            }
        __builtin_amdgcn_s_setprio(0);

        asm volatile("s_waitcnt vmcnt(0)" ::: "memory");
        __builtin_amdgcn_s_barrier();     // read-release + next-tile visibility
        cur ^= 1;
    }

#pragma unroll
    for (int mi = 0; mi < 4; mi++) {
#pragma unroll
        for (int ni = 0; ni < 4; ni++) {
#pragma unroll
            for (int r = 0; r < 4; r++) {
                const int row = row0 + wm * 64 + mi * 16 + g * 4 + r;
                const int col = col0 + wn * 64 + ni * 16 + (lane & 15);
                float v = acc[mi][ni][r];
                if (bias)  v += bias[col];
                if (relu)  v = fmaxf(v, 0.f);
                if (resid) v += resid[(size_t)row * N + col];
                if (outf)  outf[(size_t)row * N + col] = v;
                if (outh) {
                    unsigned short h = f2bf(v);
                    outh[(size_t)row * N + col] = h;
                    outl[(size_t)row * N + col] = f2bf(v - bf2f(h));
                }
                if (outp) {
                    unsigned short h = f2bf(v);
                    outp[(size_t)row * 1024 + ((col >> 6) << 7) + (col & 63)] =
                        (unsigned)h | ((unsigned)f2bf(v - bf2f(h)) << 16);
                }
            }
        }
    }
}

// ---------------------------------------------------------------------------
// bf16x3 MFMA GEMM, 256x256 tile, 8 waves, single-barrier 2-phase schedule.
// ---------------------------------------------------------------------------
__global__ __launch_bounds__(512) void gemm_bf3_256_k(
    const ushort_t* __restrict__ Ah, const ushort_t* __restrict__ Al, int lda,
    const ushort_t* __restrict__ Wh, const ushort_t* __restrict__ Wl, int ldw,
    const float* __restrict__ bias,
    ushort_t* __restrict__ outh, ushort_t* __restrict__ outl,
    int M, int N, int K, int relu)
{
    __shared__ __align__(16) ushort_t lds[2][4 * 256 * 32];   // 2 x 64KB
    const int tid  = threadIdx.x;
    const int lane = tid & 63;
    const int wv   = tid >> 6;          // 0..7
    const int wm   = wv >> 2;           // 0..1
    const int wn   = wv & 3;            // 0..3
    int bx = blockIdx.x, by = blockIdx.y;
    xcd_swz(bx, by);
    const int row0 = by * 256, col0 = bx * 256;
    const int g    = lane >> 4;
    const int srow0 = wv * 32;

    f32x4 acc[8][4];
#pragma unroll
    for (int mi = 0; mi < 8; mi++)
#pragma unroll
        for (int ni = 0; ni < 4; ni++) acc[mi][ni] = (f32x4)(0.f);

    auto STAGE = [&](int buf, int k0) {
#pragma unroll
        for (int ii = 0; ii < 2; ii++) {
            const int r   = srow0 + ii * 16 + (lane >> 2);
            const int ug  = (((lane & 3) ^ ((r >> 1) & 3)) << 3);
            const size_t ga = (size_t)(row0 + r) * lda + k0 + ug;
            const size_t gw = (size_t)(col0 + r) * ldw + k0 + ug;
            const int lo  = (srow0 + ii * 16) * 32;
            __builtin_amdgcn_global_load_lds(
                (const __attribute__((address_space(1))) void*)(Ah + ga),
                (__attribute__((address_space(3))) void*)&lds[buf][0 * 8192 + lo], 16, 0, 0);
            __builtin_amdgcn_global_load_lds(
                (const __attribute__((address_space(1))) void*)(Al + ga),
                (__attribute__((address_space(3))) void*)&lds[buf][1 * 8192 + lo], 16, 0, 0);
            __builtin_amdgcn_global_load_lds(
                (const __attribute__((address_space(1))) void*)(Wh + gw),
                (__attribute__((address_space(3))) void*)&lds[buf][2 * 8192 + lo], 16, 0, 0);
            __builtin_amdgcn_global_load_lds(
                (const __attribute__((address_space(1))) void*)(Wl + gw),
                (__attribute__((address_space(3))) void*)&lds[buf][3 * 8192 + lo], 16, 0, 0);
        }
    };

    const int nt = K >> 5;
    STAGE(0, 0);
    asm volatile("s_waitcnt vmcnt(0)" ::: "memory");
    __builtin_amdgcn_s_barrier();

    int cur = 0;
    for (int t = 0; t < nt; ++t) {
        if (t + 1 < nt) STAGE(cur ^ 1, (t + 1) << 5);

        s16x8 wh[4], wl[4];
#pragma unroll
        for (int ni = 0; ni < 4; ni++) {
            const int n  = wn * 64 + ni * 16 + (lane & 15);
            const int pn = ((g ^ ((n >> 1) & 3)) << 3);
            wh[ni] = *(const s16x8*)&lds[cur][2 * 8192 + n * 32 + pn];
            wl[ni] = *(const s16x8*)&lds[cur][3 * 8192 + n * 32 + pn];
        }
#pragma unroll
        for (int half = 0; half < 2; half++) {
            s16x8 ah[4], al[4];
#pragma unroll
            for (int mj = 0; mj < 4; mj++) {
                const int m  = wm * 128 + (half * 4 + mj) * 16 + (lane & 15);
                const int pu = ((g ^ ((m >> 1) & 3)) << 3);
                ah[mj] = *(const s16x8*)&lds[cur][0 * 8192 + m * 32 + pu];
                al[mj] = *(const s16x8*)&lds[cur][1 * 8192 + m * 32 + pu];
            }
            __builtin_amdgcn_s_setprio(1);
#pragma unroll
            for (int mj = 0; mj < 4; mj++)
#pragma unroll
                for (int ni = 0; ni < 4; ni++) {
                    acc[half * 4 + mj][ni] = __builtin_amdgcn_mfma_f32_16x16x32_bf16(ah[mj], wh[ni], acc[half * 4 + mj][ni], 0, 0, 0);
                    acc[half * 4 + mj][ni] = __builtin_amdgcn_mfma_f32_16x16x32_bf16(al[mj], wh[ni], acc[half * 4 + mj][ni], 0, 0, 0);
                    acc[half * 4 + mj][ni] = __builtin_amdgcn_mfma_f32_16x16x32_bf16(ah[mj], wl[ni], acc[half * 4 + mj][ni], 0, 0, 0);
                }
            __builtin_amdgcn_s_setprio(0);
        }

        asm volatile("s_waitcnt vmcnt(0)" ::: "memory");
        __builtin_amdgcn_s_barrier();     // read-release + next-tile visibility
        cur ^= 1;
    }

#pragma unroll
    for (int mi = 0; mi < 8; mi++) {
#pragma unroll
        for (int ni = 0; ni < 4; ni++) {
#pragma unroll
            for (int r = 0; r < 4; r++) {
                const int row = row0 + wm * 128 + mi * 16 + g * 4 + r;
                const int col = col0 + wn * 64 + ni * 16 + (lane & 15);
                float v = acc[mi][ni][r];
                if (bias) v += bias[col];
                if (relu) v = fmaxf(v, 0.f);
                unsigned short h = f2bf(v);
                outh[(size_t)row * N + col] = h;
                outl[(size_t)row * N + col] = f2bf(v - bf2f(h));
            }
        }
    }
}

// ---------------------------------------------------------------------------
// bf16x6 MFMA GEMM (qk only): emits fp32 + packed KV-interleaved (K half).
// ---------------------------------------------------------------------------
__global__ __launch_bounds__(256) void gemm_bf6_k(
    const ushort_t* __restrict__ A1, const ushort_t* __restrict__ A2,
    const ushort_t* __restrict__ A3, int lda,
    const ushort_t* __restrict__ W1, const ushort_t* __restrict__ W2,
    const ushort_t* __restrict__ W3,
    float* __restrict__ outf, unsigned* __restrict__ outp, int M, int N, int K)
{
    __shared__ __align__(16) ushort_t lds[6 * 128 * 32];   // A1,A2,A3,W1,W2,W3
    const int tid  = threadIdx.x;
    const int lane = tid & 63;
    const int wv   = tid >> 6;
    const int wm   = wv >> 1, wn = wv & 1;
    int bx = blockIdx.x, by = blockIdx.y;
    xcd_swz(bx, by);
    const int row0 = by * 128, col0 = bx * 128;
    const int g    = lane >> 4;

    f32x4 acc[4][4];
#pragma unroll
    for (int mi = 0; mi < 4; mi++)
#pragma unroll
        for (int ni = 0; ni < 4; ni++) acc[mi][ni] = (f32x4)(0.f);

    const int srow0 = wv * 32;

    for (int k0 = 0; k0 < K; k0 += 32) {
        __syncthreads();
#pragma unroll
        for (int ii = 0; ii < 2; ii++) {
            const int r   = srow0 + ii * 16 + (lane >> 2);
            const int ug  = (((lane & 3) ^ ((r >> 1) & 3)) << 3);
            const size_t ga = (size_t)(row0 + r) * lda + k0 + ug;
            const size_t gw = (size_t)(col0 + r) * K   + k0 + ug;
            const int lo  = (srow0 + ii * 16) * 32;
            __builtin_amdgcn_global_load_lds(
                (const __attribute__((address_space(1))) void*)(A1 + ga),
                (__attribute__((address_space(3))) void*)&lds[0 * 4096 + lo], 16, 0, 0);
            __builtin_amdgcn_global_load_lds(
                (const __attribute__((address_space(1))) void*)(A2 + ga),
                (__attribute__((address_space(3))) void*)&lds[1 * 4096 + lo], 16, 0, 0);
            __builtin_amdgcn_global_load_lds(
                (const __attribute__((address_space(1))) void*)(A3 + ga),
                (__attribute__((address_space(3))) void*)&lds[2 * 4096 + lo], 16, 0, 0);
            __builtin_amdgcn_global_load_lds(
                (const __attribute__((address_space(1))) void*)(W1 + gw),
                (__attribute__((address_space(3))) void*)&lds[3 * 4096 + lo], 16, 0, 0);
            __builtin_amdgcn_global_load_lds(
                (const __attribute__((address_space(1))) void*)(W2 + gw),
                (__attribute__((address_space(3))) void*)&lds[4 * 4096 + lo], 16, 0, 0);
            __builtin_amdgcn_global_load_lds(
                (const __attribute__((address_space(1))) void*)(W3 + gw),
                (__attribute__((address_space(3))) void*)&lds[5 * 4096 + lo], 16, 0, 0);
        }
        __syncthreads();

        s16x8 a1[4], a2[4], a3[4], w1[4], w2[4], w3[4];
#pragma unroll
        for (int mi = 0; mi < 4; mi++) {
            const int m  = wm * 64 + mi * 16 + (lane & 15);
            const int pu = ((g ^ ((m >> 1) & 3)) << 3);
            a1[mi] = *(const s16x8*)&lds[0 * 4096 + m * 32 + pu];
            a2[mi] = *(const s16x8*)&lds[1 * 4096 + m * 32 + pu];
            a3[mi] = *(const s16x8*)&lds[2 * 4096 + m * 32 + pu];
            const int n  = wn * 64 + mi * 16 + (lane & 15);
            const int pn = ((g ^ ((n >> 1) & 3)) << 3);
            w1[mi] = *(const s16x8*)&lds[3 * 4096 + n * 32 + pn];
            w2[mi] = *(const s16x8*)&lds[4 * 4096 + n * 32 + pn];
            w3[mi] = *(const s16x8*)&lds[5 * 4096 + n * 32 + pn];
        }
        __builtin_amdgcn_s_setprio(1);
#pragma unroll
        for (int mi = 0; mi < 4; mi++)
#pragma unroll
            for (int ni = 0; ni < 4; ni++) {
                acc[mi][ni] = __builtin_amdgcn_mfma_f32_16x16x32_bf16(a1[mi], w1[ni], acc[mi][ni], 0, 0, 0);
                acc[mi][ni] = __builtin_amdgcn_mfma_f32_16x16x32_bf16(a2[mi], w1[ni], acc[mi][ni], 0, 0, 0);
                acc[mi][ni] = __builtin_amdgcn_mfma_f32_16x16x32_bf16(a1[mi], w2[ni], acc[mi][ni], 0, 0, 0);
                acc[mi][ni] = __builtin_amdgcn_mfma_f32_16x16x32_bf16(a2[mi], w2[ni], acc[mi][ni], 0, 0, 0);
                acc[mi][ni] = __builtin_amdgcn_mfma_f32_16x16x32_bf16(a1[mi], w3[ni], acc[mi][ni], 0, 0, 0);
                acc[mi][ni] = __builtin_amdgcn_mfma_f32_16x16x32_bf16(a3[mi], w1[ni], acc[mi][ni], 0, 0, 0);
            }
        __builtin_amdgcn_s_setprio(0);
    }

#pragma unroll
    for (int mi = 0; mi < 4; mi++) {
#pragma unroll
        for (int ni = 0; ni < 4; ni++) {
#pragma unroll
            for (int r = 0; r < 4; r++) {
                const int row = row0 + wm * 64 + mi * 16 + g * 4 + r;
                const int col = col0 + wn * 64 + ni * 16 + (lane & 15);
                float v = acc[mi][ni][r];
                outf[(size_t)row * N + col] = v;
                unsigned short h = f2bf(v);
                outp[(size_t)row * 1024 + ((col >> 6) << 7) + (col & 63)] =
                    (unsigned)h | ((unsigned)f2bf(v - bf2f(h)) << 16);
            }
        }
    }
}

// ---------------------------------------------------------------------------
// fp32 -> bf16 split converter (+ optional fp32 copy)
// ---------------------------------------------------------------------------
__global__ __launch_bounds__(256) void cvt_k(
    const float* __restrict__ in, ushort_t* __restrict__ o1,
    ushort_t* __restrict__ o2, ushort_t* __restrict__ o3,
    float* __restrict__ ocopy, int n4)
{
    int i = blockIdx.x * 256 + threadIdx.x;
    if (i >= n4) return;
    float4 v = ((const float4*)in)[i];
    if (ocopy) ((float4*)ocopy)[i] = v;
    float vv[4] = {v.x, v.y, v.z, v.w};
    union { unsigned short us[4]; ushort4 v4; } H, L, M;
#pragma unroll
    for (int q = 0; q < 4; q++) {
        unsigned short a = f2bf(vv[q]);
        float r1 = vv[q] - bf2f(a);
        unsigned short b = f2bf(r1);
        H.us[q] = a; L.us[q] = b;
        M.us[q] = f2bf(r1 - bf2f(b));
    }
    ((ushort4*)o1)[i] = H.v4;
    ((ushort4*)o2)[i] = L.v4;
    if (o3) ((ushort4*)o3)[i] = M.v4;
}

// ---------------------------------------------------------------------------
// Batched per-layer weight split conversion (one launch, 2816 blocks)
// ---------------------------------------------------------------------------
__global__ __launch_bounds__(256) void cvtw_k(
    const float* __restrict__ Wqk_i, const float* __restrict__ Wv_i,
    const float* __restrict__ Wout_i, const float* __restrict__ W1_i,
    const float* __restrict__ W2_i,
    ushort_t* __restrict__ wq1, ushort_t* __restrict__ wq2, ushort_t* __restrict__ wq3,
    ushort_t* __restrict__ wvh, ushort_t* __restrict__ wvl,
    ushort_t* __restrict__ woh, ushort_t* __restrict__ wol,
    ushort_t* __restrict__ w1h, ushort_t* __restrict__ w1l,
    ushort_t* __restrict__ w2h, ushort_t* __restrict__ w2l)
{
    const int blk = blockIdx.x;
    const float* in;
    ushort_t *o1, *o2, *o3 = nullptr;
    int i;
    if (blk < 256)       { in = Wqk_i;  o1 = wq1; o2 = wq2; o3 = wq3; i = blk * 256; }
    else if (blk < 512)  { in = Wv_i;   o1 = wvh; o2 = wvl; i = (blk - 256) * 256; }
    else if (blk < 768)  { in = Wout_i; o1 = woh; o2 = wol; i = (blk - 512) * 256; }
    else if (blk < 1792) { in = W1_i;   o1 = w1h; o2 = w1l; i = (blk - 768) * 256; }
    else                 { in = W2_i;   o1 = w2h; o2 = w2l; i = (blk - 1792) * 256; }
    i += threadIdx.x;
    float4 v = ((const float4*)in)[i];
    float vv[4] = {v.x, v.y, v.z, v.w};
    union { unsigned short us[4]; ushort4 v4; } H, L, M;
#pragma unroll
    for (int q = 0; q < 4; q++) {
        unsigned short a = f2bf(vv[q]);
        float r1 = vv[q] - bf2f(a);
        unsigned short b = f2bf(r1);
        H.us[q] = a; L.us[q] = b;
        M.us[q] = f2bf(r1 - bf2f(b));
    }
    ((ushort4*)o1)[i] = H.v4;
    ((ushort4*)o2)[i] = L.v4;
    if (o3) ((ushort4*)o3)[i] = M.v4;
}

// ---------------------------------------------------------------------------
// Bucket kernel v2 (all 4 rounds per block) — reads fp32 qk
// ---------------------------------------------------------------------------
__global__ __launch_bounds__(256) void bucket_k(
    const float* __restrict__ qk, const float* __restrict__ rot,
    int* __restrict__ bkt)
{
    __shared__ float rs[NH][64][32];    // 32 KB
    const int bh = blockIdx.y;
    const int t = blockIdx.x * 256 + threadIdx.x;
    for (int i = threadIdx.x; i < NH * 64 * 32; i += 256) {
        int r = i >> 11, f = (i >> 5) & 63, j = i & 31;
        rs[r][f][j] = rot[(f * NH + r) * 32 + j];
    }
    __syncthreads();
    const int b = bh >> 3, h = bh & 7;
    const float* q = qk + ((size_t)(b * TT + t)) * DD + h * DHH;
    float qv[64];
#pragma unroll
    for (int f4 = 0; f4 < 16; f4++) {
        float4 tmp = ((const float4*)q)[f4];
        qv[f4 * 4 + 0] = tmp.x; qv[f4 * 4 + 1] = tmp.y;
        qv[f4 * 4 + 2] = tmp.z; qv[f4 * 4 + 3] = tmp.w;
    }
    for (int r = 0; r < NH; r++) {
        float rv[32];
#pragma unroll
        for (int j = 0; j < 32; j++) rv[j] = 0.f;
        for (int f = 0; f < 64; f++) {
            float qf = qv[f];
#pragma unroll
            for (int j = 0; j < 32; j++) rv[j] = fmaf(qf, rs[r][f][j], rv[j]);
        }
        float best = rv[0];
        int bi = 0;
#pragma unroll
        for (int j = 1; j < 32; j++) { if (rv[j] > best) { best = rv[j]; bi = j; } }
#pragma unroll
        for (int j = 0; j < 32; j++) { float v = -rv[j]; if (v > best) { best = v; bi = 32 + j; } }
        bkt[((size_t)bh * NH + r) * TT + t] = bi;
    }
}

// ---------------------------------------------------------------------------
// Parallel stable counting sort per (bh, round). (verified R4)
// ---------------------------------------------------------------------------
__global__ __launch_bounds__(256) void sort_k(
    const int* __restrict__ bkt, int* __restrict__ st)
{
    __shared__ int lb[TT];
    __shared__ unsigned short cnt[128][64];
    __shared__ int base[64];
    const int r = blockIdx.x, bh = blockIdx.y;
    const int tid = threadIdx.x;
    const int* src = bkt + ((size_t)bh * NH + r) * TT;

    const int4* s4 = (const int4*)src;
    int4* l4 = (int4*)lb;
#pragma unroll
    for (int q = 0; q < 4; q++) l4[tid + q * 256] = s4[tid + q * 256];
    unsigned* cz = (unsigned*)cnt;
#pragma unroll
    for (int q = 0; q < 16; q++) cz[tid + q * 256] = 0;
    __syncthreads();

    if (tid < 128) {
        for (int it = 0; it < 32; it++) {
            int bb = lb[tid * 32 + it];
            cnt[tid][bb]++;
        }
    }
    __syncthreads();

    if (tid < 64) {
        const int bb = tid;
        int run = 0;
        for (int s = 0; s < 128; s++) {
            int t = cnt[s][bb];
            cnt[s][bb] = (unsigned short)run;
            run += t;
        }
        int inc = run;
#pragma unroll
        for (int off = 1; off < 64; off <<= 1) {
            int n = __shfl_up(inc, off, 64);
            if (tid >= off) inc += n;
        }
        base[bb] = inc - run;
    }
    __syncthreads();

    if (tid < 128) {
        int* dst = st + (size_t)bh * (NH * TT) + (size_t)r * TT;
        for (int it = 0; it < 32; it++) {
            int t = tid * 32 + it;
            int bb = lb[t];
            int pos = base[bb] + (int)cnt[tid][bb];
            cnt[tid][bb]++;
            dst[pos] = t;
        }
    }
}

// ---------------------------------------------------------------------------
// Attention v7: KV-interleaved packed input (row t, head h: 512B slab
// [K 64xu32 | V 64xu32]) -> one contiguous gather per row.
// 1-D grid of 2048 blocks: bhl = bid&7, c = bid>>3.
// ---------------------------------------------------------------------------
__global__ __launch_bounds__(256, 2) void attn_k(
    const unsigned* __restrict__ kvp,
    const int* __restrict__ st, float* __restrict__ obuf,
    float* __restrict__ lseb, int bh0)
{
    __shared__ __align__(16) ushort_t ksh[128 * 72];
    __shared__ __align__(16) ushort_t ksl[128 * 72];
    __shared__ __align__(16) unsigned vsp[128 * 66];
    __shared__ float invn[128];
    __shared__ int   tks[128];

    const int bid = blockIdx.x;
    const int bhl = bid & 7;
    const int c   = bid >> 3;
    const int bh  = bh0 + bhl;
    const int b   = bh >> 3, h = bh & 7;
    const int tid = threadIdx.x;
    const int* stb = st + (size_t)bh * (NH * TT);

    if (tid < 128) {
        int cc = (tid < 64) ? c : ((c + NC - 1) & (NC - 1));
        tks[tid] = stb[cc * 64 + (tid & 63)];
    }
    __syncthreads();

    {   // stage K (unpack hi/lo) + V (verbatim) + inv k-norms
        const int row = tid >> 1, c0 = (tid & 1) * 32;
        const int t = tks[row];
        const unsigned* kr = kvp + ((size_t)(b * TT + t)) * 1024 + h * 128;
        const uint4* kg = (const uint4*)(kr + c0);
        const uint4* vg = (const uint4*)(kr + 64 + c0);
        unsigned kp[32];
        uint4 vq[8];
        float ss = 0.f;
#pragma unroll
        for (int q = 0; q < 8; q++) {
            uint4 kq = kg[q];
            kp[4 * q + 0] = kq.x; kp[4 * q + 1] = kq.y;
            kp[4 * q + 2] = kq.z; kp[4 * q + 3] = kq.w;
            vq[q] = vg[q];
        }
#pragma unroll
        for (int e = 0; e < 32; e++) {
            float f = __uint_as_float(kp[e] << 16) + __uint_as_float(kp[e] & 0xffff0000u);
            ss = fmaf(f, f, ss);
        }
        ss += __shfl_xor(ss, 1);
        if ((tid & 1) == 0) invn[row] = 1.0f / fmaxf(sqrtf(ss), 1e-12f);

        unsigned hw[16], lw[16];
#pragma unroll
        for (int e = 0; e < 16; e++) {
            hw[e] = (kp[2 * e] & 0xffffu) | (kp[2 * e + 1] << 16);
            lw[e] = (kp[2 * e] >> 16) | (kp[2 * e + 1] & 0xffff0000u);
        }
        uint4* kdh = (uint4*)&ksh[row * 72 + c0];
        uint4* kdl = (uint4*)&ksl[row * 72 + c0];
#pragma unroll
        for (int q = 0; q < 4; q++) {
            kdh[q] = make_uint4(hw[4 * q], hw[4 * q + 1], hw[4 * q + 2], hw[4 * q + 3]);
            kdl[q] = make_uint4(lw[4 * q], lw[4 * q + 1], lw[4 * q + 2], lw[4 * q + 3]);
        }
        uint2* vd = (uint2*)&vsp[row * 66 + c0];
#pragma unroll
        for (int q = 0; q < 8; q++) {
            vd[2 * q]     = make_uint2(vq[q].x, vq[q].y);
            vd[2 * q + 1] = make_uint2(vq[q].z, vq[q].w);
        }
    }
    __syncthreads();

    const int lane = tid & 63;
    const int wv   = tid >> 6;
    const int cc16 = lane & 15;
    const int g    = lane >> 4;
    const int rr   = c >> 6;

    f32x4 stt[8];
#pragma unroll
    for (int jt = 0; jt < 8; jt++) stt[jt] = (f32x4)(0.f);

    const int qrow = wv * 16 + cc16;
#pragma unroll
    for (int ks = 0; ks < 2; ks++) {
        s16x8 qh = *(const s16x8*)&ksh[qrow * 72 + ks * 32 + g * 8];
        s16x8 ql = *(const s16x8*)&ksl[qrow * 72 + ks * 32 + g * 8];
        __builtin_amdgcn_s_setprio(1);
#pragma unroll
        for (int jt = 0; jt < 8; jt++) {
            const int krow = jt * 16 + cc16;
            s16x8 ah = *(const s16x8*)&ksh[krow * 72 + ks * 32 + g * 8];
            s16x8 al = *(const s16x8*)&ksl[krow * 72 + ks * 32 + g * 8];
            stt[jt] = __builtin_amdgcn_mfma_f32_16x16x32_bf16(ah, qh, stt[jt], 0, 0, 0);
            stt[jt] = __builtin_amdgcn_mfma_f32_16x16x32_bf16(al, qh, stt[jt], 0, 0, 0);
            stt[jt] = __builtin_amdgcn_mfma_f32_16x16x32_bf16(ah, ql, stt[jt], 0, 0, 0);
        }
        __builtin_amdgcn_s_setprio(0);
    }

    const int tqi = tks[wv * 16 + cc16];
    float m = -INFINITY;
#pragma unroll
    for (int jt = 0; jt < 8; jt++) {
#pragma unroll
        for (int r4 = 0; r4 < 4; r4++) {
            const int j = jt * 16 + g * 4 + r4;
            float d = stt[jt][r4] * invn[j] * 0.125f;
            if (tqi == tks[j]) d = -5e4f;
            stt[jt][r4] = d;
            m = fmaxf(m, d);
        }
    }
    m = fmaxf(m, __shfl_xor(m, 16));
    m = fmaxf(m, __shfl_xor(m, 32));
    float s = 0.f;
#pragma unroll
    for (int jt = 0; jt < 8; jt++) {
#pragma unroll
        for (int r4 = 0; r4 < 4; r4++) {
            float e = expf(stt[jt][r4] - m);
            stt[jt][r4] = e;
            s += e;
        }
    }
    s += __shfl_xor(s, 16);
    s += __shfl_xor(s, 32);
    const float is = 1.0f / s;
    if (g == 0) lseb[((size_t)bh * NH + rr) * TT + tqi] = m + logf(s);

    unsigned ph[8][2], pl[8][2];
#pragma unroll
    for (int jt = 0; jt < 8; jt++) {
#pragma unroll
        for (int w2 = 0; w2 < 2; w2++) {
            float p0 = stt[jt][2 * w2] * is;
            float p1 = stt[jt][2 * w2 + 1] * is;
            unsigned short h0 = f2bf(p0), h1 = f2bf(p1);
            ph[jt][w2] = (unsigned)h0 | ((unsigned)h1 << 16);
            pl[jt][w2] = (unsigned)f2bf(p0 - bf2f(h0)) | ((unsigned)f2bf(p1 - bf2f(h1)) << 16);
        }
    }

    f32x4 occ[4];
#pragma unroll
    for (int nt = 0; nt < 4; nt++) occ[nt] = (f32x4)(0.f);

    const int srcLow  = ((g & 1) << 5) + cc16;
    const int srcHigh = srcLow + 16;
    const bool hiT = (lane & 32) != 0;

#pragma unroll
    for (int ks = 0; ks < 4; ks++) {
        U4 Phi, Plo;
        {
            unsigned a0 = (unsigned)__shfl((int)ph[2 * ks][0], srcLow);
            unsigned a1 = (unsigned)__shfl((int)ph[2 * ks][1], srcLow);
            unsigned a2 = (unsigned)__shfl((int)ph[2 * ks][0], srcHigh);
            unsigned a3 = (unsigned)__shfl((int)ph[2 * ks][1], srcHigh);
            unsigned b0 = (unsigned)__shfl((int)ph[2 * ks + 1][0], srcLow);
            unsigned b1 = (unsigned)__shfl((int)ph[2 * ks + 1][1], srcLow);
            unsigned b2 = (unsigned)__shfl((int)ph[2 * ks + 1][0], srcHigh);
            unsigned b3 = (unsigned)__shfl((int)ph[2 * ks + 1][1], srcHigh);
            Phi.u[0] = hiT ? b0 : a0; Phi.u[1] = hiT ? b1 : a1;
            Phi.u[2] = hiT ? b2 : a2; Phi.u[3] = hiT ? b3 : a3;
            unsigned c0 = (unsigned)__shfl((int)pl[2 * ks][0], srcLow);
            unsigned c1 = (unsigned)__shfl((int)pl[2 * ks][1], srcLow);
            unsigned c2 = (unsigned)__shfl((int)pl[2 * ks][0], srcHigh);
            unsigned c3 = (unsigned)__shfl((int)pl[2 * ks][1], srcHigh);
            unsigned d0 = (unsigned)__shfl((int)pl[2 * ks + 1][0], srcLow);
            unsigned d1 = (unsigned)__shfl((int)pl[2 * ks + 1][1], srcLow);
            unsigned d2 = (unsigned)__shfl((int)pl[2 * ks + 1][0], srcHigh);
            unsigned d3 = (unsigned)__shfl((int)pl[2 * ks + 1][1], srcHigh);
            Plo.u[0] = hiT ? d0 : c0; Plo.u[1] = hiT ? d1 : c1;
            Plo.u[2] = hiT ? d2 : c2; Plo.u[3] = hiT ? d3 : c3;
        }
#pragma unroll
        for (int nt = 0; nt < 4; nt++) {
            unsigned u[8];
#pragma unroll
            for (int e = 0; e < 8; e++)
                u[e] = vsp[(32 * ks + 8 * g + e) * 66 + nt * 16 + cc16];
            U4 Vh, Vl;
#pragma unroll
            for (int m2 = 0; m2 < 4; m2++) {
                Vh.u[m2] = (u[2 * m2] & 0xffffu) | (u[2 * m2 + 1] << 16);
                Vl.u[m2] = (u[2 * m2] >> 16) | (u[2 * m2 + 1] & 0xffff0000u);
            }
            __builtin_amdgcn_s_setprio(1);
            occ[nt] = __builtin_amdgcn_mfma_f32_16x16x32_bf16(Phi.v, Vh.v, occ[nt], 0, 0, 0);
            occ[nt] = __builtin_amdgcn_mfma_f32_16x16x32_bf16(Plo.v, Vh.v, occ[nt], 0, 0, 0);
            occ[nt] = __builtin_amdgcn_mfma_f32_16x16x32_bf16(Phi.v, Vl.v, occ[nt], 0, 0, 0);
            __builtin_amdgcn_s_setprio(0);
        }
    }

#pragma unroll
    for (int r4 = 0; r4 < 4; r4++) {
        const int i = wv * 16 + g * 4 + r4;
        const int ti = tks[i];
        float* dst = obuf + (((size_t)bhl * NH + rr) * TT + ti) * DHH + cc16;
        dst[0]  = occ[0][r4];
        dst[16] = occ[1][r4];
        dst[32] = occ[2][r4];
        dst[48] = occ[3][r4];
    }
}

// ---------------------------------------------------------------------------
// Combine rounds for an 8-bh strip
// ---------------------------------------------------------------------------
__global__ __launch_bounds__(256) void combine_k(
    const float* __restrict__ obuf, const float* __restrict__ lseb,
    ushort_t* __restrict__ att, int bh0)
{
    int idx = blockIdx.x * 256 + threadIdx.x;
    int d = idx & 63;
    int t = (idx >> 6) & (TT - 1);
    int bhl = idx >> 18;
    int bh = bh0 + bhl;
    float l0 = lseb[((size_t)bh * NH + 0) * TT + t];
    float l1 = lseb[((size_t)bh * NH + 1) * TT + t];
    float l2 = lseb[((size_t)bh * NH + 2) * TT + t];
    float l3 = lseb[((size_t)bh * NH + 3) * TT + t];
    float m = fmaxf(fmaxf(l0, l1), fmaxf(l2, l3));
    float e0 = expf(l0 - m), e1 = expf(l1 - m), e2 = expf(l2 - m), e3 = expf(l3 - m);
    float inv = 1.0f / (e0 + e1 + e2 + e3);
    float o0 = obuf[(((size_t)bhl * NH + 0) * TT + t) * DHH + d];
    float o1 = obuf[(((size_t)bhl * NH + 1) * TT + t) * DHH + d];
    float o2 = obuf[(((size_t)bhl * NH + 2) * TT + t) * DHH + d];
    float o3 = obuf[(((size_t)bhl * NH + 3) * TT + t) * DHH + d];
    float o = (e0 * o0 + e1 * o1 + e2 * o2 + e3 * o3) * inv;
    int b = bh >> 3, h = bh & 7;
    size_t base = (size_t)(b * TT + t) * 1024 + h * DHH + d;
    unsigned short hi = f2bf(o);
    att[base]       = hi;
    att[base + 512] = f2bf(o - bf2f(hi));
}

// ---------------------------------------------------------------------------
// LayerNorm over D=512; optional 3-way bf16 split output. Safe in-place.
// ---------------------------------------------------------------------------
__global__ __launch_bounds__(64) void ln_k(
    const float* __restrict__ in, const float* __restrict__ g,
    const float* __restrict__ be, float* __restrict__ out,
    ushort_t* __restrict__ oh, ushort_t* __restrict__ ol,
    ushort_t* __restrict__ ol2)
{
    const int row = blockIdx.x;
    const int tid = threadIdx.x;
    const float* x = in + (size_t)row * DD;
    float4 a = *(const float4*)(x + tid * 8);
    float4 b = *(const float4*)(x + tid * 8 + 4);
    float s = a.x + a.y + a.z + a.w + b.x + b.y + b.z + b.w;
#pragma unroll
    for (int o = 32; o >= 1; o >>= 1) s += __shfl_xor(s, o, 64);
    float mean = s * (1.0f / 512.0f);
    float dx[8];
    dx[0] = a.x - mean; dx[1] = a.y - mean; dx[2] = a.z - mean; dx[3] = a.w - mean;
    dx[4] = b.x - mean; dx[5] = b.y - mean; dx[6] = b.z - mean; dx[7] = b.w - mean;
    float ss = 0.f;
#pragma unroll
    for (int q = 0; q < 8; q++) ss += dx[q] * dx[q];
#pragma unroll
    for (int o = 32; o >= 1; o >>= 1) ss += __shfl_xor(ss, o, 64);
    float var = ss * (1.0f / 512.0f);
    float inv = 1.0f / sqrtf(var + 1e-6f);
    const float* gp = g + tid * 8;
    const float* bp = be + tid * 8;
    float y[8];
#pragma unroll
    for (int q = 0; q < 8; q++) y[q] = dx[q] * inv * gp[q] + bp[q];
    float* yp = out + (size_t)row * DD + tid * 8;
    *(float4*)(yp)     = make_float4(y[0], y[1], y[2], y[3]);
    *(float4*)(yp + 4) = make_float4(y[4], y[5], y[6], y[7]);
    if (oh) {
        union { unsigned short us[8]; ushort4 v4[2]; } H, L, M;
#pragma unroll
        for (int q = 0; q < 8; q++) {
            unsigned short h = f2bf(y[q]);
            float r1 = y[q] - bf2f(h);
            unsigned short l = f2bf(r1);
            H.us[q] = h; L.us[q] = l;
            M.us[q] = f2bf(r1 - bf2f(l));
        }
        size_t e = (size_t)row * DD + tid * 8;
        *(ushort4*)(oh + e)      = H.v4[0];
        *(ushort4*)(oh + e + 4)  = H.v4[1];
        *(ushort4*)(ol + e)      = L.v4[0];
        *(ushort4*)(ol + e + 4)  = L.v4[1];
        *(ushort4*)(ol2 + e)     = M.v4[0];
        *(ushort4*)(ol2 + e + 4) = M.v4[1];
    }
}

// ---------------------------------------------------------------------------
extern "C" void kernel_launch(void* const* d_in, const int* in_sizes, int n_in,
                              void* d_out, int out_size, void* d_ws, size_t ws_size,
                              hipStream_t stream)
{
    const float* src  = (const float*)d_in[0];
    const float* rots = (const float*)d_in[1];
    const float* Wqk  = (const float*)d_in[2];
    const float* Wv   = (const float*)d_in[3];
    const float* Wout = (const float*)d_in[4];
    const float* bout = (const float*)d_in[5];
    const float* W1   = (const float*)d_in[6];
    const float* b1   = (const float*)d_in[7];
    const float* W2   = (const float*)d_in[8];
    const float* b2   = (const float*)d_in[9];
    const float* g2   = (const float*)d_in[10];
    const float* be2  = (const float*)d_in[11];
    const float* gf   = (const float*)d_in[12];
    const float* bf   = (const float*)d_in[13];
    float* out = (float*)d_out;

    // ---- workspace layout (~234 MB) ----
    char* w = (char*)d_ws;
    const size_t SZ_X = (size_t)MROWS * DD * 4;               // 33.55 MB
    const size_t XHALF = (size_t)MROWS * DD;
    float*    x     = (float*)(w);
    ushort_t* xs    = (ushort_t*)(w + SZ_X);
    ushort_t* xh    = xs;
    ushort_t* xl    = xs + XHALF;
    ushort_t* xl2   = xs + 2 * XHALF;
    char*     p     = w + SZ_X + 3 * XHALF * 2;
    float*    qkb   = (float*)(p);
    ushort_t* attb  = (ushort_t*)(p);
    unsigned* kvp   = (unsigned*)(p + SZ_X);                  // 2 SZ_X, interleaved
    float*    obuf  = (float*)(p + 3 * SZ_X);
    ushort_t* h1h   = (ushort_t*)(p);                         // FFN: spans p..p+2SZ_X
    ushort_t* h1l   = (ushort_t*)(p + 2 * SZ_X);              // FFN: spans p+2..p+4SZ_X
    ushort_t* wb    = (ushort_t*)(p + 4 * SZ_X);
    char*     tail  = p + 4 * SZ_X + 6029312 * 2;
    int*      bkt   = (int*)(tail);
    int*      st    = (int*)(tail + (size_t)BHH * NH * TT * 4);
    float*    lseb  = (float*)(tail + 2 * (size_t)BHH * NH * TT * 4);

    ushort_t* wvh = wb;            ushort_t* wvl = wb + 262144;
    ushort_t* woh = wb + 524288;   ushort_t* wol = wb + 786432;
    ushort_t* w1h = wb + 1048576;  ushort_t* w1l = wb + 2097152;
    ushort_t* w2h = wb + 3145728;  ushort_t* w2l = wb + 4194304;
    ushort_t* wq1 = wb + 5242880;  ushort_t* wq2 = wb + 5505024;
    ushort_t* wq3 = wb + 5767168;

    // x copy + 3-way split in one pass
    cvt_k<<<(MROWS * DD / 4 + 255) / 256, 256, 0, stream>>>(src, xh, xl, xl2, x,
                                                            MROWS * DD / 4);

    for (int i = 0; i < LLAY; i++) {
        const float* Wqk_i = Wqk + (size_t)i * DD * DD;
        const float* Wv_i  = Wv  + (size_t)i * DD * DD;
        const float* Wout_i= Wout+ (size_t)i * DD * DD;
        const float* bout_i= bout+ (size_t)i * DD;
        const float* W1_i  = W1  + (size_t)i * DFFN * DD;
        const float* b1_i  = b1  + (size_t)i * DFFN;
        const float* W2_i  = W2  + (size_t)i * DD * DFFN;
        const float* b2_i  = b2  + (size_t)i * DD;
        const float* g2_i  = g2  + (size_t)i * DD;
        const float* be2_i = be2 + (size_t)i * DD;
        const float* rot_i = rots + (size_t)i * DHH * NH * 32;

        cvtw_k<<<2816, 256, 0, stream>>>(Wqk_i, Wv_i, Wout_i, W1_i, W2_i,
                                         wq1, wq2, wq3, wvh, wvl, woh, wol,
                                         w1h, w1l, w2h, w2l);

        // qk = x @ Wqk^T  (bf16x6, fp32 for bucket + packed K-half of kvp)
        gemm_bf6_k<<<dim3(4, 128), 256, 0, stream>>>(xh, xl, xl2, DD, wq1, wq2, wq3,
                                                     qkb, kvp, MROWS, DD, DD);
        // v = x @ Wv^T  (bf16x3, packed V-half of kvp)
        gemm_bf3_k<<<dim3(4, 128), 256, 0, stream>>>(xh, xl, DD, wvh, wvl, DD,
                                                     nullptr, nullptr,
                                                     nullptr, nullptr, nullptr, kvp + 64,
                                                     MROWS, DD, DD, 0);
        bucket_k<<<dim3(16, BHH), 256, 0, stream>>>(qkb, rot_i, bkt);
        sort_k<<<dim3(NH, BHH), 256, 0, stream>>>(bkt, st);

        // attention in 4 strips of 8 bh; combine -> att hi/lo
        for (int s = 0; s < 4; s++) {
            attn_k<<<2048, 256, 0, stream>>>(kvp, st, obuf, lseb, s * 8);
            combine_k<<<8192, 256, 0, stream>>>(obuf, lseb, attb, s * 8);
        }

        // x = x + att @ Wout^T + bout ; emit x hi/lo (for FFN input)
        gemm_bf3_k<<<dim3(4, 128), 256, 0, stream>>>(attb, attb + 512, 1024, woh, wol, DD,
                                                     bout_i, x, x, xh, xl, nullptr,
                                                     MROWS, DD, DD, 0);
        // FFN1 full-N via 256x256 tile / 8-wave kernel: h1 = relu(x @ W1^T + b1)
        gemm_bf3_256_k<<<dim3(8, 64), 512, 0, stream>>>(xh, xl, DD, w1h, w1l, DD,
                                                        b1_i, h1h, h1l,
                                                        MROWS, DFFN, DD, 1);
        // FFN2 full-K: x = x + h1 @ W2^T + b2  (in-place residual on x)
        gemm_bf3_k<<<dim3(4, 128), 256, 0, stream>>>(h1h, h1l, DFFN, w2h, w2l, DFFN,
                                                     b2_i, x,
                                                     x, nullptr, nullptr, nullptr,
                                                     MROWS, DD, DFFN, 0);
        // x = LN(x) in-place; emit 3-way split for next layer's qk/v
        ln_k<<<MROWS, 64, 0, stream>>>(x, g2_i, be2_i, x, xh, xl, xl2);
    }
    ln_k<<<MROWS, 64, 0, stream>>>(x, gf, bf, out, nullptr, nullptr, nullptr);
}